// Round 14
// baseline (332.035 us; speedup 1.0000x reference)
//
#include <hip/hip_runtime.h>
#include <math.h>

typedef unsigned short u16;
typedef __attribute__((ext_vector_type(8))) short short8;
typedef __attribute__((ext_vector_type(4))) float f32x4;

#define BB 32
#define WW 256
#define DD 512
#define NHEADS 4
#define NHID 128

__device__ __forceinline__ u16 f2bf(float f) {
  union { float f; unsigned int i; } x; x.f = f;
  unsigned int i = x.i;
  i += 0x7fffu + ((i >> 16) & 1u);
  return (u16)(i >> 16);
}
__device__ __forceinline__ float bf2f(u16 u) {
  union { float f; unsigned int i; } x; x.i = ((unsigned int)u) << 16; return x.f;
}

union BF8 { short8 v; u16 u[8]; };
union BF4 { ushort4 v; u16 u[4]; };
union F8 { float4 v4[2]; float f[8]; };

// ---------- prep (once) ----------
__global__ __launch_bounds__(256) void kprep_w(
    const float* __restrict__ qW, const float* __restrict__ kW, const float* __restrict__ vW,
    u16* __restrict__ Wt)
{
  int idx = blockIdx.x*256 + threadIdx.x;     // (c, o, i)
  if (idx >= 3*DD*DD) return;
  int c = idx >> 18;
  int oi = idx & (DD*DD - 1);
  int i = oi & (DD-1);
  int o = oi >> 9;
  const float* W = (c==0) ? qW : (c==1) ? kW : vW;
  float w0 = W[oi*3+0], w1 = W[oi*3+1], w2 = W[oi*3+2];
  Wt[((size_t)(c*3+0)*DD + o)*DD + i] = f2bf(w0);
  Wt[((size_t)(c*3+1)*DD + o)*DD + i] = f2bf(w1);
  Wt[((size_t)(c*3+2)*DD + o)*DD + i] = f2bf(w2);
}

__global__ __launch_bounds__(256) void kcvt(const float* __restrict__ s, u16* __restrict__ d, int n) {
  int i = blockIdx.x*256 + threadIdx.x;
  if (i < n) d[i] = f2bf(s[i]);
}

__global__ __launch_bounds__(256) void kprep_a(
    const float* __restrict__ hW, const float* __restrict__ hai, const float* __restrict__ haib,
    const float* __restrict__ haj, const float* __restrict__ hajb,
    const float* __restrict__ hb,
    const float* __restrict__ oW, const float* __restrict__ oai, const float* __restrict__ oaib,
    const float* __restrict__ oaj, const float* __restrict__ oajb,
    const float* __restrict__ ob,
    float* __restrict__ ahat_i, float* __restrict__ ahat_j,
    float* __restrict__ oahat_i, float* __restrict__ oahat_j,
    float* __restrict__ cvec)
{
  int idx = blockIdx.x*256 + threadIdx.x;
  if (idx < 1024) {
    int h = idx >> 8, f = idx & 255;
    float s = 0.f;
    for (int o = 0; o < NHID; ++o) s += hW[((size_t)h*NHID + o)*WW + f] * hai[h*NHID + o];
    ahat_i[idx] = s;
  } else if (idx < 2048) {
    int t = idx - 1024; int h = t >> 8, f = t & 255;
    float s = 0.f;
    for (int o = 0; o < NHID; ++o) s += hW[((size_t)h*NHID + o)*WW + f] * haj[h*NHID + o];
    ahat_j[t] = s;
  } else if (idx < 2560) {
    int f = idx - 2048;
    float s = 0.f;
    for (int o = 0; o < WW; ++o) s += oW[(size_t)o*DD + f] * oai[o];
    oahat_i[f] = s;
  } else if (idx < 3072) {
    int f = idx - 2560;
    float s = 0.f;
    for (int o = 0; o < WW; ++o) s += oW[(size_t)o*DD + f] * oaj[o];
    oahat_j[f] = s;
  } else if (idx < 3082) {
    int t = idx - 3072;
    if (t < 4) {
      float s = 0.f;
      for (int o = 0; o < NHID; ++o) s += hb[t*NHID + o]*hai[t*NHID + o];
      cvec[t] = s + haib[t];
    } else if (t < 8) {
      int h = t - 4; float s = 0.f;
      for (int o = 0; o < NHID; ++o) s += hb[h*NHID + o]*haj[h*NHID + o];
      cvec[t] = s + hajb[h];
    } else if (t == 8) {
      float s = 0.f;
      for (int o = 0; o < WW; ++o) s += ob[o]*oai[o];
      cvec[8] = s + oaib[0];
    } else {
      float s = 0.f;
      for (int o = 0; o < WW; ++o) s += ob[o]*oaj[o];
      cvec[9] = s + oajb[0];
    }
  }
}

// x f32 -> xpad bf16 [z][258][512] with zero halo rows (t=-1, t=256)
__global__ __launch_bounds__(256) void kprep_x(
    const float* __restrict__ x, int zb, int nrow8, u16* __restrict__ xpad)
{
  int idx8 = blockIdx.x*256 + threadIdx.x;
  if (idx8 >= nrow8) return;
  int i8 = idx8 & 63;
  int rowg = idx8 >> 6;                       // z*258 + r
  int z = rowg / 258, r = rowg - z*258;
  int t = r - 1;
  BF8 o8;
  if (t >= 0 && t < WW) {
    const float* src = x + ((size_t)(zb+z)*WW + t)*DD + i8*8;
    float4 v0 = *reinterpret_cast<const float4*>(src);
    float4 v1 = *reinterpret_cast<const float4*>(src + 4);
    o8.u[0]=f2bf(v0.x); o8.u[1]=f2bf(v0.y); o8.u[2]=f2bf(v0.z); o8.u[3]=f2bf(v0.w);
    o8.u[4]=f2bf(v1.x); o8.u[5]=f2bf(v1.y); o8.u[6]=f2bf(v1.z); o8.u[7]=f2bf(v1.w);
  } else {
    #pragma unroll
    for (int j = 0; j < 8; ++j) o8.u[j] = 0;
  }
  *reinterpret_cast<short8*>(xpad + (size_t)rowg*DD + i8*8) = o8.v;
}

// kexp2: per row-group (512 e2 values): M2 = max, E2p = exp(e2-M2), E2n = exp(0.1(e2-M2))
__global__ __launch_bounds__(256) void kexp2(
    const float* __restrict__ e2, float* __restrict__ M2,
    float* __restrict__ E2p, float* __restrict__ E2n)
{
  __shared__ float s4[4];
  const int zh = blockIdx.x, tid = threadIdx.x;
  float v0 = e2[(size_t)zh*DD + tid], v1 = e2[(size_t)zh*DD + 256 + tid];
  float m = fmaxf(v0, v1);
  #pragma unroll
  for (int off=32; off>=1; off>>=1) m = fmaxf(m, __shfl_xor(m, off));
  if ((tid & 63) == 0) s4[tid >> 6] = m;
  __syncthreads();
  m = fmaxf(fmaxf(s4[0], s4[1]), fmaxf(s4[2], s4[3]));
  if (tid == 0) M2[zh] = m;
  E2p[(size_t)zh*DD + tid]       = expf(v0 - m);
  E2p[(size_t)zh*DD + 256 + tid] = expf(v1 - m);
  E2n[(size_t)zh*DD + tid]       = expf(0.1f*(v0 - m));
  E2n[(size_t)zh*DD + 256 + tid] = expf(0.1f*(v1 - m));
}

// ---------- K1: conv via MFMA; 64o x 128t tile; B LDS-staged (swizzled, dbuf) ----------
__global__ __launch_bounds__(256) void k1_mfma(
    const u16* __restrict__ xpad, const u16* __restrict__ Wt,
    const float* __restrict__ qb, const float* __restrict__ kb, const float* __restrict__ vb,
    u16* __restrict__ qbf, u16* __restrict__ kbf, u16* __restrict__ vbf)
{
  __shared__ u16 bt[2][130*64];
  const int tid = threadIdx.x;
  const int w  = tid >> 6;
  const int l  = tid & 63;
  const int ln = l & 15;
  const int kg = l >> 4;
  const int og = blockIdx.x * 64 + w * 16;
  const int t0 = blockIdx.y * 128;
  const int z  = blockIdx.z;

  const u16* A0 = Wt + (size_t)(og + ln)*DD + kg*8;
  const u16* Xb = xpad + ((size_t)z*258 + t0)*DD;

  f32x4 acc[3][8];
  #pragma unroll
  for (int c=0;c<3;++c)
    #pragma unroll
    for (int ts=0;ts<8;++ts) acc[c][ts] = (f32x4){0.f,0.f,0.f,0.f};

  short8 ArP[9], ArQ[9];
  short8 sg0, sg1, sg2, sg3, sg4;
  const int ccw = tid & 7;
  const int rs = tid >> 3;

#define K1_LOADX(i0v) do { \
    sg0 = *reinterpret_cast<const short8*>(Xb + (size_t)rs*DD + (i0v) + ccw*8); \
    sg1 = *reinterpret_cast<const short8*>(Xb + (size_t)(rs+32)*DD + (i0v) + ccw*8); \
    sg2 = *reinterpret_cast<const short8*>(Xb + (size_t)(rs+64)*DD + (i0v) + ccw*8); \
    sg3 = *reinterpret_cast<const short8*>(Xb + (size_t)(rs+96)*DD + (i0v) + ccw*8); \
    if (tid < 16) sg4 = *reinterpret_cast<const short8*>(Xb + (size_t)(rs+128)*DD + (i0v) + ccw*8); \
  } while(0)

#define K1_WRITEX(bufv) do { \
    *reinterpret_cast<short8*>(&bt[bufv][rs*64 + ((ccw^(rs&7))<<3)]) = sg0; \
    *reinterpret_cast<short8*>(&bt[bufv][(rs+32)*64 + ((ccw^((rs+32)&7))<<3)]) = sg1; \
    *reinterpret_cast<short8*>(&bt[bufv][(rs+64)*64 + ((ccw^((rs+64)&7))<<3)]) = sg2; \
    *reinterpret_cast<short8*>(&bt[bufv][(rs+96)*64 + ((ccw^((rs+96)&7))<<3)]) = sg3; \
    if (tid < 16) *reinterpret_cast<short8*>(&bt[bufv][(rs+128)*64 + ((ccw^((rs+128)&7))<<3)]) = sg4; \
  } while(0)

#define K1_LOADA(Abuf, i0v, khv) do { \
    _Pragma("unroll") \
    for (int c = 0; c < 3; ++c) { \
      _Pragma("unroll") \
      for (int tap = 0; tap < 3; ++tap) \
        Abuf[c*3+tap] = *reinterpret_cast<const short8*>(A0 + (size_t)(c*3+tap)*DD*DD + (i0v) + (khv)*32); \
    } \
  } while(0)

#define K1_MFMAS(Abuf, khv) do { \
    _Pragma("unroll") \
    for (int tap = 0; tap < 3; ++tap) { \
      _Pragma("unroll") \
      for (int ts = 0; ts < 8; ++ts) { \
        int row = ts*16 + ln + tap; \
        short8 bfr = *reinterpret_cast<const short8*>(&bt[cur][row*64 + ((((khv)*4+kg) ^ (row&7))<<3)]); \
        acc[0][ts] = __builtin_amdgcn_mfma_f32_16x16x32_bf16(Abuf[0*3+tap], bfr, acc[0][ts], 0,0,0); \
        acc[1][ts] = __builtin_amdgcn_mfma_f32_16x16x32_bf16(Abuf[1*3+tap], bfr, acc[1][ts], 0,0,0); \
        acc[2][ts] = __builtin_amdgcn_mfma_f32_16x16x32_bf16(Abuf[2*3+tap], bfr, acc[2][ts], 0,0,0); \
      } \
    } \
  } while(0)

  K1_LOADX(0);
  K1_LOADA(ArP, 0, 0);
  K1_WRITEX(0);
  __syncthreads();

  int cur = 0;
  #pragma unroll 1
  for (int p = 0; p < 8; ++p) {
    const int i0 = p*64;
    if (p < 7) K1_LOADX(i0 + 64);
    K1_LOADA(ArQ, i0, 1);
    K1_MFMAS(ArP, 0);
    const int i0n = (p < 7) ? i0 + 64 : 0;
    K1_LOADA(ArP, i0n, 0);
    K1_MFMAS(ArQ, 1);
    if (p < 7) {
      K1_WRITEX(cur ^ 1);
      __syncthreads();
      cur ^= 1;
    }
  }

#undef K1_LOADX
#undef K1_WRITEX
#undef K1_LOADA
#undef K1_MFMAS

  #pragma unroll
  for (int ts=0; ts<8; ++ts) {
    int tg = t0 + ts*16 + ln;
    #pragma unroll
    for (int r=0;r<4;++r) {
      int o = og + kg*4 + r;
      size_t oi = (size_t)(z*DD + o)*WW + tg;
      qbf[oi] = f2bf(acc[0][ts][r] + qb[o]);
      kbf[oi] = f2bf(acc[1][ts][r] + kb[o]);
      vbf[oi] = f2bf(acc[2][ts][r] + vb[o]);
    }
  }
}

// ---------- K2: adj = sigmoid(q.kT * scale), B=k-panel staged ----------
__global__ __launch_bounds__(256) void k2_adj(
    const u16* __restrict__ qbf, const u16* __restrict__ kbf, int zb, float* __restrict__ adjo)
{
  __shared__ u16 bp[2][64*64];
  const int tid = threadIdx.x;
  const int w = tid >> 6, l = tid & 63, ln = l & 15, kg = l >> 4;
  const int d0 = blockIdx.x*64 + w*16;
  const int e0 = blockIdx.y*64;
  const int z  = blockIdx.z;
  const int sc = tid & 7, sr = tid >> 3;
  const int sp = sc ^ (sr & 7);
  const int sp2 = sc ^ ((sr+32) & 7);
  const u16* B0 = kbf + (size_t)(z*DD + e0)*WW;
  const u16* Asrc = qbf + (size_t)(z*DD + d0 + ln)*WW + kg*8;

  f32x4 acc[4];
  #pragma unroll
  for (int es=0;es<4;++es) acc[es] = (f32x4){0.f,0.f,0.f,0.f};
  short8 aP0, aP1, aQ0, aQ1, sg0, sg1;

  sg0 = *reinterpret_cast<const short8*>(B0 + (size_t)sr*WW + sc*8);
  sg1 = *reinterpret_cast<const short8*>(B0 + (size_t)(sr+32)*WW + sc*8);
  aP0 = *reinterpret_cast<const short8*>(Asrc);
  aP1 = *reinterpret_cast<const short8*>(Asrc + 32);
  *reinterpret_cast<short8*>(&bp[0][sr*64 + sp*8]) = sg0;
  *reinterpret_cast<short8*>(&bp[0][(sr+32)*64 + sp2*8]) = sg1;
  __syncthreads();

  int cur = 0;
  #pragma unroll 1
  for (int s = 0; s < 4; ++s) {
    const int fn = (s+1)*64;
    if (s < 3) {
      sg0 = *reinterpret_cast<const short8*>(B0 + (size_t)sr*WW + fn + sc*8);
      sg1 = *reinterpret_cast<const short8*>(B0 + (size_t)(sr+32)*WW + fn + sc*8);
      aQ0 = *reinterpret_cast<const short8*>(Asrc + fn);
      aQ1 = *reinterpret_cast<const short8*>(Asrc + fn + 32);
    }
    #pragma unroll
    for (int es = 0; es < 4; ++es) {
      int row = es*16 + ln;
      short8 b0 = *reinterpret_cast<const short8*>(&bp[cur][row*64 + ((kg ^ (row&7))<<3)]);
      acc[es] = __builtin_amdgcn_mfma_f32_16x16x32_bf16(aP0, b0, acc[es], 0,0,0);
      short8 b1 = *reinterpret_cast<const short8*>(&bp[cur][row*64 + (((4+kg) ^ (row&7))<<3)]);
      acc[es] = __builtin_amdgcn_mfma_f32_16x16x32_bf16(aP1, b1, acc[es], 0,0,0);
    }
    if (s < 3) {
      *reinterpret_cast<short8*>(&bp[cur^1][sr*64 + sp*8]) = sg0;
      *reinterpret_cast<short8*>(&bp[cur^1][(sr+32)*64 + sp2*8]) = sg1;
      __syncthreads();
      cur ^= 1;
      aP0 = aQ0; aP1 = aQ1;
    }
  }
  const float scale = 0.044194173824159216f;
  #pragma unroll
  for (int es=0; es<4; ++es)
    #pragma unroll
    for (int r=0; r<4; ++r) {
      float sig = 1.f/(1.f + expf(-acc[es][r]*scale));
      adjo[((size_t)(zb+z)*DD + d0 + kg*4 + r)*DD + e0 + es*16 + ln] = sig;
    }
}

// ---------- K3: Whtbf[zh][o][n] = (v @ hW^T + hb)^T, B=hW-panel staged ----------
__global__ __launch_bounds__(256) void k3_wh(
    const u16* __restrict__ vbf, const u16* __restrict__ hWbf, const float* __restrict__ hb,
    u16* __restrict__ Whtbf)
{
  __shared__ u16 bp[2][64*64];
  const int tid = threadIdx.x;
  const int w = tid >> 6, l = tid & 63, ln = l & 15, kg = l >> 4;
  const int n0 = blockIdx.x*64 + w*16;
  const int o0 = blockIdx.y*64;
  const int zh = blockIdx.z, z = zh >> 2, h = zh & 3;
  const int sc = tid & 7, sr = tid >> 3;
  const int sp = sc ^ (sr & 7);
  const int sp2 = sc ^ ((sr+32) & 7);
  const u16* B0 = hWbf + (size_t)(h*NHID + o0)*WW;
  const u16* Asrc = vbf + (size_t)(z*DD + n0 + ln)*WW + kg*8;

  f32x4 acc[4];
  #pragma unroll
  for (int os=0;os<4;++os) acc[os] = (f32x4){0.f,0.f,0.f,0.f};
  short8 aP0, aP1, aQ0, aQ1, sg0, sg1;

  sg0 = *reinterpret_cast<const short8*>(B0 + (size_t)sr*WW + sc*8);
  sg1 = *reinterpret_cast<const short8*>(B0 + (size_t)(sr+32)*WW + sc*8);
  aP0 = *reinterpret_cast<const short8*>(Asrc);
  aP1 = *reinterpret_cast<const short8*>(Asrc + 32);
  *reinterpret_cast<short8*>(&bp[0][sr*64 + sp*8]) = sg0;
  *reinterpret_cast<short8*>(&bp[0][(sr+32)*64 + sp2*8]) = sg1;
  __syncthreads();

  int cur = 0;
  #pragma unroll 1
  for (int s = 0; s < 4; ++s) {
    const int fn = (s+1)*64;
    if (s < 3) {
      sg0 = *reinterpret_cast<const short8*>(B0 + (size_t)sr*WW + fn + sc*8);
      sg1 = *reinterpret_cast<const short8*>(B0 + (size_t)(sr+32)*WW + fn + sc*8);
      aQ0 = *reinterpret_cast<const short8*>(Asrc + fn);
      aQ1 = *reinterpret_cast<const short8*>(Asrc + fn + 32);
    }
    #pragma unroll
    for (int os = 0; os < 4; ++os) {
      int row = os*16 + ln;
      short8 b0 = *reinterpret_cast<const short8*>(&bp[cur][row*64 + ((kg ^ (row&7))<<3)]);
      acc[os] = __builtin_amdgcn_mfma_f32_16x16x32_bf16(aP0, b0, acc[os], 0,0,0);
      short8 b1 = *reinterpret_cast<const short8*>(&bp[cur][row*64 + (((4+kg) ^ (row&7))<<3)]);
      acc[os] = __builtin_amdgcn_mfma_f32_16x16x32_bf16(aP1, b1, acc[os], 0,0,0);
    }
    if (s < 3) {
      *reinterpret_cast<short8*>(&bp[cur^1][sr*64 + sp*8]) = sg0;
      *reinterpret_cast<short8*>(&bp[cur^1][(sr+32)*64 + sp2*8]) = sg1;
      __syncthreads();
      cur ^= 1;
      aP0 = aQ0; aP1 = aQ1;
    }
  }
  #pragma unroll
  for (int os=0; os<4; ++os)
    #pragma unroll
    for (int r=0; r<4; ++r) {
      int o = o0 + os*16 + ln;
      int n = n0 + kg*4 + r;
      Whtbf[((size_t)zh*NHID + o)*DD + n] = f2bf(acc[os][r] + hb[h*NHID + o]);
    }
}

// ---------- K4: e1h/e2h ----------
__global__ __launch_bounds__(256) void k4_eheads(
    const u16* __restrict__ vbf,
    const float* __restrict__ ahat_i, const float* __restrict__ ahat_j,
    const float* __restrict__ cvec,
    float* __restrict__ e1, float* __restrict__ e2)
{
  int row = blockIdx.x*4 + (threadIdx.x >> 6);   // row = zh*512 + n
  int lane = threadIdx.x & 63;
  int zh = row >> 9, n = row & 511;
  int z = zh >> 2, h = zh & 3;
  BF4 v4; v4.v = *reinterpret_cast<const ushort4*>(vbf + ((size_t)(z*DD + n))*WW + lane*4);
  const float* aif = ahat_i + h*WW + lane*4;
  const float* ajf = ahat_j + h*WW + lane*4;
  float a1 = 0.f, a2 = 0.f;
  #pragma unroll
  for (int j = 0; j < 4; ++j) {
    float vf = bf2f(v4.u[j]);
    a1 += vf * aif[j];
    a2 += vf * ajf[j];
  }
  #pragma unroll
  for (int off = 32; off >= 1; off >>= 1) { a1 += __shfl_xor(a1, off); a2 += __shfl_xor(a2, off); }
  if (lane == 0) { e1[row] = a1 + cvec[h]; e2[row] = a2 + cvec[4+h]; }
}

// swizzled att chunk index
__device__ __forceinline__ int attsw(int c, int row) {
  return c ^ ((c >> 3) & 7) ^ (row & 7);
}

// ---------- K5: heads attention; factorized softmax (no exp in hot loop) ----------
__global__ __launch_bounds__(256) void k5_attn(
    const float* __restrict__ e1h, const float* __restrict__ e2h,
    const float* __restrict__ M2h, const float* __restrict__ E2p, const float* __restrict__ E2n,
    const u16* __restrict__ Whtbf, u16* __restrict__ hcatbf, int nzh)
{
  __shared__ u16 att[64*512];
  __shared__ float inv_lds[64];
  // XCD-chunked decode: orig&7 = presumed XCD; all 8 nb of a zh share it
  const int orig = blockIdx.x;
  const int xcd = orig & 7;
  const int k = orig >> 3;
  const int nb = k & 7;
  const int zh = xcd * (nzh >> 3) + (k >> 3);
  const int z = zh >> 2, h = zh & 3;
  const int n0 = nb*64;
  const int tid = threadIdx.x;

  // phase A: factorized softmax numerators
  const int r = tid >> 2, qd = tid & 3;
  const float e1n = e1h[(size_t)zh*DD + n0 + r];
  const float M2 = M2h[zh];
  const float s = e1n + M2;
  const float mx = (s > 0.f) ? s : 0.1f*s;        // = max_m leaky(e1n+e2m)
  const float Ap = expf(s - mx);
  const float An = expf(0.1f*s - mx);
  const float thr = -e1n;
  const float* e2r = e2h + (size_t)zh*DD + qd*128;
  const float* Epr = E2p + (size_t)zh*DD + qd*128;
  const float* Enr = E2n + (size_t)zh*DD + qd*128;
  float lsum = 0.f;
  for (int jc = 0; jc < 16; ++jc) {
    int j0 = jc*8;
    F8 e2x, epx, enx;
    e2x.v4[0] = *reinterpret_cast<const float4*>(e2r + j0);
    e2x.v4[1] = *reinterpret_cast<const float4*>(e2r + j0 + 4);
    epx.v4[0] = *reinterpret_cast<const float4*>(Epr + j0);
    epx.v4[1] = *reinterpret_cast<const float4*>(Epr + j0 + 4);
    enx.v4[0] = *reinterpret_cast<const float4*>(Enr + j0);
    enx.v4[1] = *reinterpret_cast<const float4*>(Enr + j0 + 4);
    BF8 pk;
    #pragma unroll
    for (int jj = 0; jj < 8; ++jj) {
      float p = (e2x.f[jj] > thr) ? Ap * epx.f[jj] : An * enx.f[jj];
      lsum += p;
      pk.u[jj] = f2bf(p);
    }
    int c = qd*16 + jc;
    *reinterpret_cast<short8*>(&att[r*512 + attsw(c, r)*8]) = pk.v;
  }
  lsum += __shfl_xor(lsum, 1);
  lsum += __shfl_xor(lsum, 2);
  if ((tid & 3) == 0) inv_lds[r] = 1.f / lsum;
  __syncthreads();

  // phase B: PV. wave w owns os {2w, 2w+1}; all 64 n rows.
  const int w = tid >> 6, l = tid & 63, ln = l & 15, kg = l >> 4;
  const u16* B0 = Whtbf + ((size_t)zh*NHID + w*32 + ln)*DD + kg*8;
  f32x4 acc[4][2];
  #pragma unroll
  for (int ns=0; ns<4; ++ns) { acc[ns][0] = (f32x4){0,0,0,0}; acc[ns][1] = (f32x4){0,0,0,0}; }

  short8 Pb0,Pb1,Qb0,Qb1,Rb0,Rb1,Sb0,Sb1;
#define K5_LDB(R0,R1,kkv) do { int kc = ((kkv) < 16) ? (kkv) : 0; \
    R0 = *reinterpret_cast<const short8*>(B0 + (size_t)kc*32); \
    R1 = *reinterpret_cast<const short8*>(B0 + (size_t)16*DD + (size_t)kc*32); } while(0)
#define K5_MM(R0,R1,kkv) do { \
    _Pragma("unroll") \
    for (int ns = 0; ns < 4; ++ns) { \
      int row = ns*16 + ln; int c = (kkv)*4 + kg; \
      short8 af = *reinterpret_cast<const short8*>(&att[row*512 + attsw(c,row)*8]); \
      acc[ns][0] = __builtin_amdgcn_mfma_f32_16x16x32_bf16(af, R0, acc[ns][0], 0,0,0); \
      acc[ns][1] = __builtin_amdgcn_mfma_f32_16x16x32_bf16(af, R1, acc[ns][1], 0,0,0); \
    } } while(0)

  K5_LDB(Pb0,Pb1,0); K5_LDB(Qb0,Qb1,1); K5_LDB(Rb0,Rb1,2);
  #pragma unroll 1
  for (int kk = 0; kk < 16; kk += 4) {
    K5_LDB(Sb0,Sb1,kk+3); K5_MM(Pb0,Pb1,kk);
    K5_LDB(Pb0,Pb1,kk+4); K5_MM(Qb0,Qb1,kk+1);
    K5_LDB(Qb0,Qb1,kk+5); K5_MM(Rb0,Rb1,kk+2);
    K5_LDB(Rb0,Rb1,kk+6); K5_MM(Sb0,Sb1,kk+3);
  }
#undef K5_LDB
#undef K5_MM

  #pragma unroll
  for (int ns = 0; ns < 4; ++ns)
    #pragma unroll
    for (int rr = 0; rr < 4; ++rr) {
      int n = ns*16 + kg*4 + rr;
      float inv = inv_lds[n];
      #pragma unroll
      for (int j = 0; j < 2; ++j) {
        float sv = acc[ns][j][rr] * inv;
        sv = (sv > 0.f) ? sv : expm1f(sv);
        hcatbf[((size_t)z*DD + n0 + n)*DD + h*NHID + w*32 + j*16 + ln] = f2bf(sv);
      }
    }
}

// ---------- K6: Wh2tbf[z][o][n] = (hcat @ oW^T + ob)^T, B=oW-panel staged ----------
__global__ __launch_bounds__(256) void k6_wh2(
    const u16* __restrict__ hcatbf, const u16* __restrict__ oWbf, const float* __restrict__ ob,
    u16* __restrict__ Wh2tbf)
{
  __shared__ u16 bp[2][64*64];
  const int tid = threadIdx.x;
  const int w = tid >> 6, l = tid & 63, ln = l & 15, kg = l >> 4;
  const int n0 = blockIdx.x*64 + w*16;
  const int o0 = blockIdx.y*64;
  const int z  = blockIdx.z;
  const int sc = tid & 7, sr = tid >> 3;
  const int sp = sc ^ (sr & 7);
  const int sp2 = sc ^ ((sr+32) & 7);
  const u16* B0 = oWbf + (size_t)o0*DD;
  const u16* Asrc = hcatbf + (size_t)(z*DD + n0 + ln)*DD + kg*8;

  f32x4 acc[4];
  #pragma unroll
  for (int os=0;os<4;++os) acc[os] = (f32x4){0.f,0.f,0.f,0.f};
  short8 aP0, aP1, aQ0, aQ1, sg0, sg1;

  sg0 = *reinterpret_cast<const short8*>(B0 + (size_t)sr*DD + sc*8);
  sg1 = *reinterpret_cast<const short8*>(B0 + (size_t)(sr+32)*DD + sc*8);
  aP0 = *reinterpret_cast<const short8*>(Asrc);
  aP1 = *reinterpret_cast<const short8*>(Asrc + 32);
  *reinterpret_cast<short8*>(&bp[0][sr*64 + sp*8]) = sg0;
  *reinterpret_cast<short8*>(&bp[0][(sr+32)*64 + sp2*8]) = sg1;
  __syncthreads();

  int cur = 0;
  #pragma unroll 1
  for (int s = 0; s < 8; ++s) {
    const int fn = (s+1)*64;
    if (s < 7) {
      sg0 = *reinterpret_cast<const short8*>(B0 + (size_t)sr*DD + fn + sc*8);
      sg1 = *reinterpret_cast<const short8*>(B0 + (size_t)(sr+32)*DD + fn + sc*8);
      aQ0 = *reinterpret_cast<const short8*>(Asrc + fn);
      aQ1 = *reinterpret_cast<const short8*>(Asrc + fn + 32);
    }
    #pragma unroll
    for (int os = 0; os < 4; ++os) {
      int row = os*16 + ln;
      short8 b0 = *reinterpret_cast<const short8*>(&bp[cur][row*64 + ((kg ^ (row&7))<<3)]);
      acc[os] = __builtin_amdgcn_mfma_f32_16x16x32_bf16(aP0, b0, acc[os], 0,0,0);
      short8 b1 = *reinterpret_cast<const short8*>(&bp[cur][row*64 + (((4+kg) ^ (row&7))<<3)]);
      acc[os] = __builtin_amdgcn_mfma_f32_16x16x32_bf16(aP1, b1, acc[os], 0,0,0);
    }
    if (s < 7) {
      *reinterpret_cast<short8*>(&bp[cur^1][sr*64 + sp*8]) = sg0;
      *reinterpret_cast<short8*>(&bp[cur^1][(sr+32)*64 + sp2*8]) = sg1;
      __syncthreads();
      cur ^= 1;
      aP0 = aQ0; aP1 = aQ1;
    }
  }
  #pragma unroll
  for (int os=0; os<4; ++os)
    #pragma unroll
    for (int r=0; r<4; ++r) {
      int o = o0 + os*16 + ln;
      int n = n0 + kg*4 + r;
      Wh2tbf[((size_t)z*WW + o)*DD + n] = f2bf(acc[os][r] + ob[o]);
    }
}

// ---------- K7: e1o/e2o ----------
__global__ __launch_bounds__(256) void k7_eout(
    const u16* __restrict__ hcatbf,
    const float* __restrict__ oahat_i, const float* __restrict__ oahat_j,
    const float* __restrict__ cvec,
    float* __restrict__ e1, float* __restrict__ e2)
{
  int row = blockIdx.x*4 + (threadIdx.x >> 6);
  int lane = threadIdx.x & 63;
  BF8 v8; v8.v = *reinterpret_cast<const short8*>(hcatbf + (size_t)row*DD + lane*8);
  float a1 = 0.f, a2 = 0.f;
  #pragma unroll
  for (int j = 0; j < 8; ++j) {
    float vf = bf2f(v8.u[j]);
    a1 += vf * oahat_i[lane*8 + j];
    a2 += vf * oahat_j[lane*8 + j];
  }
  #pragma unroll
  for (int off = 32; off >= 1; off >>= 1) { a1 += __shfl_xor(a1, off); a2 += __shfl_xor(a2, off); }
  if (lane == 0) { e1[row] = a1 + cvec[8]; e2[row] = a2 + cvec[9]; }
}

// ---------- K8a: out attention PV; factorized softmax -> g f32 (elu) ----------
__global__ __launch_bounds__(256) void k8_pv(
    const float* __restrict__ e1o, const float* __restrict__ e2o,
    const float* __restrict__ M2o, const float* __restrict__ E2p, const float* __restrict__ E2n,
    const u16* __restrict__ Wh2tbf, float* __restrict__ g, int CBv)
{
  __shared__ u16 att[64*512];
  __shared__ float inv_lds[64];
  const int orig = blockIdx.x;
  int nb, z, oh;
  if (CBv >= 8) {
    int xcd = orig & 7;
    int k = orig >> 3;
    nb = k & 7;
    int rest = k >> 3;
    oh = rest & 1;
    z = xcd * (CBv >> 3) + (rest >> 1);
  } else {
    nb = orig & 7;
    int k = orig >> 3;
    z = k >> 1;
    oh = k & 1;
  }
  const int n0 = nb*64;
  const int tid = threadIdx.x;

  const int r = tid >> 2, qd = tid & 3;
  const float e1n = e1o[(size_t)z*DD + n0 + r];
  const float M2 = M2o[z];
  const float s = e1n + M2;
  const float mx = (s > 0.f) ? s : 0.1f*s;
  const float Ap = expf(s - mx);
  const float An = expf(0.1f*s - mx);
  const float thr = -e1n;
  const float* e2r = e2o + (size_t)z*DD + qd*128;
  const float* Epr = E2p + (size_t)z*DD + qd*128;
  const float* Enr = E2n + (size_t)z*DD + qd*128;
  float lsum = 0.f;
  for (int jc = 0; jc < 16; ++jc) {
    int j0 = jc*8;
    F8 e2x, epx, enx;
    e2x.v4[0] = *reinterpret_cast<const float4*>(e2r + j0);
    e2x.v4[1] = *reinterpret_cast<const float4*>(e2r + j0 + 4);
    epx.v4[0] = *reinterpret_cast<const float4*>(Epr + j0);
    epx.v4[1] = *reinterpret_cast<const float4*>(Epr + j0 + 4);
    enx.v4[0] = *reinterpret_cast<const float4*>(Enr + j0);
    enx.v4[1] = *reinterpret_cast<const float4*>(Enr + j0 + 4);
    BF8 pk;
    #pragma unroll
    for (int jj = 0; jj < 8; ++jj) {
      float p = (e2x.f[jj] > thr) ? Ap * epx.f[jj] : An * enx.f[jj];
      lsum += p;
      pk.u[jj] = f2bf(p);
    }
    int c = qd*16 + jc;
    *reinterpret_cast<short8*>(&att[r*512 + attsw(c, r)*8]) = pk.v;
  }
  lsum += __shfl_xor(lsum, 1);
  lsum += __shfl_xor(lsum, 2);
  if ((tid & 3) == 0) inv_lds[r] = 1.f / lsum;
  __syncthreads();

  const int w = tid >> 6, l = tid & 63, ln = l & 15, kg = l >> 4;
  const u16* B0 = Wh2tbf + ((size_t)z*WW + oh*128 + w*32 + ln)*DD + kg*8;
  f32x4 acc[4][2];
  #pragma unroll
  for (int ns=0; ns<4; ++ns) { acc[ns][0] = (f32x4){0,0,0,0}; acc[ns][1] = (f32x4){0,0,0,0}; }

  short8 Pb0,Pb1,Qb0,Qb1,Rb0,Rb1,Sb0,Sb1;
#define K8_LDB(R0,R1,kkv) do { int kc = ((kkv) < 16) ? (kkv) : 0; \
    R0 = *reinterpret_cast<const short8*>(B0 + (size_t)kc*32); \
    R1 = *reinterpret_cast<const short8*>(B0 + (size_t)16*DD + (size_t)kc*32); } while(0)
#define K8_MM(R0,R1,kkv) do { \
    _Pragma("unroll") \
    for (int ns = 0; ns < 4; ++ns) { \
      int row = ns*16 + ln; int c = (kkv)*4 + kg; \
      short8 af = *reinterpret_cast<const short8*>(&att[row*512 + attsw(c,row)*8]); \
      acc[ns][0] = __builtin_amdgcn_mfma_f32_16x16x32_bf16(af, R0, acc[ns][0], 0,0,0); \
      acc[ns][1] = __builtin_amdgcn_mfma_f32_16x16x32_bf16(af, R1, acc[ns][1], 0,0,0); \
    } } while(0)

  K8_LDB(Pb0,Pb1,0); K8_LDB(Qb0,Qb1,1); K8_LDB(Rb0,Rb1,2);
  #pragma unroll 1
  for (int kk = 0; kk < 16; kk += 4) {
    K8_LDB(Sb0,Sb1,kk+3); K8_MM(Pb0,Pb1,kk);
    K8_LDB(Pb0,Pb1,kk+4); K8_MM(Qb0,Qb1,kk+1);
    K8_LDB(Qb0,Qb1,kk+5); K8_MM(Rb0,Rb1,kk+2);
    K8_LDB(Rb0,Rb1,kk+6); K8_MM(Sb0,Sb1,kk+3);
  }
#undef K8_LDB
#undef K8_MM

  #pragma unroll
  for (int ns = 0; ns < 4; ++ns)
    #pragma unroll
    for (int rr = 0; rr < 4; ++rr) {
      int n = ns*16 + kg*4 + rr;
      float inv = inv_lds[n];
      #pragma unroll
      for (int j = 0; j < 2; ++j) {
        float val = acc[ns][j][rr] * inv;
        val = (val > 0.f) ? val : expm1f(val);    // elu
        g[((size_t)z*DD + n0 + n)*WW + oh*128 + w*32 + j*16 + ln] = val;
      }
    }
}

// ---------- K8b: row log_softmax over o(256) -> gaty bf16 ----------
__global__ __launch_bounds__(256) void k8_lsm(
    const float* __restrict__ g, u16* __restrict__ gatybf)
{
  int row = blockIdx.x*4 + (threadIdx.x >> 6);
  int lane = threadIdx.x & 63;
  const float* gr = g + (size_t)row*WW;
  float v0 = gr[lane], v1 = gr[lane+64], v2 = gr[lane+128], v3 = gr[lane+192];
  float mx = fmaxf(fmaxf(v0,v1), fmaxf(v2,v3));
  #pragma unroll
  for (int off = 32; off >= 1; off >>= 1) mx = fmaxf(mx, __shfl_xor(mx, off));
  float sm = expf(v0-mx) + expf(v1-mx) + expf(v2-mx) + expf(v3-mx);
  #pragma unroll
  for (int off = 32; off >= 1; off >>= 1) sm += __shfl_xor(sm, off);
  float lg = mx + logf(sm);
  u16* go = gatybf + (size_t)row*WW;
  go[lane]     = f2bf(v0 - lg);
  go[lane+64]  = f2bf(v1 - lg);
  go[lane+128] = f2bf(v2 - lg);
  go[lane+192] = f2bf(v3 - lg);
}

// ---------- K9: out = gaty^T @ pW^T + pb ----------
__global__ __launch_bounds__(256) void k9_proj(
    const u16* __restrict__ gatybf, const u16* __restrict__ pWbf, const float* __restrict__ pb,
    int zb, float* __restrict__ out0)
{
  __shared__ u16 gt[64*40];
  const int t0 = blockIdx.x*64, d0 = blockIdx.y*64, z = blockIdx.z;
  const int tid = threadIdx.x;
  const int w = tid >> 6, l = tid & 63, ln = l & 15, kg = l >> 4;
  const int el = tid >> 3, t8 = tid & 7;
  f32x4 acc[4];
  #pragma unroll
  for (int os=0;os<4;++os) acc[os] = (f32x4){0.f,0.f,0.f,0.f};
  for (int e0 = 0; e0 < DD; e0 += 32) {
    __syncthreads();
    BF8 g8;
    g8.v = *reinterpret_cast<const short8*>(gatybf + ((size_t)z*DD + e0 + el)*WW + t0 + t8*8);
    #pragma unroll
    for (int j = 0; j < 8; ++j) gt[(t8*8 + j)*40 + el] = g8.u[j];
    __syncthreads();
    short8 a = *reinterpret_cast<const short8*>(&gt[(w*16 + ln)*40 + kg*8]);
    #pragma unroll
    for (int os = 0; os < 4; ++os) {
      short8 b = *reinterpret_cast<const short8*>(pWbf + (size_t)(d0 + os*16 + ln)*DD + e0 + kg*8);
      acc[os] = __builtin_amdgcn_mfma_f32_16x16x32_bf16(a, b, acc[os], 0,0,0);
    }
  }
  #pragma unroll
  for (int os=0; os<4; ++os)
    #pragma unroll
    for (int rr=0; rr<4; ++rr) {
      int t = t0 + w*16 + kg*4 + rr;
      int d = d0 + os*16 + ln;
      out0[((size_t)(zb+z)*WW + t)*DD + d] = acc[os][rr] + pb[d];
    }
}

extern "C" void kernel_launch(void* const* d_in, const int* in_sizes, int n_in,
                              void* d_out, int out_size, void* d_ws, size_t ws_size,
                              hipStream_t stream)
{
  const float* x   = (const float*)d_in[0];
  const float* qW  = (const float*)d_in[1];
  const float* qb  = (const float*)d_in[2];
  const float* kW  = (const float*)d_in[3];
  const float* kb  = (const float*)d_in[4];
  const float* vW  = (const float*)d_in[5];
  const float* vb  = (const float*)d_in[6];
  const float* hW  = (const float*)d_in[7];
  const float* hb  = (const float*)d_in[8];
  const float* hai = (const float*)d_in[9];
  const float* haib= (const float*)d_in[10];
  const float* haj = (const float*)d_in[11];
  const float* hajb= (const float*)d_in[12];
  const float* oW  = (const float*)d_in[13];
  const float* ob  = (const float*)d_in[14];
  const float* oai = (const float*)d_in[15];
  const float* oaib= (const float*)d_in[16];
  const float* oaj = (const float*)d_in[17];
  const float* oajb= (const float*)d_in[18];
  const float* pW  = (const float*)d_in[19];
  const float* pb  = (const float*)d_in[20];

  float* out0 = (float*)d_out;                   // [B,W,D] f32
  float* adjo = out0 + (size_t)BB*WW*DD;         // [B,D,D] f32

  // static region (float offsets)
  float* ws      = (float*)d_ws;
  u16*   Wt      = (u16*)(ws + 0);           // 1,179,648 f
  u16*   hWbf    = (u16*)(ws + 1179648);     //    65,536 f
  u16*   oWbf    = (u16*)(ws + 1245184);     //    65,536 f
  u16*   pWbf    = (u16*)(ws + 1310720);     //   131,072 f
  float* ahat_i  = ws + 1441792;
  float* ahat_j  = ws + 1442816;
  float* oahat_i = ws + 1443840;
  float* oahat_j = ws + 1444352;
  float* cvec    = ws + 1444864;
  float* e1h     = ws + 1444880;             //    65,536 f (CB=32 max)
  float* e2h     = ws + 1510416;
  float* e1o     = ws + 1575952;             //    16,384 f
  float* e2o     = ws + 1592336;
  float* M2h     = ws + 1608720;             //       128 f
  float* E2hp    = ws + 1608848;             //    65,536 f
  float* E2hn    = ws + 1674384;             //    65,536 f
  float* M2o     = ws + 1739920;             //        32 f
  float* E2op    = ws + 1739952;             //    16,384 f
  float* E2on    = ws + 1756336;             //    16,384 f
  const size_t X0 = 1772720;                 // dynamic region start

  // per-CB dynamic: xpad 66,048 + vbf 65,536 + qbf 65,536 + kbf 65,536 + Whtbf 131,072 = 393,728 f
  int CB = 4;
  {
    const int cand[3] = {32, 16, 8};
    for (int i = 0; i < 3; ++i) {
      size_t need = (X0 + (size_t)cand[i]*393728) * 4;
      if (need <= ws_size) { CB = cand[i]; break; }
    }
  }

  u16* xpad   = (u16*)(ws + X0);                        // CB*66,048 f  ([z][258][512])
  u16* vbf    = (u16*)(ws + X0 + (size_t)CB*66048);     // CB*65,536 f
  u16* qbf    = (u16*)(ws + X0 + (size_t)CB*131584);    // CB*65,536 f
  u16* kbf    = (u16*)(ws + X0 + (size_t)CB*197120);    // CB*65,536 f
  u16* Whtbf  = (u16*)(ws + X0 + (size_t)CB*262656);    // CB*131,072 f
  // overlays (lifetimes: xpad dead after k1; vbf dead after k4; qbf,kbf dead after k2;
  // hcatbf dead after k7; Whtbf dead after k5)
  u16*   hcatbf = (u16*)(ws + X0);                      // over xpad+vbf
  float* g      = (float*)(ws + X0);                    // over hcatbf region (k8 phase)
  u16*   gatybf = (u16*)(ws + X0 + (size_t)CB*131584);  // over qbf
  u16*   Wh2tbf = (u16*)(ws + X0 + (size_t)CB*197120);  // over kbf

  kprep_w<<<dim3((3*DD*DD + 255)/256), 256, 0, stream>>>(qW, kW, vW, Wt);
  kcvt<<<dim3((NHEADS*NHID*WW + 255)/256), 256, 0, stream>>>(hW, hWbf, NHEADS*NHID*WW);
  kcvt<<<dim3((WW*DD + 255)/256), 256, 0, stream>>>(oW, oWbf, WW*DD);
  kcvt<<<dim3((DD*DD + 255)/256), 256, 0, stream>>>(pW, pWbf, DD*DD);
  kprep_a<<<dim3(13), 256, 0, stream>>>(hW, hai, haib, haj, hajb, hb,
                                        oW, oai, oaib, oaj, oajb, ob,
                                        ahat_i, ahat_j, oahat_i, oahat_j, cvec);

  for (int zb = 0; zb < BB; zb += CB) {
    int nrow8 = CB*258*64;
    kprep_x  <<<dim3((nrow8 + 255)/256), 256, 0, stream>>>(x, zb, nrow8, xpad);
    k1_mfma  <<<dim3(DD/64, WW/128, CB), 256, 0, stream>>>(xpad, Wt, qb, kb, vb, qbf, kbf, vbf);
    k2_adj   <<<dim3(DD/64, DD/64, CB), 256, 0, stream>>>(qbf, kbf, zb, adjo);
    k3_wh    <<<dim3(DD/64, NHID/64, CB*NHEADS), 256, 0, stream>>>(vbf, hWbf, hb, Whtbf);
    k4_eheads<<<dim3(CB*NHEADS*DD/4), 256, 0, stream>>>(vbf, ahat_i, ahat_j, cvec, e1h, e2h);
    kexp2    <<<dim3(CB*NHEADS), 256, 0, stream>>>(e2h, M2h, E2hp, E2hn);
    k5_attn  <<<dim3(32*CB), 256, 0, stream>>>(e1h, e2h, M2h, E2hp, E2hn, Whtbf, hcatbf, CB*NHEADS);
    k6_wh2   <<<dim3(DD/64, WW/64, CB), 256, 0, stream>>>(hcatbf, oWbf, ob, Wh2tbf);
    k7_eout  <<<dim3(CB*DD/4), 256, 0, stream>>>(hcatbf, oahat_i, oahat_j, cvec, e1o, e2o);
    kexp2    <<<dim3(CB), 256, 0, stream>>>(e2o, M2o, E2op, E2on);
    k8_pv    <<<dim3(16*CB), 256, 0, stream>>>(e1o, e2o, M2o, E2op, E2on, Wh2tbf, g, CB);
    k8_lsm   <<<dim3(CB*128), 256, 0, stream>>>(g, gatybf);
    k9_proj  <<<dim3(WW/64, DD/64, CB), 256, 0, stream>>>(gatybf, pWbf, pb, zb, out0);
  }
}

// Round 15
// 318.481 us; speedup vs baseline: 1.0426x; 1.0426x over previous
//
#include <hip/hip_runtime.h>
#include <math.h>

typedef unsigned short u16;
typedef __attribute__((ext_vector_type(8))) short short8;
typedef __attribute__((ext_vector_type(4))) float f32x4;

#define BB 32
#define WW 256
#define DD 512
#define NHEADS 4
#define NHID 128

__device__ __forceinline__ u16 f2bf(float f) {
  union { float f; unsigned int i; } x; x.f = f;
  unsigned int i = x.i;
  i += 0x7fffu + ((i >> 16) & 1u);
  return (u16)(i >> 16);
}
__device__ __forceinline__ float bf2f(u16 u) {
  union { float f; unsigned int i; } x; x.i = ((unsigned int)u) << 16; return x.f;
}

union BF8 { short8 v; u16 u[8]; };
union BF4 { ushort4 v; u16 u[4]; };
union F8 { float4 v4[2]; float f[8]; };

// ---------- prep (once) ----------
__global__ __launch_bounds__(256) void kprep_w(
    const float* __restrict__ qW, const float* __restrict__ kW, const float* __restrict__ vW,
    u16* __restrict__ Wt)
{
  int idx = blockIdx.x*256 + threadIdx.x;     // (c, o, i)
  if (idx >= 3*DD*DD) return;
  int c = idx >> 18;
  int oi = idx & (DD*DD - 1);
  int i = oi & (DD-1);
  int o = oi >> 9;
  const float* W = (c==0) ? qW : (c==1) ? kW : vW;
  float w0 = W[oi*3+0], w1 = W[oi*3+1], w2 = W[oi*3+2];
  Wt[((size_t)(c*3+0)*DD + o)*DD + i] = f2bf(w0);
  Wt[((size_t)(c*3+1)*DD + o)*DD + i] = f2bf(w1);
  Wt[((size_t)(c*3+2)*DD + o)*DD + i] = f2bf(w2);
}

__global__ __launch_bounds__(256) void kcvt(const float* __restrict__ s, u16* __restrict__ d, int n) {
  int i = blockIdx.x*256 + threadIdx.x;
  if (i < n) d[i] = f2bf(s[i]);
}

__global__ __launch_bounds__(256) void kprep_a(
    const float* __restrict__ hW, const float* __restrict__ hai, const float* __restrict__ haib,
    const float* __restrict__ haj, const float* __restrict__ hajb,
    const float* __restrict__ hb,
    const float* __restrict__ oW, const float* __restrict__ oai, const float* __restrict__ oaib,
    const float* __restrict__ oaj, const float* __restrict__ oajb,
    const float* __restrict__ ob,
    float* __restrict__ ahat_i, float* __restrict__ ahat_j,
    float* __restrict__ oahat_i, float* __restrict__ oahat_j,
    float* __restrict__ cvec)
{
  int idx = blockIdx.x*256 + threadIdx.x;
  if (idx < 1024) {
    int h = idx >> 8, f = idx & 255;
    float s = 0.f;
    for (int o = 0; o < NHID; ++o) s += hW[((size_t)h*NHID + o)*WW + f] * hai[h*NHID + o];
    ahat_i[idx] = s;
  } else if (idx < 2048) {
    int t = idx - 1024; int h = t >> 8, f = t & 255;
    float s = 0.f;
    for (int o = 0; o < NHID; ++o) s += hW[((size_t)h*NHID + o)*WW + f] * haj[h*NHID + o];
    ahat_j[t] = s;
  } else if (idx < 2560) {
    int f = idx - 2048;
    float s = 0.f;
    for (int o = 0; o < WW; ++o) s += oW[(size_t)o*DD + f] * oai[o];
    oahat_i[f] = s;
  } else if (idx < 3072) {
    int f = idx - 2560;
    float s = 0.f;
    for (int o = 0; o < WW; ++o) s += oW[(size_t)o*DD + f] * oaj[o];
    oahat_j[f] = s;
  } else if (idx < 3082) {
    int t = idx - 3072;
    if (t < 4) {
      float s = 0.f;
      for (int o = 0; o < NHID; ++o) s += hb[t*NHID + o]*hai[t*NHID + o];
      cvec[t] = s + haib[t];
    } else if (t < 8) {
      int h = t - 4; float s = 0.f;
      for (int o = 0; o < NHID; ++o) s += hb[h*NHID + o]*haj[h*NHID + o];
      cvec[t] = s + hajb[h];
    } else if (t == 8) {
      float s = 0.f;
      for (int o = 0; o < WW; ++o) s += ob[o]*oai[o];
      cvec[8] = s + oaib[0];
    } else {
      float s = 0.f;
      for (int o = 0; o < WW; ++o) s += ob[o]*oaj[o];
      cvec[9] = s + oajb[0];
    }
  }
}

// x f32 -> xpad bf16 [z][258][512] with zero halo rows (t=-1, t=256)
__global__ __launch_bounds__(256) void kprep_x(
    const float* __restrict__ x, int zb, int nrow8, u16* __restrict__ xpad)
{
  int idx8 = blockIdx.x*256 + threadIdx.x;
  if (idx8 >= nrow8) return;
  int i8 = idx8 & 63;
  int rowg = idx8 >> 6;                       // z*258 + r
  int z = rowg / 258, r = rowg - z*258;
  int t = r - 1;
  BF8 o8;
  if (t >= 0 && t < WW) {
    const float* src = x + ((size_t)(zb+z)*WW + t)*DD + i8*8;
    float4 v0 = *reinterpret_cast<const float4*>(src);
    float4 v1 = *reinterpret_cast<const float4*>(src + 4);
    o8.u[0]=f2bf(v0.x); o8.u[1]=f2bf(v0.y); o8.u[2]=f2bf(v0.z); o8.u[3]=f2bf(v0.w);
    o8.u[4]=f2bf(v1.x); o8.u[5]=f2bf(v1.y); o8.u[6]=f2bf(v1.z); o8.u[7]=f2bf(v1.w);
  } else {
    #pragma unroll
    for (int j = 0; j < 8; ++j) o8.u[j] = 0;
  }
  *reinterpret_cast<short8*>(xpad + (size_t)rowg*DD + i8*8) = o8.v;
}

// kexp2: per row-group (512 e2 values): M2 = max, E2p = exp(e2-M2), E2n = exp(0.1(e2-M2))
__global__ __launch_bounds__(256) void kexp2(
    const float* __restrict__ e2, float* __restrict__ M2,
    float* __restrict__ E2p, float* __restrict__ E2n)
{
  __shared__ float s4[4];
  const int zh = blockIdx.x, tid = threadIdx.x;
  float v0 = e2[(size_t)zh*DD + tid], v1 = e2[(size_t)zh*DD + 256 + tid];
  float m = fmaxf(v0, v1);
  #pragma unroll
  for (int off=32; off>=1; off>>=1) m = fmaxf(m, __shfl_xor(m, off));
  if ((tid & 63) == 0) s4[tid >> 6] = m;
  __syncthreads();
  m = fmaxf(fmaxf(s4[0], s4[1]), fmaxf(s4[2], s4[3]));
  if (tid == 0) M2[zh] = m;
  E2p[(size_t)zh*DD + tid]       = expf(v0 - m);
  E2p[(size_t)zh*DD + 256 + tid] = expf(v1 - m);
  E2n[(size_t)zh*DD + tid]       = expf(0.1f*(v0 - m));
  E2n[(size_t)zh*DD + 256 + tid] = expf(0.1f*(v1 - m));
}

// ---------- K1: conv via MFMA; 64o x 128t tile; B LDS-staged (swizzled, dbuf) ----------
__global__ __launch_bounds__(256) void k1_mfma(
    const u16* __restrict__ xpad, const u16* __restrict__ Wt,
    const float* __restrict__ qb, const float* __restrict__ kb, const float* __restrict__ vb,
    u16* __restrict__ qbf, u16* __restrict__ kbf, u16* __restrict__ vbf)
{
  __shared__ u16 bt[2][130*64];
  const int tid = threadIdx.x;
  const int w  = tid >> 6;
  const int l  = tid & 63;
  const int ln = l & 15;
  const int kg = l >> 4;
  const int og = blockIdx.x * 64 + w * 16;
  const int t0 = blockIdx.y * 128;
  const int z  = blockIdx.z;

  const u16* A0 = Wt + (size_t)(og + ln)*DD + kg*8;
  const u16* Xb = xpad + ((size_t)z*258 + t0)*DD;

  f32x4 acc[3][8];
  #pragma unroll
  for (int c=0;c<3;++c)
    #pragma unroll
    for (int ts=0;ts<8;++ts) acc[c][ts] = (f32x4){0.f,0.f,0.f,0.f};

  short8 ArP[9], ArQ[9];
  short8 sg0, sg1, sg2, sg3, sg4;
  const int ccw = tid & 7;
  const int rs = tid >> 3;

#define K1_LOADX(i0v) do { \
    sg0 = *reinterpret_cast<const short8*>(Xb + (size_t)rs*DD + (i0v) + ccw*8); \
    sg1 = *reinterpret_cast<const short8*>(Xb + (size_t)(rs+32)*DD + (i0v) + ccw*8); \
    sg2 = *reinterpret_cast<const short8*>(Xb + (size_t)(rs+64)*DD + (i0v) + ccw*8); \
    sg3 = *reinterpret_cast<const short8*>(Xb + (size_t)(rs+96)*DD + (i0v) + ccw*8); \
    if (tid < 16) sg4 = *reinterpret_cast<const short8*>(Xb + (size_t)(rs+128)*DD + (i0v) + ccw*8); \
  } while(0)

#define K1_WRITEX(bufv) do { \
    *reinterpret_cast<short8*>(&bt[bufv][rs*64 + ((ccw^(rs&7))<<3)]) = sg0; \
    *reinterpret_cast<short8*>(&bt[bufv][(rs+32)*64 + ((ccw^((rs+32)&7))<<3)]) = sg1; \
    *reinterpret_cast<short8*>(&bt[bufv][(rs+64)*64 + ((ccw^((rs+64)&7))<<3)]) = sg2; \
    *reinterpret_cast<short8*>(&bt[bufv][(rs+96)*64 + ((ccw^((rs+96)&7))<<3)]) = sg3; \
    if (tid < 16) *reinterpret_cast<short8*>(&bt[bufv][(rs+128)*64 + ((ccw^((rs+128)&7))<<3)]) = sg4; \
  } while(0)

#define K1_LOADA(Abuf, i0v, khv) do { \
    _Pragma("unroll") \
    for (int c = 0; c < 3; ++c) { \
      _Pragma("unroll") \
      for (int tap = 0; tap < 3; ++tap) \
        Abuf[c*3+tap] = *reinterpret_cast<const short8*>(A0 + (size_t)(c*3+tap)*DD*DD + (i0v) + (khv)*32); \
    } \
  } while(0)

#define K1_MFMAS(Abuf, khv) do { \
    _Pragma("unroll") \
    for (int tap = 0; tap < 3; ++tap) { \
      _Pragma("unroll") \
      for (int ts = 0; ts < 8; ++ts) { \
        int row = ts*16 + ln + tap; \
        short8 bfr = *reinterpret_cast<const short8*>(&bt[cur][row*64 + ((((khv)*4+kg) ^ (row&7))<<3)]); \
        acc[0][ts] = __builtin_amdgcn_mfma_f32_16x16x32_bf16(Abuf[0*3+tap], bfr, acc[0][ts], 0,0,0); \
        acc[1][ts] = __builtin_amdgcn_mfma_f32_16x16x32_bf16(Abuf[1*3+tap], bfr, acc[1][ts], 0,0,0); \
        acc[2][ts] = __builtin_amdgcn_mfma_f32_16x16x32_bf16(Abuf[2*3+tap], bfr, acc[2][ts], 0,0,0); \
      } \
    } \
  } while(0)

  K1_LOADX(0);
  K1_LOADA(ArP, 0, 0);
  K1_WRITEX(0);
  __syncthreads();

  int cur = 0;
  #pragma unroll 1
  for (int p = 0; p < 8; ++p) {
    const int i0 = p*64;
    if (p < 7) K1_LOADX(i0 + 64);
    K1_LOADA(ArQ, i0, 1);
    K1_MFMAS(ArP, 0);
    const int i0n = (p < 7) ? i0 + 64 : 0;
    K1_LOADA(ArP, i0n, 0);
    K1_MFMAS(ArQ, 1);
    if (p < 7) {
      K1_WRITEX(cur ^ 1);
      __syncthreads();
      cur ^= 1;
    }
  }

#undef K1_LOADX
#undef K1_WRITEX
#undef K1_LOADA
#undef K1_MFMAS

  #pragma unroll
  for (int ts=0; ts<8; ++ts) {
    int tg = t0 + ts*16 + ln;
    #pragma unroll
    for (int r=0;r<4;++r) {
      int o = og + kg*4 + r;
      size_t oi = (size_t)(z*DD + o)*WW + tg;
      qbf[oi] = f2bf(acc[0][ts][r] + qb[o]);
      kbf[oi] = f2bf(acc[1][ts][r] + kb[o]);
      vbf[oi] = f2bf(acc[2][ts][r] + vb[o]);
    }
  }
}

// ---------- K2: adj = sigmoid(q.kT * scale), B=k-panel staged ----------
__global__ __launch_bounds__(256) void k2_adj(
    const u16* __restrict__ qbf, const u16* __restrict__ kbf, int zb, float* __restrict__ adjo)
{
  __shared__ u16 bp[2][64*64];
  const int tid = threadIdx.x;
  const int w = tid >> 6, l = tid & 63, ln = l & 15, kg = l >> 4;
  const int d0 = blockIdx.x*64 + w*16;
  const int e0 = blockIdx.y*64;
  const int z  = blockIdx.z;
  const int sc = tid & 7, sr = tid >> 3;
  const int sp = sc ^ (sr & 7);
  const int sp2 = sc ^ ((sr+32) & 7);
  const u16* B0 = kbf + (size_t)(z*DD + e0)*WW;
  const u16* Asrc = qbf + (size_t)(z*DD + d0 + ln)*WW + kg*8;

  f32x4 acc[4];
  #pragma unroll
  for (int es=0;es<4;++es) acc[es] = (f32x4){0.f,0.f,0.f,0.f};
  short8 aP0, aP1, aQ0, aQ1, sg0, sg1;

  sg0 = *reinterpret_cast<const short8*>(B0 + (size_t)sr*WW + sc*8);
  sg1 = *reinterpret_cast<const short8*>(B0 + (size_t)(sr+32)*WW + sc*8);
  aP0 = *reinterpret_cast<const short8*>(Asrc);
  aP1 = *reinterpret_cast<const short8*>(Asrc + 32);
  *reinterpret_cast<short8*>(&bp[0][sr*64 + sp*8]) = sg0;
  *reinterpret_cast<short8*>(&bp[0][(sr+32)*64 + sp2*8]) = sg1;
  __syncthreads();

  int cur = 0;
  #pragma unroll 1
  for (int s = 0; s < 4; ++s) {
    const int fn = (s+1)*64;
    if (s < 3) {
      sg0 = *reinterpret_cast<const short8*>(B0 + (size_t)sr*WW + fn + sc*8);
      sg1 = *reinterpret_cast<const short8*>(B0 + (size_t)(sr+32)*WW + fn + sc*8);
      aQ0 = *reinterpret_cast<const short8*>(Asrc + fn);
      aQ1 = *reinterpret_cast<const short8*>(Asrc + fn + 32);
    }
    #pragma unroll
    for (int es = 0; es < 4; ++es) {
      int row = es*16 + ln;
      short8 b0 = *reinterpret_cast<const short8*>(&bp[cur][row*64 + ((kg ^ (row&7))<<3)]);
      acc[es] = __builtin_amdgcn_mfma_f32_16x16x32_bf16(aP0, b0, acc[es], 0,0,0);
      short8 b1 = *reinterpret_cast<const short8*>(&bp[cur][row*64 + (((4+kg) ^ (row&7))<<3)]);
      acc[es] = __builtin_amdgcn_mfma_f32_16x16x32_bf16(aP1, b1, acc[es], 0,0,0);
    }
    if (s < 3) {
      *reinterpret_cast<short8*>(&bp[cur^1][sr*64 + sp*8]) = sg0;
      *reinterpret_cast<short8*>(&bp[cur^1][(sr+32)*64 + sp2*8]) = sg1;
      __syncthreads();
      cur ^= 1;
      aP0 = aQ0; aP1 = aQ1;
    }
  }
  const float scale = 0.044194173824159216f;
  #pragma unroll
  for (int es=0; es<4; ++es)
    #pragma unroll
    for (int r=0; r<4; ++r) {
      float sig = 1.f/(1.f + expf(-acc[es][r]*scale));
      adjo[((size_t)(zb+z)*DD + d0 + kg*4 + r)*DD + e0 + es*16 + ln] = sig;
    }
}

// ---------- K3: Whtbf[zh][o][n] = (v @ hW^T + hb)^T, B=hW-panel staged ----------
__global__ __launch_bounds__(256) void k3_wh(
    const u16* __restrict__ vbf, const u16* __restrict__ hWbf, const float* __restrict__ hb,
    u16* __restrict__ Whtbf)
{
  __shared__ u16 bp[2][64*64];
  const int tid = threadIdx.x;
  const int w = tid >> 6, l = tid & 63, ln = l & 15, kg = l >> 4;
  const int n0 = blockIdx.x*64 + w*16;
  const int o0 = blockIdx.y*64;
  const int zh = blockIdx.z, z = zh >> 2, h = zh & 3;
  const int sc = tid & 7, sr = tid >> 3;
  const int sp = sc ^ (sr & 7);
  const int sp2 = sc ^ ((sr+32) & 7);
  const u16* B0 = hWbf + (size_t)(h*NHID + o0)*WW;
  const u16* Asrc = vbf + (size_t)(z*DD + n0 + ln)*WW + kg*8;

  f32x4 acc[4];
  #pragma unroll
  for (int os=0;os<4;++os) acc[os] = (f32x4){0.f,0.f,0.f,0.f};
  short8 aP0, aP1, aQ0, aQ1, sg0, sg1;

  sg0 = *reinterpret_cast<const short8*>(B0 + (size_t)sr*WW + sc*8);
  sg1 = *reinterpret_cast<const short8*>(B0 + (size_t)(sr+32)*WW + sc*8);
  aP0 = *reinterpret_cast<const short8*>(Asrc);
  aP1 = *reinterpret_cast<const short8*>(Asrc + 32);
  *reinterpret_cast<short8*>(&bp[0][sr*64 + sp*8]) = sg0;
  *reinterpret_cast<short8*>(&bp[0][(sr+32)*64 + sp2*8]) = sg1;
  __syncthreads();

  int cur = 0;
  #pragma unroll 1
  for (int s = 0; s < 4; ++s) {
    const int fn = (s+1)*64;
    if (s < 3) {
      sg0 = *reinterpret_cast<const short8*>(B0 + (size_t)sr*WW + fn + sc*8);
      sg1 = *reinterpret_cast<const short8*>(B0 + (size_t)(sr+32)*WW + fn + sc*8);
      aQ0 = *reinterpret_cast<const short8*>(Asrc + fn);
      aQ1 = *reinterpret_cast<const short8*>(Asrc + fn + 32);
    }
    #pragma unroll
    for (int os = 0; os < 4; ++os) {
      int row = os*16 + ln;
      short8 b0 = *reinterpret_cast<const short8*>(&bp[cur][row*64 + ((kg ^ (row&7))<<3)]);
      acc[os] = __builtin_amdgcn_mfma_f32_16x16x32_bf16(aP0, b0, acc[os], 0,0,0);
      short8 b1 = *reinterpret_cast<const short8*>(&bp[cur][row*64 + (((4+kg) ^ (row&7))<<3)]);
      acc[os] = __builtin_amdgcn_mfma_f32_16x16x32_bf16(aP1, b1, acc[os], 0,0,0);
    }
    if (s < 3) {
      *reinterpret_cast<short8*>(&bp[cur^1][sr*64 + sp*8]) = sg0;
      *reinterpret_cast<short8*>(&bp[cur^1][(sr+32)*64 + sp2*8]) = sg1;
      __syncthreads();
      cur ^= 1;
      aP0 = aQ0; aP1 = aQ1;
    }
  }
  #pragma unroll
  for (int os=0; os<4; ++os)
    #pragma unroll
    for (int r=0; r<4; ++r) {
      int o = o0 + os*16 + ln;
      int n = n0 + kg*4 + r;
      Whtbf[((size_t)zh*NHID + o)*DD + n] = f2bf(acc[os][r] + hb[h*NHID + o]);
    }
}

// ---------- K4: e1h/e2h ----------
__global__ __launch_bounds__(256) void k4_eheads(
    const u16* __restrict__ vbf,
    const float* __restrict__ ahat_i, const float* __restrict__ ahat_j,
    const float* __restrict__ cvec,
    float* __restrict__ e1, float* __restrict__ e2)
{
  int row = blockIdx.x*4 + (threadIdx.x >> 6);   // row = zh*512 + n
  int lane = threadIdx.x & 63;
  int zh = row >> 9, n = row & 511;
  int z = zh >> 2, h = zh & 3;
  BF4 v4; v4.v = *reinterpret_cast<const ushort4*>(vbf + ((size_t)(z*DD + n))*WW + lane*4);
  const float* aif = ahat_i + h*WW + lane*4;
  const float* ajf = ahat_j + h*WW + lane*4;
  float a1 = 0.f, a2 = 0.f;
  #pragma unroll
  for (int j = 0; j < 4; ++j) {
    float vf = bf2f(v4.u[j]);
    a1 += vf * aif[j];
    a2 += vf * ajf[j];
  }
  #pragma unroll
  for (int off = 32; off >= 1; off >>= 1) { a1 += __shfl_xor(a1, off); a2 += __shfl_xor(a2, off); }
  if (lane == 0) { e1[row] = a1 + cvec[h]; e2[row] = a2 + cvec[4+h]; }
}

// swizzled att chunk index
__device__ __forceinline__ int attsw(int c, int row) {
  return c ^ ((c >> 3) & 7) ^ (row & 7);
}

// ---------- K5: heads attention; 8 waves, factorized softmax ----------
__global__ __launch_bounds__(512) void k5_attn(
    const float* __restrict__ e1h, const float* __restrict__ e2h,
    const float* __restrict__ M2h, const float* __restrict__ E2p, const float* __restrict__ E2n,
    const u16* __restrict__ Whtbf, u16* __restrict__ hcatbf, int nzh)
{
  __shared__ u16 att[64*512];
  __shared__ float inv_lds[64];
  const int orig = blockIdx.x;
  const int xcd = orig & 7;
  const int k = orig >> 3;
  const int nb = k & 7;
  const int zh = xcd * (nzh >> 3) + (k >> 3);
  const int z = zh >> 2, h = zh & 3;
  const int n0 = nb*64;
  const int tid = threadIdx.x;

  // phase A: factorized softmax. thread = (r = tid>>3, qd = tid&7), 64 m per thread
  const int r = tid >> 3, qd = tid & 7;
  const float e1n = e1h[(size_t)zh*DD + n0 + r];
  const float M2 = M2h[zh];
  const float s = e1n + M2;
  const float mx = (s > 0.f) ? s : 0.1f*s;
  const float Ap = expf(s - mx);
  const float An = expf(0.1f*s - mx);
  const float thr = -e1n;
  const float* e2r = e2h + (size_t)zh*DD + qd*64;
  const float* Epr = E2p + (size_t)zh*DD + qd*64;
  const float* Enr = E2n + (size_t)zh*DD + qd*64;
  float lsum = 0.f;
  for (int jc = 0; jc < 8; ++jc) {
    int j0 = jc*8;
    F8 e2x, epx, enx;
    e2x.v4[0] = *reinterpret_cast<const float4*>(e2r + j0);
    e2x.v4[1] = *reinterpret_cast<const float4*>(e2r + j0 + 4);
    epx.v4[0] = *reinterpret_cast<const float4*>(Epr + j0);
    epx.v4[1] = *reinterpret_cast<const float4*>(Epr + j0 + 4);
    enx.v4[0] = *reinterpret_cast<const float4*>(Enr + j0);
    enx.v4[1] = *reinterpret_cast<const float4*>(Enr + j0 + 4);
    BF8 pk;
    #pragma unroll
    for (int jj = 0; jj < 8; ++jj) {
      float p = (e2x.f[jj] > thr) ? Ap * epx.f[jj] : An * enx.f[jj];
      lsum += p;
      pk.u[jj] = f2bf(p);
    }
    int c = qd*8 + jc;
    *reinterpret_cast<short8*>(&att[r*512 + attsw(c, r)*8]) = pk.v;
  }
  lsum += __shfl_xor(lsum, 1);
  lsum += __shfl_xor(lsum, 2);
  lsum += __shfl_xor(lsum, 4);
  if ((tid & 7) == 0) inv_lds[r] = 1.f / lsum;
  __syncthreads();

  // phase B: PV. 8 waves; wave w owns os column w*16..+15; all 64 n rows.
  const int w = tid >> 6, l = tid & 63, ln = l & 15, kg = l >> 4;
  const u16* B0 = Whtbf + ((size_t)zh*NHID + w*16 + ln)*DD + kg*8;
  f32x4 acc[4];
  #pragma unroll
  for (int ns=0; ns<4; ++ns) acc[ns] = (f32x4){0,0,0,0};

  short8 Pb,Qb,Rb,Sb;
#define K5_LDB(R0,kkv) do { int kc = ((kkv) < 16) ? (kkv) : 0; \
    R0 = *reinterpret_cast<const short8*>(B0 + (size_t)kc*32); } while(0)
#define K5_MM(R0,kkv) do { \
    _Pragma("unroll") \
    for (int ns = 0; ns < 4; ++ns) { \
      int row = ns*16 + ln; int c = (kkv)*4 + kg; \
      short8 af = *reinterpret_cast<const short8*>(&att[row*512 + attsw(c,row)*8]); \
      acc[ns] = __builtin_amdgcn_mfma_f32_16x16x32_bf16(af, R0, acc[ns], 0,0,0); \
    } } while(0)

  K5_LDB(Pb,0); K5_LDB(Qb,1); K5_LDB(Rb,2);
  #pragma unroll 1
  for (int kk = 0; kk < 16; kk += 4) {
    K5_LDB(Sb,kk+3); K5_MM(Pb,kk);
    K5_LDB(Pb,kk+4); K5_MM(Qb,kk+1);
    K5_LDB(Qb,kk+5); K5_MM(Rb,kk+2);
    K5_LDB(Rb,kk+6); K5_MM(Sb,kk+3);
  }
#undef K5_LDB
#undef K5_MM

  #pragma unroll
  for (int ns = 0; ns < 4; ++ns)
    #pragma unroll
    for (int rr = 0; rr < 4; ++rr) {
      int n = ns*16 + kg*4 + rr;
      float inv = inv_lds[n];
      float sv = acc[ns][rr] * inv;
      sv = (sv > 0.f) ? sv : expm1f(sv);
      hcatbf[((size_t)z*DD + n0 + n)*DD + h*NHID + w*16 + ln] = f2bf(sv);
    }
}

// ---------- K6: Wh2tbf[z][o][n] = (hcat @ oW^T + ob)^T, B=oW-panel staged ----------
__global__ __launch_bounds__(256) void k6_wh2(
    const u16* __restrict__ hcatbf, const u16* __restrict__ oWbf, const float* __restrict__ ob,
    u16* __restrict__ Wh2tbf)
{
  __shared__ u16 bp[2][64*64];
  const int tid = threadIdx.x;
  const int w = tid >> 6, l = tid & 63, ln = l & 15, kg = l >> 4;
  const int n0 = blockIdx.x*64 + w*16;
  const int o0 = blockIdx.y*64;
  const int z  = blockIdx.z;
  const int sc = tid & 7, sr = tid >> 3;
  const int sp = sc ^ (sr & 7);
  const int sp2 = sc ^ ((sr+32) & 7);
  const u16* B0 = oWbf + (size_t)o0*DD;
  const u16* Asrc = hcatbf + (size_t)(z*DD + n0 + ln)*DD + kg*8;

  f32x4 acc[4];
  #pragma unroll
  for (int os=0;os<4;++os) acc[os] = (f32x4){0.f,0.f,0.f,0.f};
  short8 aP0, aP1, aQ0, aQ1, sg0, sg1;

  sg0 = *reinterpret_cast<const short8*>(B0 + (size_t)sr*DD + sc*8);
  sg1 = *reinterpret_cast<const short8*>(B0 + (size_t)(sr+32)*DD + sc*8);
  aP0 = *reinterpret_cast<const short8*>(Asrc);
  aP1 = *reinterpret_cast<const short8*>(Asrc + 32);
  *reinterpret_cast<short8*>(&bp[0][sr*64 + sp*8]) = sg0;
  *reinterpret_cast<short8*>(&bp[0][(sr+32)*64 + sp2*8]) = sg1;
  __syncthreads();

  int cur = 0;
  #pragma unroll 1
  for (int s = 0; s < 8; ++s) {
    const int fn = (s+1)*64;
    if (s < 7) {
      sg0 = *reinterpret_cast<const short8*>(B0 + (size_t)sr*DD + fn + sc*8);
      sg1 = *reinterpret_cast<const short8*>(B0 + (size_t)(sr+32)*DD + fn + sc*8);
      aQ0 = *reinterpret_cast<const short8*>(Asrc + fn);
      aQ1 = *reinterpret_cast<const short8*>(Asrc + fn + 32);
    }
    #pragma unroll
    for (int os = 0; os < 4; ++os) {
      int row = os*16 + ln;
      short8 b0 = *reinterpret_cast<const short8*>(&bp[cur][row*64 + ((kg ^ (row&7))<<3)]);
      acc[os] = __builtin_amdgcn_mfma_f32_16x16x32_bf16(aP0, b0, acc[os], 0,0,0);
      short8 b1 = *reinterpret_cast<const short8*>(&bp[cur][row*64 + (((4+kg) ^ (row&7))<<3)]);
      acc[os] = __builtin_amdgcn_mfma_f32_16x16x32_bf16(aP1, b1, acc[os], 0,0,0);
    }
    if (s < 7) {
      *reinterpret_cast<short8*>(&bp[cur^1][sr*64 + sp*8]) = sg0;
      *reinterpret_cast<short8*>(&bp[cur^1][(sr+32)*64 + sp2*8]) = sg1;
      __syncthreads();
      cur ^= 1;
      aP0 = aQ0; aP1 = aQ1;
    }
  }
  #pragma unroll
  for (int os=0; os<4; ++os)
    #pragma unroll
    for (int r=0; r<4; ++r) {
      int o = o0 + os*16 + ln;
      int n = n0 + kg*4 + r;
      Wh2tbf[((size_t)z*WW + o)*DD + n] = f2bf(acc[os][r] + ob[o]);
    }
}

// ---------- K7: e1o/e2o ----------
__global__ __launch_bounds__(256) void k7_eout(
    const u16* __restrict__ hcatbf,
    const float* __restrict__ oahat_i, const float* __restrict__ oahat_j,
    const float* __restrict__ cvec,
    float* __restrict__ e1, float* __restrict__ e2)
{
  int row = blockIdx.x*4 + (threadIdx.x >> 6);
  int lane = threadIdx.x & 63;
  BF8 v8; v8.v = *reinterpret_cast<const short8*>(hcatbf + (size_t)row*DD + lane*8);
  float a1 = 0.f, a2 = 0.f;
  #pragma unroll
  for (int j = 0; j < 8; ++j) {
    float vf = bf2f(v8.u[j]);
    a1 += vf * oahat_i[lane*8 + j];
    a2 += vf * oahat_j[lane*8 + j];
  }
  #pragma unroll
  for (int off = 32; off >= 1; off >>= 1) { a1 += __shfl_xor(a1, off); a2 += __shfl_xor(a2, off); }
  if (lane == 0) { e1[row] = a1 + cvec[8]; e2[row] = a2 + cvec[9]; }
}

// ---------- K8a: out attention PV; 8 waves, factorized softmax -> g f32 (elu) ----------
__global__ __launch_bounds__(512) void k8_pv(
    const float* __restrict__ e1o, const float* __restrict__ e2o,
    const float* __restrict__ M2o, const float* __restrict__ E2p, const float* __restrict__ E2n,
    const u16* __restrict__ Wh2tbf, float* __restrict__ g, int CBv)
{
  __shared__ u16 att[64*512];
  __shared__ float inv_lds[64];
  const int orig = blockIdx.x;
  int nb, z, oh;
  if (CBv >= 8) {
    int xcd = orig & 7;
    int k = orig >> 3;
    nb = k & 7;
    int rest = k >> 3;
    oh = rest & 1;
    z = xcd * (CBv >> 3) + (rest >> 1);
  } else {
    nb = orig & 7;
    int k = orig >> 3;
    z = k >> 1;
    oh = k & 1;
  }
  const int n0 = nb*64;
  const int tid = threadIdx.x;

  const int r = tid >> 3, qd = tid & 7;
  const float e1n = e1o[(size_t)z*DD + n0 + r];
  const float M2 = M2o[z];
  const float s = e1n + M2;
  const float mx = (s > 0.f) ? s : 0.1f*s;
  const float Ap = expf(s - mx);
  const float An = expf(0.1f*s - mx);
  const float thr = -e1n;
  const float* e2r = e2o + (size_t)z*DD + qd*64;
  const float* Epr = E2p + (size_t)z*DD + qd*64;
  const float* Enr = E2n + (size_t)z*DD + qd*64;
  float lsum = 0.f;
  for (int jc = 0; jc < 8; ++jc) {
    int j0 = jc*8;
    F8 e2x, epx, enx;
    e2x.v4[0] = *reinterpret_cast<const float4*>(e2r + j0);
    e2x.v4[1] = *reinterpret_cast<const float4*>(e2r + j0 + 4);
    epx.v4[0] = *reinterpret_cast<const float4*>(Epr + j0);
    epx.v4[1] = *reinterpret_cast<const float4*>(Epr + j0 + 4);
    enx.v4[0] = *reinterpret_cast<const float4*>(Enr + j0);
    enx.v4[1] = *reinterpret_cast<const float4*>(Enr + j0 + 4);
    BF8 pk;
    #pragma unroll
    for (int jj = 0; jj < 8; ++jj) {
      float p = (e2x.f[jj] > thr) ? Ap * epx.f[jj] : An * enx.f[jj];
      lsum += p;
      pk.u[jj] = f2bf(p);
    }
    int c = qd*8 + jc;
    *reinterpret_cast<short8*>(&att[r*512 + attsw(c, r)*8]) = pk.v;
  }
  lsum += __shfl_xor(lsum, 1);
  lsum += __shfl_xor(lsum, 2);
  lsum += __shfl_xor(lsum, 4);
  if ((tid & 7) == 0) inv_lds[r] = 1.f / lsum;
  __syncthreads();

  const int w = tid >> 6, l = tid & 63, ln = l & 15, kg = l >> 4;
  const u16* B0 = Wh2tbf + ((size_t)z*WW + oh*128 + w*16 + ln)*DD + kg*8;
  f32x4 acc[4];
  #pragma unroll
  for (int ns=0; ns<4; ++ns) acc[ns] = (f32x4){0,0,0,0};

  short8 Pb,Qb,Rb,Sb;
#define K8_LDB(R0,kkv) do { int kc = ((kkv) < 16) ? (kkv) : 0; \
    R0 = *reinterpret_cast<const short8*>(B0 + (size_t)kc*32); } while(0)
#define K8_MM(R0,kkv) do { \
    _Pragma("unroll") \
    for (int ns = 0; ns < 4; ++ns) { \
      int row = ns*16 + ln; int c = (kkv)*4 + kg; \
      short8 af = *reinterpret_cast<const short8*>(&att[row*512 + attsw(c,row)*8]); \
      acc[ns] = __builtin_amdgcn_mfma_f32_16x16x32_bf16(af, R0, acc[ns], 0,0,0); \
    } } while(0)

  K8_LDB(Pb,0); K8_LDB(Qb,1); K8_LDB(Rb,2);
  #pragma unroll 1
  for (int kk = 0; kk < 16; kk += 4) {
    K8_LDB(Sb,kk+3); K8_MM(Pb,kk);
    K8_LDB(Pb,kk+4); K8_MM(Qb,kk+1);
    K8_LDB(Qb,kk+5); K8_MM(Rb,kk+2);
    K8_LDB(Rb,kk+6); K8_MM(Sb,kk+3);
  }
#undef K8_LDB
#undef K8_MM

  #pragma unroll
  for (int ns = 0; ns < 4; ++ns)
    #pragma unroll
    for (int rr = 0; rr < 4; ++rr) {
      int n = ns*16 + kg*4 + rr;
      float inv = inv_lds[n];
      float val = acc[ns][rr] * inv;
      val = (val > 0.f) ? val : expm1f(val);    // elu
      g[((size_t)z*DD + n0 + n)*WW + oh*128 + w*16 + ln] = val;
    }
}

// ---------- K8b: row log_softmax over o(256) -> gaty bf16 ----------
__global__ __launch_bounds__(256) void k8_lsm(
    const float* __restrict__ g, u16* __restrict__ gatybf)
{
  int row = blockIdx.x*4 + (threadIdx.x >> 6);
  int lane = threadIdx.x & 63;
  const float* gr = g + (size_t)row*WW;
  float v0 = gr[lane], v1 = gr[lane+64], v2 = gr[lane+128], v3 = gr[lane+192];
  float mx = fmaxf(fmaxf(v0,v1), fmaxf(v2,v3));
  #pragma unroll
  for (int off = 32; off >= 1; off >>= 1) mx = fmaxf(mx, __shfl_xor(mx, off));
  float sm = expf(v0-mx) + expf(v1-mx) + expf(v2-mx) + expf(v3-mx);
  #pragma unroll
  for (int off = 32; off >= 1; off >>= 1) sm += __shfl_xor(sm, off);
  float lg = mx + logf(sm);
  u16* go = gatybf + (size_t)row*WW;
  go[lane]     = f2bf(v0 - lg);
  go[lane+64]  = f2bf(v1 - lg);
  go[lane+128] = f2bf(v2 - lg);
  go[lane+192] = f2bf(v3 - lg);
}

// ---------- K9: out = gaty^T @ pW^T + pb ----------
__global__ __launch_bounds__(256) void k9_proj(
    const u16* __restrict__ gatybf, const u16* __restrict__ pWbf, const float* __restrict__ pb,
    int zb, float* __restrict__ out0)
{
  __shared__ u16 gt[64*40];
  const int t0 = blockIdx.x*64, d0 = blockIdx.y*64, z = blockIdx.z;
  const int tid = threadIdx.x;
  const int w = tid >> 6, l = tid & 63, ln = l & 15, kg = l >> 4;
  const int el = tid >> 3, t8 = tid & 7;
  f32x4 acc[4];
  #pragma unroll
  for (int os=0;os<4;++os) acc[os] = (f32x4){0.f,0.f,0.f,0.f};
  for (int e0 = 0; e0 < DD; e0 += 32) {
    __syncthreads();
    BF8 g8;
    g8.v = *reinterpret_cast<const short8*>(gatybf + ((size_t)z*DD + e0 + el)*WW + t0 + t8*8);
    #pragma unroll
    for (int j = 0; j < 8; ++j) gt[(t8*8 + j)*40 + el] = g8.u[j];
    __syncthreads();
    short8 a = *reinterpret_cast<const short8*>(&gt[(w*16 + ln)*40 + kg*8]);
    #pragma unroll
    for (int os = 0; os < 4; ++os) {
      short8 b = *reinterpret_cast<const short8*>(pWbf + (size_t)(d0 + os*16 + ln)*DD + e0 + kg*8);
      acc[os] = __builtin_amdgcn_mfma_f32_16x16x32_bf16(a, b, acc[os], 0,0,0);
    }
  }
  #pragma unroll
  for (int os=0; os<4; ++os)
    #pragma unroll
    for (int rr=0; rr<4; ++rr) {
      int t = t0 + w*16 + kg*4 + rr;
      int d = d0 + os*16 + ln;
      out0[((size_t)(zb+z)*WW + t)*DD + d] = acc[os][rr] + pb[d];
    }
}

extern "C" void kernel_launch(void* const* d_in, const int* in_sizes, int n_in,
                              void* d_out, int out_size, void* d_ws, size_t ws_size,
                              hipStream_t stream)
{
  const float* x   = (const float*)d_in[0];
  const float* qW  = (const float*)d_in[1];
  const float* qb  = (const float*)d_in[2];
  const float* kW  = (const float*)d_in[3];
  const float* kb  = (const float*)d_in[4];
  const float* vW  = (const float*)d_in[5];
  const float* vb  = (const float*)d_in[6];
  const float* hW  = (const float*)d_in[7];
  const float* hb  = (const float*)d_in[8];
  const float* hai = (const float*)d_in[9];
  const float* haib= (const float*)d_in[10];
  const float* haj = (const float*)d_in[11];
  const float* hajb= (const float*)d_in[12];
  const float* oW  = (const float*)d_in[13];
  const float* ob  = (const float*)d_in[14];
  const float* oai = (const float*)d_in[15];
  const float* oaib= (const float*)d_in[16];
  const float* oaj = (const float*)d_in[17];
  const float* oajb= (const float*)d_in[18];
  const float* pW  = (const float*)d_in[19];
  const float* pb  = (const float*)d_in[20];

  float* out0 = (float*)d_out;                   // [B,W,D] f32
  float* adjo = out0 + (size_t)BB*WW*DD;         // [B,D,D] f32

  // static region (float offsets)
  float* ws      = (float*)d_ws;
  u16*   Wt      = (u16*)(ws + 0);           // 1,179,648 f
  u16*   hWbf    = (u16*)(ws + 1179648);     //    65,536 f
  u16*   oWbf    = (u16*)(ws + 1245184);     //    65,536 f
  u16*   pWbf    = (u16*)(ws + 1310720);     //   131,072 f
  float* ahat_i  = ws + 1441792;
  float* ahat_j  = ws + 1442816;
  float* oahat_i = ws + 1443840;
  float* oahat_j = ws + 1444352;
  float* cvec    = ws + 1444864;
  float* e1h     = ws + 1444880;             //    65,536 f (CB=32 max)
  float* e2h     = ws + 1510416;
  float* e1o     = ws + 1575952;             //    16,384 f
  float* e2o     = ws + 1592336;
  float* M2h     = ws + 1608720;             //       128 f
  float* E2hp    = ws + 1608848;             //    65,536 f
  float* E2hn    = ws + 1674384;             //    65,536 f
  float* M2o     = ws + 1739920;             //        32 f
  float* E2op    = ws + 1739952;             //    16,384 f
  float* E2on    = ws + 1756336;             //    16,384 f
  const size_t X0 = 1772720;                 // dynamic region start

  // per-CB dynamic: xpad 66,048 + vbf 65,536 + qbf 65,536 + kbf 65,536 + Whtbf 131,072 = 393,728 f
  int CB = 4;
  {
    const int cand[3] = {32, 16, 8};
    for (int i = 0; i < 3; ++i) {
      size_t need = (X0 + (size_t)cand[i]*393728) * 4;
      if (need <= ws_size) { CB = cand[i]; break; }
    }
  }

  u16* xpad   = (u16*)(ws + X0);                        // CB*66,048 f  ([z][258][512])
  u16* vbf    = (u16*)(ws + X0 + (size_t)CB*66048);     // CB*65,536 f
  u16* qbf    = (u16*)(ws + X0 + (size_t)CB*131584);    // CB*65,536 f
  u16* kbf    = (u16*)(ws + X0 + (size_t)CB*197120);    // CB*65,536 f
  u16* Whtbf  = (u16*)(ws + X0 + (size_t)CB*262656);    // CB*131,072 f
  // overlays (lifetimes: xpad dead after k1; vbf dead after k4; qbf,kbf dead after k2;
  // hcatbf dead after k7; Whtbf dead after k5)
  u16*   hcatbf = (u16*)(ws + X0);                      // over xpad+vbf
  float* g      = (float*)(ws + X0);                    // over hcatbf region (k8 phase)
  u16*   gatybf = (u16*)(ws + X0 + (size_t)CB*131584);  // over qbf
  u16*   Wh2tbf = (u16*)(ws + X0 + (size_t)CB*197120);  // over kbf

  kprep_w<<<dim3((3*DD*DD + 255)/256), 256, 0, stream>>>(qW, kW, vW, Wt);
  kcvt<<<dim3((NHEADS*NHID*WW + 255)/256), 256, 0, stream>>>(hW, hWbf, NHEADS*NHID*WW);
  kcvt<<<dim3((WW*DD + 255)/256), 256, 0, stream>>>(oW, oWbf, WW*DD);
  kcvt<<<dim3((DD*DD + 255)/256), 256, 0, stream>>>(pW, pWbf, DD*DD);
  kprep_a<<<dim3(13), 256, 0, stream>>>(hW, hai, haib, haj, hajb, hb,
                                        oW, oai, oaib, oaj, oajb, ob,
                                        ahat_i, ahat_j, oahat_i, oahat_j, cvec);

  for (int zb = 0; zb < BB; zb += CB) {
    int nrow8 = CB*258*64;
    kprep_x  <<<dim3((nrow8 + 255)/256), 256, 0, stream>>>(x, zb, nrow8, xpad);
    k1_mfma  <<<dim3(DD/64, WW/128, CB), 256, 0, stream>>>(xpad, Wt, qb, kb, vb, qbf, kbf, vbf);
    k2_adj   <<<dim3(DD/64, DD/64, CB), 256, 0, stream>>>(qbf, kbf, zb, adjo);
    k3_wh    <<<dim3(DD/64, NHID/64, CB*NHEADS), 256, 0, stream>>>(vbf, hWbf, hb, Whtbf);
    k4_eheads<<<dim3(CB*NHEADS*DD/4), 256, 0, stream>>>(vbf, ahat_i, ahat_j, cvec, e1h, e2h);
    kexp2    <<<dim3(CB*NHEADS), 256, 0, stream>>>(e2h, M2h, E2hp, E2hn);
    k5_attn  <<<dim3(32*CB), 512, 0, stream>>>(e1h, e2h, M2h, E2hp, E2hn, Whtbf, hcatbf, CB*NHEADS);
    k6_wh2   <<<dim3(DD/64, WW/64, CB), 256, 0, stream>>>(hcatbf, oWbf, ob, Wh2tbf);
    k7_eout  <<<dim3(CB*DD/4), 256, 0, stream>>>(hcatbf, oahat_i, oahat_j, cvec, e1o, e2o);
    kexp2    <<<dim3(CB), 256, 0, stream>>>(e2o, M2o, E2op, E2on);
    k8_pv    <<<dim3(16*CB), 512, 0, stream>>>(e1o, e2o, M2o, E2op, E2on, Wh2tbf, g, CB);
    k8_lsm   <<<dim3(CB*128), 256, 0, stream>>>(g, gatybf);
    k9_proj  <<<dim3(WW/64, DD/64, CB), 256, 0, stream>>>(gatybf, pWbf, pb, zb, out0);
  }
}

// Round 16
// 316.140 us; speedup vs baseline: 1.0503x; 1.0074x over previous
//
#include <hip/hip_runtime.h>
#include <math.h>

typedef unsigned short u16;
typedef __attribute__((ext_vector_type(8))) short short8;
typedef __attribute__((ext_vector_type(4))) float f32x4;

#define BB 32
#define WW 256
#define DD 512
#define NHEADS 4
#define NHID 128

__device__ __forceinline__ u16 f2bf(float f) {
  union { float f; unsigned int i; } x; x.f = f;
  unsigned int i = x.i;
  i += 0x7fffu + ((i >> 16) & 1u);
  return (u16)(i >> 16);
}
__device__ __forceinline__ float bf2f(u16 u) {
  union { float f; unsigned int i; } x; x.i = ((unsigned int)u) << 16; return x.f;
}

union BF8 { short8 v; u16 u[8]; };
union BF4 { ushort4 v; u16 u[4]; };
union F8 { float4 v4[2]; float f[8]; };

// ---------- prep (once) ----------
__global__ __launch_bounds__(256) void kprep_w(
    const float* __restrict__ qW, const float* __restrict__ kW, const float* __restrict__ vW,
    u16* __restrict__ Wt)
{
  int idx = blockIdx.x*256 + threadIdx.x;     // (c, o, i)
  if (idx >= 3*DD*DD) return;
  int c = idx >> 18;
  int oi = idx & (DD*DD - 1);
  int i = oi & (DD-1);
  int o = oi >> 9;
  const float* W = (c==0) ? qW : (c==1) ? kW : vW;
  float w0 = W[oi*3+0], w1 = W[oi*3+1], w2 = W[oi*3+2];
  Wt[((size_t)(c*3+0)*DD + o)*DD + i] = f2bf(w0);
  Wt[((size_t)(c*3+1)*DD + o)*DD + i] = f2bf(w1);
  Wt[((size_t)(c*3+2)*DD + o)*DD + i] = f2bf(w2);
}

__global__ __launch_bounds__(256) void kcvt(const float* __restrict__ s, u16* __restrict__ d, int n) {
  int i = blockIdx.x*256 + threadIdx.x;
  if (i < n) d[i] = f2bf(s[i]);
}

__global__ __launch_bounds__(256) void kprep_a(
    const float* __restrict__ hW, const float* __restrict__ hai, const float* __restrict__ haib,
    const float* __restrict__ haj, const float* __restrict__ hajb,
    const float* __restrict__ hb,
    const float* __restrict__ oW, const float* __restrict__ oai, const float* __restrict__ oaib,
    const float* __restrict__ oaj, const float* __restrict__ oajb,
    const float* __restrict__ ob,
    float* __restrict__ ahat_i, float* __restrict__ ahat_j,
    float* __restrict__ oahat_i, float* __restrict__ oahat_j,
    float* __restrict__ cvec)
{
  int idx = blockIdx.x*256 + threadIdx.x;
  if (idx < 1024) {
    int h = idx >> 8, f = idx & 255;
    float s = 0.f;
    for (int o = 0; o < NHID; ++o) s += hW[((size_t)h*NHID + o)*WW + f] * hai[h*NHID + o];
    ahat_i[idx] = s;
  } else if (idx < 2048) {
    int t = idx - 1024; int h = t >> 8, f = t & 255;
    float s = 0.f;
    for (int o = 0; o < NHID; ++o) s += hW[((size_t)h*NHID + o)*WW + f] * haj[h*NHID + o];
    ahat_j[t] = s;
  } else if (idx < 2560) {
    int f = idx - 2048;
    float s = 0.f;
    for (int o = 0; o < WW; ++o) s += oW[(size_t)o*DD + f] * oai[o];
    oahat_i[f] = s;
  } else if (idx < 3072) {
    int f = idx - 2560;
    float s = 0.f;
    for (int o = 0; o < WW; ++o) s += oW[(size_t)o*DD + f] * oaj[o];
    oahat_j[f] = s;
  } else if (idx < 3082) {
    int t = idx - 3072;
    if (t < 4) {
      float s = 0.f;
      for (int o = 0; o < NHID; ++o) s += hb[t*NHID + o]*hai[t*NHID + o];
      cvec[t] = s + haib[t];
    } else if (t < 8) {
      int h = t - 4; float s = 0.f;
      for (int o = 0; o < NHID; ++o) s += hb[h*NHID + o]*haj[h*NHID + o];
      cvec[t] = s + hajb[h];
    } else if (t == 8) {
      float s = 0.f;
      for (int o = 0; o < WW; ++o) s += ob[o]*oai[o];
      cvec[8] = s + oaib[0];
    } else {
      float s = 0.f;
      for (int o = 0; o < WW; ++o) s += ob[o]*oaj[o];
      cvec[9] = s + oajb[0];
    }
  }
}

// x f32 -> xpad bf16 [z][258][512] with zero halo rows (t=-1, t=256)
__global__ __launch_bounds__(256) void kprep_x(
    const float* __restrict__ x, int zb, int nrow8, u16* __restrict__ xpad)
{
  int idx8 = blockIdx.x*256 + threadIdx.x;
  if (idx8 >= nrow8) return;
  int i8 = idx8 & 63;
  int rowg = idx8 >> 6;                       // z*258 + r
  int z = rowg / 258, r = rowg - z*258;
  int t = r - 1;
  BF8 o8;
  if (t >= 0 && t < WW) {
    const float* src = x + ((size_t)(zb+z)*WW + t)*DD + i8*8;
    float4 v0 = *reinterpret_cast<const float4*>(src);
    float4 v1 = *reinterpret_cast<const float4*>(src + 4);
    o8.u[0]=f2bf(v0.x); o8.u[1]=f2bf(v0.y); o8.u[2]=f2bf(v0.z); o8.u[3]=f2bf(v0.w);
    o8.u[4]=f2bf(v1.x); o8.u[5]=f2bf(v1.y); o8.u[6]=f2bf(v1.z); o8.u[7]=f2bf(v1.w);
  } else {
    #pragma unroll
    for (int j = 0; j < 8; ++j) o8.u[j] = 0;
  }
  *reinterpret_cast<short8*>(xpad + (size_t)rowg*DD + i8*8) = o8.v;
}

// kexp2: per row-group (512 e2 values): M2 = max, E2p = exp(e2-M2), E2n = exp(0.1(e2-M2))
__global__ __launch_bounds__(256) void kexp2(
    const float* __restrict__ e2, float* __restrict__ M2,
    float* __restrict__ E2p, float* __restrict__ E2n)
{
  __shared__ float s4[4];
  const int zh = blockIdx.x, tid = threadIdx.x;
  float v0 = e2[(size_t)zh*DD + tid], v1 = e2[(size_t)zh*DD + 256 + tid];
  float m = fmaxf(v0, v1);
  #pragma unroll
  for (int off=32; off>=1; off>>=1) m = fmaxf(m, __shfl_xor(m, off));
  if ((tid & 63) == 0) s4[tid >> 6] = m;
  __syncthreads();
  m = fmaxf(fmaxf(s4[0], s4[1]), fmaxf(s4[2], s4[3]));
  if (tid == 0) M2[zh] = m;
  E2p[(size_t)zh*DD + tid]       = expf(v0 - m);
  E2p[(size_t)zh*DD + 256 + tid] = expf(v1 - m);
  E2n[(size_t)zh*DD + tid]       = expf(0.1f*(v0 - m));
  E2n[(size_t)zh*DD + 256 + tid] = expf(0.1f*(v1 - m));
}

// ---------- K1: conv via MFMA; 64o x 128t tile; A triple-buffered (depth-2 prefetch) ----------
__global__ __launch_bounds__(256) void k1_mfma(
    const u16* __restrict__ xpad, const u16* __restrict__ Wt,
    const float* __restrict__ qb, const float* __restrict__ kb, const float* __restrict__ vb,
    u16* __restrict__ qbf, u16* __restrict__ kbf, u16* __restrict__ vbf)
{
  __shared__ u16 bt[2][130*64];
  const int tid = threadIdx.x;
  const int w  = tid >> 6;
  const int l  = tid & 63;
  const int ln = l & 15;
  const int kg = l >> 4;
  const int og = blockIdx.x * 64 + w * 16;
  const int t0 = blockIdx.y * 128;
  const int z  = blockIdx.z;

  const u16* A0 = Wt + (size_t)(og + ln)*DD + kg*8;
  const u16* Xb = xpad + ((size_t)z*258 + t0)*DD;

  f32x4 acc[3][8];
  #pragma unroll
  for (int c=0;c<3;++c)
    #pragma unroll
    for (int ts=0;ts<8;++ts) acc[c][ts] = (f32x4){0.f,0.f,0.f,0.f};

  short8 ArP[9], ArQ[9], ArR[9];
  short8 sg0, sg1, sg2, sg3, sg4;
  const int ccw = tid & 7;
  const int rs = tid >> 3;

#define K1_LOADX(i0v) do { \
    sg0 = *reinterpret_cast<const short8*>(Xb + (size_t)rs*DD + (i0v) + ccw*8); \
    sg1 = *reinterpret_cast<const short8*>(Xb + (size_t)(rs+32)*DD + (i0v) + ccw*8); \
    sg2 = *reinterpret_cast<const short8*>(Xb + (size_t)(rs+64)*DD + (i0v) + ccw*8); \
    sg3 = *reinterpret_cast<const short8*>(Xb + (size_t)(rs+96)*DD + (i0v) + ccw*8); \
    if (tid < 16) sg4 = *reinterpret_cast<const short8*>(Xb + (size_t)(rs+128)*DD + (i0v) + ccw*8); \
  } while(0)

#define K1_WRITEX(bufv) do { \
    *reinterpret_cast<short8*>(&bt[bufv][rs*64 + ((ccw^(rs&7))<<3)]) = sg0; \
    *reinterpret_cast<short8*>(&bt[bufv][(rs+32)*64 + ((ccw^((rs+32)&7))<<3)]) = sg1; \
    *reinterpret_cast<short8*>(&bt[bufv][(rs+64)*64 + ((ccw^((rs+64)&7))<<3)]) = sg2; \
    *reinterpret_cast<short8*>(&bt[bufv][(rs+96)*64 + ((ccw^((rs+96)&7))<<3)]) = sg3; \
    if (tid < 16) *reinterpret_cast<short8*>(&bt[bufv][(rs+128)*64 + ((ccw^((rs+128)&7))<<3)]) = sg4; \
  } while(0)

#define K1_LOADA(Abuf, i0v, khv) do { \
    _Pragma("unroll") \
    for (int c = 0; c < 3; ++c) { \
      _Pragma("unroll") \
      for (int tap = 0; tap < 3; ++tap) \
        Abuf[c*3+tap] = *reinterpret_cast<const short8*>(A0 + (size_t)(c*3+tap)*DD*DD + (i0v) + (khv)*32); \
    } \
  } while(0)

#define K1_MFMAS(Abuf, khv) do { \
    _Pragma("unroll") \
    for (int tap = 0; tap < 3; ++tap) { \
      _Pragma("unroll") \
      for (int ts = 0; ts < 8; ++ts) { \
        int row = ts*16 + ln + tap; \
        short8 bfr = *reinterpret_cast<const short8*>(&bt[cur][row*64 + ((((khv)*4+kg) ^ (row&7))<<3)]); \
        acc[0][ts] = __builtin_amdgcn_mfma_f32_16x16x32_bf16(Abuf[0*3+tap], bfr, acc[0][ts], 0,0,0); \
        acc[1][ts] = __builtin_amdgcn_mfma_f32_16x16x32_bf16(Abuf[1*3+tap], bfr, acc[1][ts], 0,0,0); \
        acc[2][ts] = __builtin_amdgcn_mfma_f32_16x16x32_bf16(Abuf[2*3+tap], bfr, acc[2][ts], 0,0,0); \
      } \
    } \
  } while(0)

// One full i0 phase: use (Ua=kh0, Ub=kh1); load next phase's (La=kh0, Lb=kh1).
#define K1_PHASE(Ua, Ub, La, Lb, p) do { \
    const int i0n = ((p) < 7) ? ((p)+1)*64 : 0; \
    if ((p) < 7) K1_LOADX(i0n); \
    K1_LOADA(La, i0n, 0); \
    K1_MFMAS(Ua, 0); \
    K1_LOADA(Lb, i0n, 1); \
    K1_MFMAS(Ub, 1); \
    if ((p) < 7) { K1_WRITEX(cur ^ 1); __syncthreads(); cur ^= 1; } \
  } while(0)

  K1_LOADX(0);
  K1_LOADA(ArP, 0, 0);
  K1_LOADA(ArQ, 0, 1);
  K1_WRITEX(0);
  __syncthreads();

  int cur = 0;
  K1_PHASE(ArP, ArQ, ArR, ArP, 0);
  K1_PHASE(ArR, ArP, ArQ, ArR, 1);
  K1_PHASE(ArQ, ArR, ArP, ArQ, 2);
  K1_PHASE(ArP, ArQ, ArR, ArP, 3);
  K1_PHASE(ArR, ArP, ArQ, ArR, 4);
  K1_PHASE(ArQ, ArR, ArP, ArQ, 5);
  K1_PHASE(ArP, ArQ, ArR, ArP, 6);
  K1_PHASE(ArR, ArP, ArQ, ArR, 7);

#undef K1_LOADX
#undef K1_WRITEX
#undef K1_LOADA
#undef K1_MFMAS
#undef K1_PHASE

  #pragma unroll
  for (int ts=0; ts<8; ++ts) {
    int tg = t0 + ts*16 + ln;
    #pragma unroll
    for (int r=0;r<4;++r) {
      int o = og + kg*4 + r;
      size_t oi = (size_t)(z*DD + o)*WW + tg;
      qbf[oi] = f2bf(acc[0][ts][r] + qb[o]);
      kbf[oi] = f2bf(acc[1][ts][r] + kb[o]);
      vbf[oi] = f2bf(acc[2][ts][r] + vb[o]);
    }
  }
}

// ---------- K2: adj = sigmoid(q.kT * scale), B=k-panel staged ----------
__global__ __launch_bounds__(256) void k2_adj(
    const u16* __restrict__ qbf, const u16* __restrict__ kbf, int zb, float* __restrict__ adjo)
{
  __shared__ u16 bp[2][64*64];
  const int tid = threadIdx.x;
  const int w = tid >> 6, l = tid & 63, ln = l & 15, kg = l >> 4;
  const int d0 = blockIdx.x*64 + w*16;
  const int e0 = blockIdx.y*64;
  const int z  = blockIdx.z;
  const int sc = tid & 7, sr = tid >> 3;
  const int sp = sc ^ (sr & 7);
  const int sp2 = sc ^ ((sr+32) & 7);
  const u16* B0 = kbf + (size_t)(z*DD + e0)*WW;
  const u16* Asrc = qbf + (size_t)(z*DD + d0 + ln)*WW + kg*8;

  f32x4 acc[4];
  #pragma unroll
  for (int es=0;es<4;++es) acc[es] = (f32x4){0.f,0.f,0.f,0.f};
  short8 aP0, aP1, aQ0, aQ1, sg0, sg1;

  sg0 = *reinterpret_cast<const short8*>(B0 + (size_t)sr*WW + sc*8);
  sg1 = *reinterpret_cast<const short8*>(B0 + (size_t)(sr+32)*WW + sc*8);
  aP0 = *reinterpret_cast<const short8*>(Asrc);
  aP1 = *reinterpret_cast<const short8*>(Asrc + 32);
  *reinterpret_cast<short8*>(&bp[0][sr*64 + sp*8]) = sg0;
  *reinterpret_cast<short8*>(&bp[0][(sr+32)*64 + sp2*8]) = sg1;
  __syncthreads();

  int cur = 0;
  #pragma unroll 1
  for (int s = 0; s < 4; ++s) {
    const int fn = (s+1)*64;
    if (s < 3) {
      sg0 = *reinterpret_cast<const short8*>(B0 + (size_t)sr*WW + fn + sc*8);
      sg1 = *reinterpret_cast<const short8*>(B0 + (size_t)(sr+32)*WW + fn + sc*8);
      aQ0 = *reinterpret_cast<const short8*>(Asrc + fn);
      aQ1 = *reinterpret_cast<const short8*>(Asrc + fn + 32);
    }
    #pragma unroll
    for (int es = 0; es < 4; ++es) {
      int row = es*16 + ln;
      short8 b0 = *reinterpret_cast<const short8*>(&bp[cur][row*64 + ((kg ^ (row&7))<<3)]);
      acc[es] = __builtin_amdgcn_mfma_f32_16x16x32_bf16(aP0, b0, acc[es], 0,0,0);
      short8 b1 = *reinterpret_cast<const short8*>(&bp[cur][row*64 + (((4+kg) ^ (row&7))<<3)]);
      acc[es] = __builtin_amdgcn_mfma_f32_16x16x32_bf16(aP1, b1, acc[es], 0,0,0);
    }
    if (s < 3) {
      *reinterpret_cast<short8*>(&bp[cur^1][sr*64 + sp*8]) = sg0;
      *reinterpret_cast<short8*>(&bp[cur^1][(sr+32)*64 + sp2*8]) = sg1;
      __syncthreads();
      cur ^= 1;
      aP0 = aQ0; aP1 = aQ1;
    }
  }
  const float scale = 0.044194173824159216f;
  #pragma unroll
  for (int es=0; es<4; ++es)
    #pragma unroll
    for (int r=0; r<4; ++r) {
      float sig = 1.f/(1.f + expf(-acc[es][r]*scale));
      adjo[((size_t)(zb+z)*DD + d0 + kg*4 + r)*DD + e0 + es*16 + ln] = sig;
    }
}

// ---------- K3: Whtbf[zh][o][n] = (v @ hW^T + hb)^T, B=hW-panel staged ----------
__global__ __launch_bounds__(256) void k3_wh(
    const u16* __restrict__ vbf, const u16* __restrict__ hWbf, const float* __restrict__ hb,
    u16* __restrict__ Whtbf)
{
  __shared__ u16 bp[2][64*64];
  const int tid = threadIdx.x;
  const int w = tid >> 6, l = tid & 63, ln = l & 15, kg = l >> 4;
  const int n0 = blockIdx.x*64 + w*16;
  const int o0 = blockIdx.y*64;
  const int zh = blockIdx.z, z = zh >> 2, h = zh & 3;
  const int sc = tid & 7, sr = tid >> 3;
  const int sp = sc ^ (sr & 7);
  const int sp2 = sc ^ ((sr+32) & 7);
  const u16* B0 = hWbf + (size_t)(h*NHID + o0)*WW;
  const u16* Asrc = vbf + (size_t)(z*DD + n0 + ln)*WW + kg*8;

  f32x4 acc[4];
  #pragma unroll
  for (int os=0;os<4;++os) acc[os] = (f32x4){0.f,0.f,0.f,0.f};
  short8 aP0, aP1, aQ0, aQ1, sg0, sg1;

  sg0 = *reinterpret_cast<const short8*>(B0 + (size_t)sr*WW + sc*8);
  sg1 = *reinterpret_cast<const short8*>(B0 + (size_t)(sr+32)*WW + sc*8);
  aP0 = *reinterpret_cast<const short8*>(Asrc);
  aP1 = *reinterpret_cast<const short8*>(Asrc + 32);
  *reinterpret_cast<short8*>(&bp[0][sr*64 + sp*8]) = sg0;
  *reinterpret_cast<short8*>(&bp[0][(sr+32)*64 + sp2*8]) = sg1;
  __syncthreads();

  int cur = 0;
  #pragma unroll 1
  for (int s = 0; s < 4; ++s) {
    const int fn = (s+1)*64;
    if (s < 3) {
      sg0 = *reinterpret_cast<const short8*>(B0 + (size_t)sr*WW + fn + sc*8);
      sg1 = *reinterpret_cast<const short8*>(B0 + (size_t)(sr+32)*WW + fn + sc*8);
      aQ0 = *reinterpret_cast<const short8*>(Asrc + fn);
      aQ1 = *reinterpret_cast<const short8*>(Asrc + fn + 32);
    }
    #pragma unroll
    for (int os = 0; os < 4; ++os) {
      int row = os*16 + ln;
      short8 b0 = *reinterpret_cast<const short8*>(&bp[cur][row*64 + ((kg ^ (row&7))<<3)]);
      acc[os] = __builtin_amdgcn_mfma_f32_16x16x32_bf16(aP0, b0, acc[os], 0,0,0);
      short8 b1 = *reinterpret_cast<const short8*>(&bp[cur][row*64 + (((4+kg) ^ (row&7))<<3)]);
      acc[os] = __builtin_amdgcn_mfma_f32_16x16x32_bf16(aP1, b1, acc[os], 0,0,0);
    }
    if (s < 3) {
      *reinterpret_cast<short8*>(&bp[cur^1][sr*64 + sp*8]) = sg0;
      *reinterpret_cast<short8*>(&bp[cur^1][(sr+32)*64 + sp2*8]) = sg1;
      __syncthreads();
      cur ^= 1;
      aP0 = aQ0; aP1 = aQ1;
    }
  }
  #pragma unroll
  for (int os=0; os<4; ++os)
    #pragma unroll
    for (int r=0; r<4; ++r) {
      int o = o0 + os*16 + ln;
      int n = n0 + kg*4 + r;
      Whtbf[((size_t)zh*NHID + o)*DD + n] = f2bf(acc[os][r] + hb[h*NHID + o]);
    }
}

// ---------- K4: e1h/e2h ----------
__global__ __launch_bounds__(256) void k4_eheads(
    const u16* __restrict__ vbf,
    const float* __restrict__ ahat_i, const float* __restrict__ ahat_j,
    const float* __restrict__ cvec,
    float* __restrict__ e1, float* __restrict__ e2)
{
  int row = blockIdx.x*4 + (threadIdx.x >> 6);   // row = zh*512 + n
  int lane = threadIdx.x & 63;
  int zh = row >> 9, n = row & 511;
  int z = zh >> 2, h = zh & 3;
  BF4 v4; v4.v = *reinterpret_cast<const ushort4*>(vbf + ((size_t)(z*DD + n))*WW + lane*4);
  const float* aif = ahat_i + h*WW + lane*4;
  const float* ajf = ahat_j + h*WW + lane*4;
  float a1 = 0.f, a2 = 0.f;
  #pragma unroll
  for (int j = 0; j < 4; ++j) {
    float vf = bf2f(v4.u[j]);
    a1 += vf * aif[j];
    a2 += vf * ajf[j];
  }
  #pragma unroll
  for (int off = 32; off >= 1; off >>= 1) { a1 += __shfl_xor(a1, off); a2 += __shfl_xor(a2, off); }
  if (lane == 0) { e1[row] = a1 + cvec[h]; e2[row] = a2 + cvec[4+h]; }
}

// swizzled att chunk index
__device__ __forceinline__ int attsw(int c, int row) {
  return c ^ ((c >> 3) & 7) ^ (row & 7);
}

// ---- shared phase-A/B macros (pipelined) ----
#define PA_LD(Ea,Pa,Na,jcv) do { int j0=(jcv)*8; \
    Ea.v4[0]=*reinterpret_cast<const float4*>(e2r+j0); Ea.v4[1]=*reinterpret_cast<const float4*>(e2r+j0+4); \
    Pa.v4[0]=*reinterpret_cast<const float4*>(Epr+j0); Pa.v4[1]=*reinterpret_cast<const float4*>(Epr+j0+4); \
    Na.v4[0]=*reinterpret_cast<const float4*>(Enr+j0); Na.v4[1]=*reinterpret_cast<const float4*>(Enr+j0+4); } while(0)
#define PA_PROC(att, Ea,Pa,Na,jcv) do { BF8 pk; \
    _Pragma("unroll") \
    for (int jj=0;jj<8;++jj){ float p=(Ea.f[jj]>thr)?Ap*Pa.f[jj]:An*Na.f[jj]; lsum+=p; pk.u[jj]=f2bf(p);} \
    int c=qd*8+(jcv); *reinterpret_cast<short8*>(&att[r*512+attsw(c,r)*8])=pk.v; } while(0)

// ---------- K5: heads attention; 8 waves, factorized softmax, pipelined ----------
__global__ __launch_bounds__(512) void k5_attn(
    const float* __restrict__ e1h, const float* __restrict__ e2h,
    const float* __restrict__ M2h, const float* __restrict__ E2p, const float* __restrict__ E2n,
    const u16* __restrict__ Whtbf, u16* __restrict__ hcatbf, int nzh)
{
  __shared__ u16 att[64*512];
  __shared__ float inv_lds[64];
  const int orig = blockIdx.x;
  const int xcd = orig & 7;
  const int k = orig >> 3;
  const int nb = k & 7;
  const int zh = xcd * (nzh >> 3) + (k >> 3);
  const int z = zh >> 2, h = zh & 3;
  const int n0 = nb*64;
  const int tid = threadIdx.x;

  // phase A: factorized softmax (double-buffered loads)
  const int r = tid >> 3, qd = tid & 7;
  const float e1n = e1h[(size_t)zh*DD + n0 + r];
  const float M2 = M2h[zh];
  const float s = e1n + M2;
  const float mx = (s > 0.f) ? s : 0.1f*s;
  const float Ap = expf(s - mx);
  const float An = expf(0.1f*s - mx);
  const float thr = -e1n;
  const float* e2r = e2h + (size_t)zh*DD + qd*64;
  const float* Epr = E2p + (size_t)zh*DD + qd*64;
  const float* Enr = E2n + (size_t)zh*DD + qd*64;
  float lsum = 0.f;
  {
    F8 e2a,epa,ena, e2b,epb,enb;
    PA_LD(e2a,epa,ena,0);
    PA_LD(e2b,epb,enb,1);
    PA_PROC(att, e2a,epa,ena,0);
    PA_LD(e2a,epa,ena,2);
    PA_PROC(att, e2b,epb,enb,1);
    PA_LD(e2b,epb,enb,3);
    PA_PROC(att, e2a,epa,ena,2);
    PA_LD(e2a,epa,ena,4);
    PA_PROC(att, e2b,epb,enb,3);
    PA_LD(e2b,epb,enb,5);
    PA_PROC(att, e2a,epa,ena,4);
    PA_LD(e2a,epa,ena,6);
    PA_PROC(att, e2b,epb,enb,5);
    PA_LD(e2b,epb,enb,7);
    PA_PROC(att, e2a,epa,ena,6);
    PA_PROC(att, e2b,epb,enb,7);
  }
  lsum += __shfl_xor(lsum, 1);
  lsum += __shfl_xor(lsum, 2);
  lsum += __shfl_xor(lsum, 4);
  if ((tid & 7) == 0) inv_lds[r] = 1.f / lsum;
  __syncthreads();

  // phase B: PV. 8 waves; wave w owns os column w*16..+15; af LDS reads double-buffered.
  const int w = tid >> 6, l = tid & 63, ln = l & 15, kg = l >> 4;
  const u16* B0 = Whtbf + ((size_t)zh*NHID + w*16 + ln)*DD + kg*8;
  f32x4 acc[4];
  #pragma unroll
  for (int ns=0; ns<4; ++ns) acc[ns] = (f32x4){0,0,0,0};

  short8 Pb,Qb,Rb,Sb;
  short8 af0[4], af1[4];
#define K5_LDB(R0,kkv) do { int kc = ((kkv) < 16) ? (kkv) : 0; \
    R0 = *reinterpret_cast<const short8*>(B0 + (size_t)kc*32); } while(0)
#define K5_AFLD(AF,kkv) do { int kc = ((kkv) < 16) ? (kkv) : 0; \
    _Pragma("unroll") \
    for (int ns = 0; ns < 4; ++ns) { int row = ns*16 + ln; int c = kc*4 + kg; \
      AF[ns] = *reinterpret_cast<const short8*>(&att[row*512 + attsw(c,row)*8]); } } while(0)
#define K5_MM(AF,R0) do { \
    _Pragma("unroll") \
    for (int ns = 0; ns < 4; ++ns) \
      acc[ns] = __builtin_amdgcn_mfma_f32_16x16x32_bf16(AF[ns], R0, acc[ns], 0,0,0); } while(0)

  K5_LDB(Pb,0); K5_LDB(Qb,1); K5_LDB(Rb,2);
  K5_AFLD(af0,0);
  #pragma unroll 1
  for (int kk = 0; kk < 16; kk += 4) {
    K5_LDB(Sb,kk+3); K5_AFLD(af1,kk+1); K5_MM(af0,Pb);
    K5_LDB(Pb,kk+4); K5_AFLD(af0,kk+2); K5_MM(af1,Qb);
    K5_LDB(Qb,kk+5); K5_AFLD(af1,kk+3); K5_MM(af0,Rb);
    K5_LDB(Rb,kk+6); K5_AFLD(af0,kk+4); K5_MM(af1,Sb);
  }
#undef K5_LDB
#undef K5_AFLD
#undef K5_MM

  #pragma unroll
  for (int ns = 0; ns < 4; ++ns)
    #pragma unroll
    for (int rr = 0; rr < 4; ++rr) {
      int n = ns*16 + kg*4 + rr;
      float inv = inv_lds[n];
      float sv = acc[ns][rr] * inv;
      sv = (sv > 0.f) ? sv : expm1f(sv);
      hcatbf[((size_t)z*DD + n0 + n)*DD + h*NHID + w*16 + ln] = f2bf(sv);
    }
}

// ---------- K6: Wh2tbf[z][o][n] = (hcat @ oW^T + ob)^T, B=oW-panel staged ----------
__global__ __launch_bounds__(256) void k6_wh2(
    const u16* __restrict__ hcatbf, const u16* __restrict__ oWbf, const float* __restrict__ ob,
    u16* __restrict__ Wh2tbf)
{
  __shared__ u16 bp[2][64*64];
  const int tid = threadIdx.x;
  const int w = tid >> 6, l = tid & 63, ln = l & 15, kg = l >> 4;
  const int n0 = blockIdx.x*64 + w*16;
  const int o0 = blockIdx.y*64;
  const int z  = blockIdx.z;
  const int sc = tid & 7, sr = tid >> 3;
  const int sp = sc ^ (sr & 7);
  const int sp2 = sc ^ ((sr+32) & 7);
  const u16* B0 = oWbf + (size_t)o0*DD;
  const u16* Asrc = hcatbf + (size_t)(z*DD + n0 + ln)*DD + kg*8;

  f32x4 acc[4];
  #pragma unroll
  for (int os=0;os<4;++os) acc[os] = (f32x4){0.f,0.f,0.f,0.f};
  short8 aP0, aP1, aQ0, aQ1, sg0, sg1;

  sg0 = *reinterpret_cast<const short8*>(B0 + (size_t)sr*DD + sc*8);
  sg1 = *reinterpret_cast<const short8*>(B0 + (size_t)(sr+32)*DD + sc*8);
  aP0 = *reinterpret_cast<const short8*>(Asrc);
  aP1 = *reinterpret_cast<const short8*>(Asrc + 32);
  *reinterpret_cast<short8*>(&bp[0][sr*64 + sp*8]) = sg0;
  *reinterpret_cast<short8*>(&bp[0][(sr+32)*64 + sp2*8]) = sg1;
  __syncthreads();

  int cur = 0;
  #pragma unroll 1
  for (int s = 0; s < 8; ++s) {
    const int fn = (s+1)*64;
    if (s < 7) {
      sg0 = *reinterpret_cast<const short8*>(B0 + (size_t)sr*DD + fn + sc*8);
      sg1 = *reinterpret_cast<const short8*>(B0 + (size_t)(sr+32)*DD + fn + sc*8);
      aQ0 = *reinterpret_cast<const short8*>(Asrc + fn);
      aQ1 = *reinterpret_cast<const short8*>(Asrc + fn + 32);
    }
    #pragma unroll
    for (int os = 0; os < 4; ++os) {
      int row = os*16 + ln;
      short8 b0 = *reinterpret_cast<const short8*>(&bp[cur][row*64 + ((kg ^ (row&7))<<3)]);
      acc[os] = __builtin_amdgcn_mfma_f32_16x16x32_bf16(aP0, b0, acc[os], 0,0,0);
      short8 b1 = *reinterpret_cast<const short8*>(&bp[cur][row*64 + (((4+kg) ^ (row&7))<<3)]);
      acc[os] = __builtin_amdgcn_mfma_f32_16x16x32_bf16(aP1, b1, acc[os], 0,0,0);
    }
    if (s < 7) {
      *reinterpret_cast<short8*>(&bp[cur^1][sr*64 + sp*8]) = sg0;
      *reinterpret_cast<short8*>(&bp[cur^1][(sr+32)*64 + sp2*8]) = sg1;
      __syncthreads();
      cur ^= 1;
      aP0 = aQ0; aP1 = aQ1;
    }
  }
  #pragma unroll
  for (int os=0; os<4; ++os)
    #pragma unroll
    for (int r=0; r<4; ++r) {
      int o = o0 + os*16 + ln;
      int n = n0 + kg*4 + r;
      Wh2tbf[((size_t)z*WW + o)*DD + n] = f2bf(acc[os][r] + ob[o]);
    }
}

// ---------- K7: e1o/e2o ----------
__global__ __launch_bounds__(256) void k7_eout(
    const u16* __restrict__ hcatbf,
    const float* __restrict__ oahat_i, const float* __restrict__ oahat_j,
    const float* __restrict__ cvec,
    float* __restrict__ e1, float* __restrict__ e2)
{
  int row = blockIdx.x*4 + (threadIdx.x >> 6);
  int lane = threadIdx.x & 63;
  BF8 v8; v8.v = *reinterpret_cast<const short8*>(hcatbf + (size_t)row*DD + lane*8);
  float a1 = 0.f, a2 = 0.f;
  #pragma unroll
  for (int j = 0; j < 8; ++j) {
    float vf = bf2f(v8.u[j]);
    a1 += vf * oahat_i[lane*8 + j];
    a2 += vf * oahat_j[lane*8 + j];
  }
  #pragma unroll
  for (int off = 32; off >= 1; off >>= 1) { a1 += __shfl_xor(a1, off); a2 += __shfl_xor(a2, off); }
  if (lane == 0) { e1[row] = a1 + cvec[8]; e2[row] = a2 + cvec[9]; }
}

// ---------- K8a: out attention PV; 8 waves, pipelined -> g f32 (elu) ----------
__global__ __launch_bounds__(512) void k8_pv(
    const float* __restrict__ e1o, const float* __restrict__ e2o,
    const float* __restrict__ M2o, const float* __restrict__ E2p, const float* __restrict__ E2n,
    const u16* __restrict__ Wh2tbf, float* __restrict__ g, int CBv)
{
  __shared__ u16 att[64*512];
  __shared__ float inv_lds[64];
  const int orig = blockIdx.x;
  int nb, z, oh;
  if (CBv >= 8) {
    int xcd = orig & 7;
    int k = orig >> 3;
    nb = k & 7;
    int rest = k >> 3;
    oh = rest & 1;
    z = xcd * (CBv >> 3) + (rest >> 1);
  } else {
    nb = orig & 7;
    int k = orig >> 3;
    z = k >> 1;
    oh = k & 1;
  }
  const int n0 = nb*64;
  const int tid = threadIdx.x;

  const int r = tid >> 3, qd = tid & 7;
  const float e1n = e1o[(size_t)z*DD + n0 + r];
  const float M2 = M2o[z];
  const float s = e1n + M2;
  const float mx = (s > 0.f) ? s : 0.1f*s;
  const float Ap = expf(s - mx);
  const float An = expf(0.1f*s - mx);
  const float thr = -e1n;
  const float* e2r = e2o + (size_t)z*DD + qd*64;
  const float* Epr = E2p + (size_t)z*DD + qd*64;
  const float* Enr = E2n + (size_t)z*DD + qd*64;
  float lsum = 0.f;
  {
    F8 e2a,epa,ena, e2b,epb,enb;
    PA_LD(e2a,epa,ena,0);
    PA_LD(e2b,epb,enb,1);
    PA_PROC(att, e2a,epa,ena,0);
    PA_LD(e2a,epa,ena,2);
    PA_PROC(att, e2b,epb,enb,1);
    PA_LD(e2b,epb,enb,3);
    PA_PROC(att, e2a,epa,ena,2);
    PA_LD(e2a,epa,ena,4);
    PA_PROC(att, e2b,epb,enb,3);
    PA_LD(e2b,epb,enb,5);
    PA_PROC(att, e2a,epa,ena,4);
    PA_LD(e2a,epa,ena,6);
    PA_PROC(att, e2b,epb,enb,5);
    PA_LD(e2b,epb,enb,7);
    PA_PROC(att, e2a,epa,ena,6);
    PA_PROC(att, e2b,epb,enb,7);
  }
  lsum += __shfl_xor(lsum, 1);
  lsum += __shfl_xor(lsum, 2);
  lsum += __shfl_xor(lsum, 4);
  if ((tid & 7) == 0) inv_lds[r] = 1.f / lsum;
  __syncthreads();

  const int w = tid >> 6, l = tid & 63, ln = l & 15, kg = l >> 4;
  const u16* B0 = Wh2tbf + ((size_t)z*WW + oh*128 + w*16 + ln)*DD + kg*8;
  f32x4 acc[4];
  #pragma unroll
  for (int ns=0; ns<4; ++ns) acc[ns] = (f32x4){0,0,0,0};

  short8 Pb,Qb,Rb,Sb;
  short8 af0[4], af1[4];
#define K8_LDB(R0,kkv) do { int kc = ((kkv) < 16) ? (kkv) : 0; \
    R0 = *reinterpret_cast<const short8*>(B0 + (size_t)kc*32); } while(0)
#define K8_AFLD(AF,kkv) do { int kc = ((kkv) < 16) ? (kkv) : 0; \
    _Pragma("unroll") \
    for (int ns = 0; ns < 4; ++ns) { int row = ns*16 + ln; int c = kc*4 + kg; \
      AF[ns] = *reinterpret_cast<const short8*>(&att[row*512 + attsw(c,row)*8]); } } while(0)
#define K8_MM(AF,R0) do { \
    _Pragma("unroll") \
    for (int ns = 0; ns < 4; ++ns) \
      acc[ns] = __builtin_amdgcn_mfma_f32_16x16x32_bf16(AF[ns], R0, acc[ns], 0,0,0); } while(0)

  K8_LDB(Pb,0); K8_LDB(Qb,1); K8_LDB(Rb,2);
  K8_AFLD(af0,0);
  #pragma unroll 1
  for (int kk = 0; kk < 16; kk += 4) {
    K8_LDB(Sb,kk+3); K8_AFLD(af1,kk+1); K8_MM(af0,Pb);
    K8_LDB(Pb,kk+4); K8_AFLD(af0,kk+2); K8_MM(af1,Qb);
    K8_LDB(Qb,kk+5); K8_AFLD(af1,kk+3); K8_MM(af0,Rb);
    K8_LDB(Rb,kk+6); K8_AFLD(af0,kk+4); K8_MM(af1,Sb);
  }
#undef K8_LDB
#undef K8_AFLD
#undef K8_MM

  #pragma unroll
  for (int ns = 0; ns < 4; ++ns)
    #pragma unroll
    for (int rr = 0; rr < 4; ++rr) {
      int n = ns*16 + kg*4 + rr;
      float inv = inv_lds[n];
      float val = acc[ns][rr] * inv;
      val = (val > 0.f) ? val : expm1f(val);    // elu
      g[((size_t)z*DD + n0 + n)*WW + oh*128 + w*16 + ln] = val;
    }
}

// ---------- K8b: row log_softmax over o(256) -> gaty bf16 ----------
__global__ __launch_bounds__(256) void k8_lsm(
    const float* __restrict__ g, u16* __restrict__ gatybf)
{
  int row = blockIdx.x*4 + (threadIdx.x >> 6);
  int lane = threadIdx.x & 63;
  const float* gr = g + (size_t)row*WW;
  float v0 = gr[lane], v1 = gr[lane+64], v2 = gr[lane+128], v3 = gr[lane+192];
  float mx = fmaxf(fmaxf(v0,v1), fmaxf(v2,v3));
  #pragma unroll
  for (int off = 32; off >= 1; off >>= 1) mx = fmaxf(mx, __shfl_xor(mx, off));
  float sm = expf(v0-mx) + expf(v1-mx) + expf(v2-mx) + expf(v3-mx);
  #pragma unroll
  for (int off = 32; off >= 1; off >>= 1) sm += __shfl_xor(sm, off);
  float lg = mx + logf(sm);
  u16* go = gatybf + (size_t)row*WW;
  go[lane]     = f2bf(v0 - lg);
  go[lane+64]  = f2bf(v1 - lg);
  go[lane+128] = f2bf(v2 - lg);
  go[lane+192] = f2bf(v3 - lg);
}

// ---------- K9: out = gaty^T @ pW^T + pb ----------
__global__ __launch_bounds__(256) void k9_proj(
    const u16* __restrict__ gatybf, const u16* __restrict__ pWbf, const float* __restrict__ pb,
    int zb, float* __restrict__ out0)
{
  __shared__ u16 gt[64*40];
  const int t0 = blockIdx.x*64, d0 = blockIdx.y*64, z = blockIdx.z;
  const int tid = threadIdx.x;
  const int w = tid >> 6, l = tid & 63, ln = l & 15, kg = l >> 4;
  const int el = tid >> 3, t8 = tid & 7;
  f32x4 acc[4];
  #pragma unroll
  for (int os=0;os<4;++os) acc[os] = (f32x4){0.f,0.f,0.f,0.f};
  for (int e0 = 0; e0 < DD; e0 += 32) {
    __syncthreads();
    BF8 g8;
    g8.v = *reinterpret_cast<const short8*>(gatybf + ((size_t)z*DD + e0 + el)*WW + t0 + t8*8);
    #pragma unroll
    for (int j = 0; j < 8; ++j) gt[(t8*8 + j)*40 + el] = g8.u[j];
    __syncthreads();
    short8 a = *reinterpret_cast<const short8*>(&gt[(w*16 + ln)*40 + kg*8]);
    #pragma unroll
    for (int os = 0; os < 4; ++os) {
      short8 b = *reinterpret_cast<const short8*>(pWbf + (size_t)(d0 + os*16 + ln)*DD + e0 + kg*8);
      acc[os] = __builtin_amdgcn_mfma_f32_16x16x32_bf16(a, b, acc[os], 0,0,0);
    }
  }
  #pragma unroll
  for (int os=0; os<4; ++os)
    #pragma unroll
    for (int rr=0; rr<4; ++rr) {
      int t = t0 + w*16 + kg*4 + rr;
      int d = d0 + os*16 + ln;
      out0[((size_t)(zb+z)*WW + t)*DD + d] = acc[os][rr] + pb[d];
    }
}

extern "C" void kernel_launch(void* const* d_in, const int* in_sizes, int n_in,
                              void* d_out, int out_size, void* d_ws, size_t ws_size,
                              hipStream_t stream)
{
  const float* x   = (const float*)d_in[0];
  const float* qW  = (const float*)d_in[1];
  const float* qb  = (const float*)d_in[2];
  const float* kW  = (const float*)d_in[3];
  const float* kb  = (const float*)d_in[4];
  const float* vW  = (const float*)d_in[5];
  const float* vb  = (const float*)d_in[6];
  const float* hW  = (const float*)d_in[7];
  const float* hb  = (const float*)d_in[8];
  const float* hai = (const float*)d_in[9];
  const float* haib= (const float*)d_in[10];
  const float* haj = (const float*)d_in[11];
  const float* hajb= (const float*)d_in[12];
  const float* oW  = (const float*)d_in[13];
  const float* ob  = (const float*)d_in[14];
  const float* oai = (const float*)d_in[15];
  const float* oaib= (const float*)d_in[16];
  const float* oaj = (const float*)d_in[17];
  const float* oajb= (const float*)d_in[18];
  const float* pW  = (const float*)d_in[19];
  const float* pb  = (const float*)d_in[20];

  float* out0 = (float*)d_out;                   // [B,W,D] f32
  float* adjo = out0 + (size_t)BB*WW*DD;         // [B,D,D] f32

  // static region (float offsets)
  float* ws      = (float*)d_ws;
  u16*   Wt      = (u16*)(ws + 0);           // 1,179,648 f
  u16*   hWbf    = (u16*)(ws + 1179648);     //    65,536 f
  u16*   oWbf    = (u16*)(ws + 1245184);     //    65,536 f
  u16*   pWbf    = (u16*)(ws + 1310720);     //   131,072 f
  float* ahat_i  = ws + 1441792;
  float* ahat_j  = ws + 1442816;
  float* oahat_i = ws + 1443840;
  float* oahat_j = ws + 1444352;
  float* cvec    = ws + 1444864;
  float* e1h     = ws + 1444880;             //    65,536 f (CB=32 max)
  float* e2h     = ws + 1510416;
  float* e1o     = ws + 1575952;             //    16,384 f
  float* e2o     = ws + 1592336;
  float* M2h     = ws + 1608720;             //       128 f
  float* E2hp    = ws + 1608848;             //    65,536 f
  float* E2hn    = ws + 1674384;             //    65,536 f
  float* M2o     = ws + 1739920;             //        32 f
  float* E2op    = ws + 1739952;             //    16,384 f
  float* E2on    = ws + 1756336;             //    16,384 f
  const size_t X0 = 1772720;                 // dynamic region start

  // per-CB dynamic: xpad 66,048 + vbf 65,536 + qbf 65,536 + kbf 65,536 + Whtbf 131,072 = 393,728 f
  int CB = 4;
  {
    const int cand[3] = {32, 16, 8};
    for (int i = 0; i < 3; ++i) {
      size_t need = (X0 + (size_t)cand[i]*393728) * 4;
      if (need <= ws_size) { CB = cand[i]; break; }
    }
  }

  u16* xpad   = (u16*)(ws + X0);                        // CB*66,048 f  ([z][258][512])
  u16* vbf    = (u16*)(ws + X0 + (size_t)CB*66048);     // CB*65,536 f
  u16* qbf    = (u16*)(ws + X0 + (size_t)CB*131584);    // CB*65,536 f
  u16* kbf    = (u16*)(ws + X0 + (size_t)CB*197120);    // CB*65,536 f
  u16* Whtbf  = (u16*)(ws + X0 + (size_t)CB*262656);    // CB*131,072 f
  // overlays (lifetimes: xpad dead after k1; vbf dead after k4; qbf,kbf dead after k2;
  // hcatbf dead after k7; Whtbf dead after k5)
  u16*   hcatbf = (u16*)(ws + X0);                      // over xpad+vbf
  float* g      = (float*)(ws + X0);                    // over hcatbf region (k8 phase)
  u16*   gatybf = (u16*)(ws + X0 + (size_t)CB*131584);  // over qbf
  u16*   Wh2tbf = (u16*)(ws + X0 + (size_t)CB*197120);  // over kbf

  kprep_w<<<dim3((3*DD*DD + 255)/256), 256, 0, stream>>>(qW, kW, vW, Wt);
  kcvt<<<dim3((NHEADS*NHID*WW + 255)/256), 256, 0, stream>>>(hW, hWbf, NHEADS*NHID*WW);
  kcvt<<<dim3((WW*DD + 255)/256), 256, 0, stream>>>(oW, oWbf, WW*DD);
  kcvt<<<dim3((DD*DD + 255)/256), 256, 0, stream>>>(pW, pWbf, DD*DD);
  kprep_a<<<dim3(13), 256, 0, stream>>>(hW, hai, haib, haj, hajb, hb,
                                        oW, oai, oaib, oaj, oajb, ob,
                                        ahat_i, ahat_j, oahat_i, oahat_j, cvec);

  for (int zb = 0; zb < BB; zb += CB) {
    int nrow8 = CB*258*64;
    kprep_x  <<<dim3((nrow8 + 255)/256), 256, 0, stream>>>(x, zb, nrow8, xpad);
    k1_mfma  <<<dim3(DD/64, WW/128, CB), 256, 0, stream>>>(xpad, Wt, qb, kb, vb, qbf, kbf, vbf);
    k2_adj   <<<dim3(DD/64, DD/64, CB), 256, 0, stream>>>(qbf, kbf, zb, adjo);
    k3_wh    <<<dim3(DD/64, NHID/64, CB*NHEADS), 256, 0, stream>>>(vbf, hWbf, hb, Whtbf);
    k4_eheads<<<dim3(CB*NHEADS*DD/4), 256, 0, stream>>>(vbf, ahat_i, ahat_j, cvec, e1h, e2h);
    kexp2    <<<dim3(CB*NHEADS), 256, 0, stream>>>(e2h, M2h, E2hp, E2hn);
    k5_attn  <<<dim3(32*CB), 512, 0, stream>>>(e1h, e2h, M2h, E2hp, E2hn, Whtbf, hcatbf, CB*NHEADS);
    k6_wh2   <<<dim3(DD/64, WW/64, CB), 256, 0, stream>>>(hcatbf, oWbf, ob, Wh2tbf);
    k7_eout  <<<dim3(CB*DD/4), 256, 0, stream>>>(hcatbf, oahat_i, oahat_j, cvec, e1o, e2o);
    kexp2    <<<dim3(CB), 256, 0, stream>>>(e2o, M2o, E2op, E2on);
    k8_pv    <<<dim3(16*CB), 512, 0, stream>>>(e1o, e2o, M2o, E2op, E2on, Wh2tbf, g, CB);
    k8_lsm   <<<dim3(CB*128), 256, 0, stream>>>(g, gatybf);
    k9_proj  <<<dim3(WW/64, DD/64, CB), 256, 0, stream>>>(gatybf, pWbf, pb, zb, out0);
  }
}

// Round 17
// 311.210 us; speedup vs baseline: 1.0669x; 1.0158x over previous
//
#include <hip/hip_runtime.h>
#include <math.h>

typedef unsigned short u16;
typedef __attribute__((ext_vector_type(8))) short short8;
typedef __attribute__((ext_vector_type(4))) float f32x4;

#define BB 32
#define WW 256
#define DD 512
#define NHEADS 4
#define NHID 128

__device__ __forceinline__ u16 f2bf(float f) {
  union { float f; unsigned int i; } x; x.f = f;
  unsigned int i = x.i;
  i += 0x7fffu + ((i >> 16) & 1u);
  return (u16)(i >> 16);
}
__device__ __forceinline__ float bf2f(u16 u) {
  union { float f; unsigned int i; } x; x.i = ((unsigned int)u) << 16; return x.f;
}

union BF8 { short8 v; u16 u[8]; };
union BF4 { ushort4 v; u16 u[4]; };
union F8 { float4 v4[2]; float f[8]; };

// ---------- prep (once) ----------
__global__ __launch_bounds__(256) void kprep_w(
    const float* __restrict__ qW, const float* __restrict__ kW, const float* __restrict__ vW,
    u16* __restrict__ Wt)
{
  int idx = blockIdx.x*256 + threadIdx.x;     // (c, o, i)
  if (idx >= 3*DD*DD) return;
  int c = idx >> 18;
  int oi = idx & (DD*DD - 1);
  int i = oi & (DD-1);
  int o = oi >> 9;
  const float* W = (c==0) ? qW : (c==1) ? kW : vW;
  float w0 = W[oi*3+0], w1 = W[oi*3+1], w2 = W[oi*3+2];
  Wt[((size_t)(c*3+0)*DD + o)*DD + i] = f2bf(w0);
  Wt[((size_t)(c*3+1)*DD + o)*DD + i] = f2bf(w1);
  Wt[((size_t)(c*3+2)*DD + o)*DD + i] = f2bf(w2);
}

__global__ __launch_bounds__(256) void kcvt(const float* __restrict__ s, u16* __restrict__ d, int n) {
  int i = blockIdx.x*256 + threadIdx.x;
  if (i < n) d[i] = f2bf(s[i]);
}

__global__ __launch_bounds__(256) void kprep_a(
    const float* __restrict__ hW, const float* __restrict__ hai, const float* __restrict__ haib,
    const float* __restrict__ haj, const float* __restrict__ hajb,
    const float* __restrict__ hb,
    const float* __restrict__ oW, const float* __restrict__ oai, const float* __restrict__ oaib,
    const float* __restrict__ oaj, const float* __restrict__ oajb,
    const float* __restrict__ ob,
    float* __restrict__ ahat_i, float* __restrict__ ahat_j,
    float* __restrict__ oahat_i, float* __restrict__ oahat_j,
    float* __restrict__ cvec)
{
  int idx = blockIdx.x*256 + threadIdx.x;
  if (idx < 1024) {
    int h = idx >> 8, f = idx & 255;
    float s = 0.f;
    for (int o = 0; o < NHID; ++o) s += hW[((size_t)h*NHID + o)*WW + f] * hai[h*NHID + o];
    ahat_i[idx] = s;
  } else if (idx < 2048) {
    int t = idx - 1024; int h = t >> 8, f = t & 255;
    float s = 0.f;
    for (int o = 0; o < NHID; ++o) s += hW[((size_t)h*NHID + o)*WW + f] * haj[h*NHID + o];
    ahat_j[t] = s;
  } else if (idx < 2560) {
    int f = idx - 2048;
    float s = 0.f;
    for (int o = 0; o < WW; ++o) s += oW[(size_t)o*DD + f] * oai[o];
    oahat_i[f] = s;
  } else if (idx < 3072) {
    int f = idx - 2560;
    float s = 0.f;
    for (int o = 0; o < WW; ++o) s += oW[(size_t)o*DD + f] * oaj[o];
    oahat_j[f] = s;
  } else if (idx < 3082) {
    int t = idx - 3072;
    if (t < 4) {
      float s = 0.f;
      for (int o = 0; o < NHID; ++o) s += hb[t*NHID + o]*hai[t*NHID + o];
      cvec[t] = s + haib[t];
    } else if (t < 8) {
      int h = t - 4; float s = 0.f;
      for (int o = 0; o < NHID; ++o) s += hb[h*NHID + o]*haj[h*NHID + o];
      cvec[t] = s + hajb[h];
    } else if (t == 8) {
      float s = 0.f;
      for (int o = 0; o < WW; ++o) s += ob[o]*oai[o];
      cvec[8] = s + oaib[0];
    } else {
      float s = 0.f;
      for (int o = 0; o < WW; ++o) s += ob[o]*oaj[o];
      cvec[9] = s + oajb[0];
    }
  }
}

// x f32 -> xpad bf16 [z][258][512] with zero halo rows (t=-1, t=256)
__global__ __launch_bounds__(256) void kprep_x(
    const float* __restrict__ x, int zb, int nrow8, u16* __restrict__ xpad)
{
  int idx8 = blockIdx.x*256 + threadIdx.x;
  if (idx8 >= nrow8) return;
  int i8 = idx8 & 63;
  int rowg = idx8 >> 6;                       // z*258 + r
  int z = rowg / 258, r = rowg - z*258;
  int t = r - 1;
  BF8 o8;
  if (t >= 0 && t < WW) {
    const float* src = x + ((size_t)(zb+z)*WW + t)*DD + i8*8;
    float4 v0 = *reinterpret_cast<const float4*>(src);
    float4 v1 = *reinterpret_cast<const float4*>(src + 4);
    o8.u[0]=f2bf(v0.x); o8.u[1]=f2bf(v0.y); o8.u[2]=f2bf(v0.z); o8.u[3]=f2bf(v0.w);
    o8.u[4]=f2bf(v1.x); o8.u[5]=f2bf(v1.y); o8.u[6]=f2bf(v1.z); o8.u[7]=f2bf(v1.w);
  } else {
    #pragma unroll
    for (int j = 0; j < 8; ++j) o8.u[j] = 0;
  }
  *reinterpret_cast<short8*>(xpad + (size_t)rowg*DD + i8*8) = o8.v;
}

// kexp2: per row-group (512 e2 values): M2 = max, E2p = exp(e2-M2), E2n = exp(0.1(e2-M2))
__global__ __launch_bounds__(256) void kexp2(
    const float* __restrict__ e2, float* __restrict__ M2,
    float* __restrict__ E2p, float* __restrict__ E2n)
{
  __shared__ float s4[4];
  const int zh = blockIdx.x, tid = threadIdx.x;
  float v0 = e2[(size_t)zh*DD + tid], v1 = e2[(size_t)zh*DD + 256 + tid];
  float m = fmaxf(v0, v1);
  #pragma unroll
  for (int off=32; off>=1; off>>=1) m = fmaxf(m, __shfl_xor(m, off));
  if ((tid & 63) == 0) s4[tid >> 6] = m;
  __syncthreads();
  m = fmaxf(fmaxf(s4[0], s4[1]), fmaxf(s4[2], s4[3]));
  if (tid == 0) M2[zh] = m;
  E2p[(size_t)zh*DD + tid]       = expf(v0 - m);
  E2p[(size_t)zh*DD + 256 + tid] = expf(v1 - m);
  E2n[(size_t)zh*DD + tid]       = expf(0.1f*(v0 - m));
  E2n[(size_t)zh*DD + 256 + tid] = expf(0.1f*(v1 - m));
}

// ---------- K1: conv via MFMA; 64o x 128t tile; B LDS-staged; A double-buffered ----------
__global__ __launch_bounds__(256) void k1_mfma(
    const u16* __restrict__ xpad, const u16* __restrict__ Wt,
    const float* __restrict__ qb, const float* __restrict__ kb, const float* __restrict__ vb,
    u16* __restrict__ qbf, u16* __restrict__ kbf, u16* __restrict__ vbf)
{
  __shared__ u16 bt[2][130*64];
  const int tid = threadIdx.x;
  const int w  = tid >> 6;
  const int l  = tid & 63;
  const int ln = l & 15;
  const int kg = l >> 4;
  const int og = blockIdx.x * 64 + w * 16;
  const int t0 = blockIdx.y * 128;
  const int z  = blockIdx.z;

  const u16* A0 = Wt + (size_t)(og + ln)*DD + kg*8;
  const u16* Xb = xpad + ((size_t)z*258 + t0)*DD;

  f32x4 acc[3][8];
  #pragma unroll
  for (int c=0;c<3;++c)
    #pragma unroll
    for (int ts=0;ts<8;++ts) acc[c][ts] = (f32x4){0.f,0.f,0.f,0.f};

  short8 ArP[9], ArQ[9];
  short8 sg0, sg1, sg2, sg3, sg4;
  const int ccw = tid & 7;
  const int rs = tid >> 3;

#define K1_LOADX(i0v) do { \
    sg0 = *reinterpret_cast<const short8*>(Xb + (size_t)rs*DD + (i0v) + ccw*8); \
    sg1 = *reinterpret_cast<const short8*>(Xb + (size_t)(rs+32)*DD + (i0v) + ccw*8); \
    sg2 = *reinterpret_cast<const short8*>(Xb + (size_t)(rs+64)*DD + (i0v) + ccw*8); \
    sg3 = *reinterpret_cast<const short8*>(Xb + (size_t)(rs+96)*DD + (i0v) + ccw*8); \
    if (tid < 16) sg4 = *reinterpret_cast<const short8*>(Xb + (size_t)(rs+128)*DD + (i0v) + ccw*8); \
  } while(0)

#define K1_WRITEX(bufv) do { \
    *reinterpret_cast<short8*>(&bt[bufv][rs*64 + ((ccw^(rs&7))<<3)]) = sg0; \
    *reinterpret_cast<short8*>(&bt[bufv][(rs+32)*64 + ((ccw^((rs+32)&7))<<3)]) = sg1; \
    *reinterpret_cast<short8*>(&bt[bufv][(rs+64)*64 + ((ccw^((rs+64)&7))<<3)]) = sg2; \
    *reinterpret_cast<short8*>(&bt[bufv][(rs+96)*64 + ((ccw^((rs+96)&7))<<3)]) = sg3; \
    if (tid < 16) *reinterpret_cast<short8*>(&bt[bufv][(rs+128)*64 + ((ccw^((rs+128)&7))<<3)]) = sg4; \
  } while(0)

#define K1_LOADA(Abuf, i0v, khv) do { \
    _Pragma("unroll") \
    for (int c = 0; c < 3; ++c) { \
      _Pragma("unroll") \
      for (int tap = 0; tap < 3; ++tap) \
        Abuf[c*3+tap] = *reinterpret_cast<const short8*>(A0 + (size_t)(c*3+tap)*DD*DD + (i0v) + (khv)*32); \
    } \
  } while(0)

#define K1_MFMAS(Abuf, khv) do { \
    _Pragma("unroll") \
    for (int tap = 0; tap < 3; ++tap) { \
      _Pragma("unroll") \
      for (int ts = 0; ts < 8; ++ts) { \
        int row = ts*16 + ln + tap; \
        short8 bfr = *reinterpret_cast<const short8*>(&bt[cur][row*64 + ((((khv)*4+kg) ^ (row&7))<<3)]); \
        acc[0][ts] = __builtin_amdgcn_mfma_f32_16x16x32_bf16(Abuf[0*3+tap], bfr, acc[0][ts], 0,0,0); \
        acc[1][ts] = __builtin_amdgcn_mfma_f32_16x16x32_bf16(Abuf[1*3+tap], bfr, acc[1][ts], 0,0,0); \
        acc[2][ts] = __builtin_amdgcn_mfma_f32_16x16x32_bf16(Abuf[2*3+tap], bfr, acc[2][ts], 0,0,0); \
      } \
    } \
  } while(0)

  K1_LOADX(0);
  K1_LOADA(ArP, 0, 0);
  K1_WRITEX(0);
  __syncthreads();

  int cur = 0;
  #pragma unroll 1
  for (int p = 0; p < 8; ++p) {
    const int i0 = p*64;
    if (p < 7) K1_LOADX(i0 + 64);
    K1_LOADA(ArQ, i0, 1);
    K1_MFMAS(ArP, 0);
    const int i0n = (p < 7) ? i0 + 64 : 0;
    K1_LOADA(ArP, i0n, 0);
    K1_MFMAS(ArQ, 1);
    if (p < 7) {
      K1_WRITEX(cur ^ 1);
      __syncthreads();
      cur ^= 1;
    }
  }

#undef K1_LOADX
#undef K1_WRITEX
#undef K1_LOADA
#undef K1_MFMAS

  #pragma unroll
  for (int ts=0; ts<8; ++ts) {
    int tg = t0 + ts*16 + ln;
    #pragma unroll
    for (int r=0;r<4;++r) {
      int o = og + kg*4 + r;
      size_t oi = (size_t)(z*DD + o)*WW + tg;
      qbf[oi] = f2bf(acc[0][ts][r] + qb[o]);
      kbf[oi] = f2bf(acc[1][ts][r] + kb[o]);
      vbf[oi] = f2bf(acc[2][ts][r] + vb[o]);
    }
  }
}

// ---------- K2: adj = sigmoid(q.kT * scale), B=k-panel staged ----------
__global__ __launch_bounds__(256) void k2_adj(
    const u16* __restrict__ qbf, const u16* __restrict__ kbf, int zb, float* __restrict__ adjo)
{
  __shared__ u16 bp[2][64*64];
  const int tid = threadIdx.x;
  const int w = tid >> 6, l = tid & 63, ln = l & 15, kg = l >> 4;
  const int d0 = blockIdx.x*64 + w*16;
  const int e0 = blockIdx.y*64;
  const int z  = blockIdx.z;
  const int sc = tid & 7, sr = tid >> 3;
  const int sp = sc ^ (sr & 7);
  const int sp2 = sc ^ ((sr+32) & 7);
  const u16* B0 = kbf + (size_t)(z*DD + e0)*WW;
  const u16* Asrc = qbf + (size_t)(z*DD + d0 + ln)*WW + kg*8;

  f32x4 acc[4];
  #pragma unroll
  for (int es=0;es<4;++es) acc[es] = (f32x4){0.f,0.f,0.f,0.f};
  short8 aP0, aP1, aQ0, aQ1, sg0, sg1;

  sg0 = *reinterpret_cast<const short8*>(B0 + (size_t)sr*WW + sc*8);
  sg1 = *reinterpret_cast<const short8*>(B0 + (size_t)(sr+32)*WW + sc*8);
  aP0 = *reinterpret_cast<const short8*>(Asrc);
  aP1 = *reinterpret_cast<const short8*>(Asrc + 32);
  *reinterpret_cast<short8*>(&bp[0][sr*64 + sp*8]) = sg0;
  *reinterpret_cast<short8*>(&bp[0][(sr+32)*64 + sp2*8]) = sg1;
  __syncthreads();

  int cur = 0;
  #pragma unroll 1
  for (int s = 0; s < 4; ++s) {
    const int fn = (s+1)*64;
    if (s < 3) {
      sg0 = *reinterpret_cast<const short8*>(B0 + (size_t)sr*WW + fn + sc*8);
      sg1 = *reinterpret_cast<const short8*>(B0 + (size_t)(sr+32)*WW + fn + sc*8);
      aQ0 = *reinterpret_cast<const short8*>(Asrc + fn);
      aQ1 = *reinterpret_cast<const short8*>(Asrc + fn + 32);
    }
    #pragma unroll
    for (int es = 0; es < 4; ++es) {
      int row = es*16 + ln;
      short8 b0 = *reinterpret_cast<const short8*>(&bp[cur][row*64 + ((kg ^ (row&7))<<3)]);
      acc[es] = __builtin_amdgcn_mfma_f32_16x16x32_bf16(aP0, b0, acc[es], 0,0,0);
      short8 b1 = *reinterpret_cast<const short8*>(&bp[cur][row*64 + (((4+kg) ^ (row&7))<<3)]);
      acc[es] = __builtin_amdgcn_mfma_f32_16x16x32_bf16(aP1, b1, acc[es], 0,0,0);
    }
    if (s < 3) {
      *reinterpret_cast<short8*>(&bp[cur^1][sr*64 + sp*8]) = sg0;
      *reinterpret_cast<short8*>(&bp[cur^1][(sr+32)*64 + sp2*8]) = sg1;
      __syncthreads();
      cur ^= 1;
      aP0 = aQ0; aP1 = aQ1;
    }
  }
  const float scale = 0.044194173824159216f;
  #pragma unroll
  for (int es=0; es<4; ++es)
    #pragma unroll
    for (int r=0; r<4; ++r) {
      float sig = 1.f/(1.f + expf(-acc[es][r]*scale));
      adjo[((size_t)(zb+z)*DD + d0 + kg*4 + r)*DD + e0 + es*16 + ln] = sig;
    }
}

// ---------- K3: Whtbf[zh][o][n] = (v @ hW^T + hb)^T, B=hW-panel staged ----------
__global__ __launch_bounds__(256) void k3_wh(
    const u16* __restrict__ vbf, const u16* __restrict__ hWbf, const float* __restrict__ hb,
    u16* __restrict__ Whtbf)
{
  __shared__ u16 bp[2][64*64];
  const int tid = threadIdx.x;
  const int w = tid >> 6, l = tid & 63, ln = l & 15, kg = l >> 4;
  const int n0 = blockIdx.x*64 + w*16;
  const int o0 = blockIdx.y*64;
  const int zh = blockIdx.z, z = zh >> 2, h = zh & 3;
  const int sc = tid & 7, sr = tid >> 3;
  const int sp = sc ^ (sr & 7);
  const int sp2 = sc ^ ((sr+32) & 7);
  const u16* B0 = hWbf + (size_t)(h*NHID + o0)*WW;
  const u16* Asrc = vbf + (size_t)(z*DD + n0 + ln)*WW + kg*8;

  f32x4 acc[4];
  #pragma unroll
  for (int os=0;os<4;++os) acc[os] = (f32x4){0.f,0.f,0.f,0.f};
  short8 aP0, aP1, aQ0, aQ1, sg0, sg1;

  sg0 = *reinterpret_cast<const short8*>(B0 + (size_t)sr*WW + sc*8);
  sg1 = *reinterpret_cast<const short8*>(B0 + (size_t)(sr+32)*WW + sc*8);
  aP0 = *reinterpret_cast<const short8*>(Asrc);
  aP1 = *reinterpret_cast<const short8*>(Asrc + 32);
  *reinterpret_cast<short8*>(&bp[0][sr*64 + sp*8]) = sg0;
  *reinterpret_cast<short8*>(&bp[0][(sr+32)*64 + sp2*8]) = sg1;
  __syncthreads();

  int cur = 0;
  #pragma unroll 1
  for (int s = 0; s < 4; ++s) {
    const int fn = (s+1)*64;
    if (s < 3) {
      sg0 = *reinterpret_cast<const short8*>(B0 + (size_t)sr*WW + fn + sc*8);
      sg1 = *reinterpret_cast<const short8*>(B0 + (size_t)(sr+32)*WW + fn + sc*8);
      aQ0 = *reinterpret_cast<const short8*>(Asrc + fn);
      aQ1 = *reinterpret_cast<const short8*>(Asrc + fn + 32);
    }
    #pragma unroll
    for (int os = 0; os < 4; ++os) {
      int row = os*16 + ln;
      short8 b0 = *reinterpret_cast<const short8*>(&bp[cur][row*64 + ((kg ^ (row&7))<<3)]);
      acc[os] = __builtin_amdgcn_mfma_f32_16x16x32_bf16(aP0, b0, acc[os], 0,0,0);
      short8 b1 = *reinterpret_cast<const short8*>(&bp[cur][row*64 + (((4+kg) ^ (row&7))<<3)]);
      acc[os] = __builtin_amdgcn_mfma_f32_16x16x32_bf16(aP1, b1, acc[os], 0,0,0);
    }
    if (s < 3) {
      *reinterpret_cast<short8*>(&bp[cur^1][sr*64 + sp*8]) = sg0;
      *reinterpret_cast<short8*>(&bp[cur^1][(sr+32)*64 + sp2*8]) = sg1;
      __syncthreads();
      cur ^= 1;
      aP0 = aQ0; aP1 = aQ1;
    }
  }
  #pragma unroll
  for (int os=0; os<4; ++os)
    #pragma unroll
    for (int r=0; r<4; ++r) {
      int o = o0 + os*16 + ln;
      int n = n0 + kg*4 + r;
      Whtbf[((size_t)zh*NHID + o)*DD + n] = f2bf(acc[os][r] + hb[h*NHID + o]);
    }
}

// ---------- K4: e1h/e2h ----------
__global__ __launch_bounds__(256) void k4_eheads(
    const u16* __restrict__ vbf,
    const float* __restrict__ ahat_i, const float* __restrict__ ahat_j,
    const float* __restrict__ cvec,
    float* __restrict__ e1, float* __restrict__ e2)
{
  int row = blockIdx.x*4 + (threadIdx.x >> 6);   // row = zh*512 + n
  int lane = threadIdx.x & 63;
  int zh = row >> 9, n = row & 511;
  int z = zh >> 2, h = zh & 3;
  BF4 v4; v4.v = *reinterpret_cast<const ushort4*>(vbf + ((size_t)(z*DD + n))*WW + lane*4);
  const float* aif = ahat_i + h*WW + lane*4;
  const float* ajf = ahat_j + h*WW + lane*4;
  float a1 = 0.f, a2 = 0.f;
  #pragma unroll
  for (int j = 0; j < 4; ++j) {
    float vf = bf2f(v4.u[j]);
    a1 += vf * aif[j];
    a2 += vf * ajf[j];
  }
  #pragma unroll
  for (int off = 32; off >= 1; off >>= 1) { a1 += __shfl_xor(a1, off); a2 += __shfl_xor(a2, off); }
  if (lane == 0) { e1[row] = a1 + cvec[h]; e2[row] = a2 + cvec[4+h]; }
}

// swizzled att chunk index
__device__ __forceinline__ int attsw(int c, int row) {
  return c ^ ((c >> 3) & 7) ^ (row & 7);
}

// ---- shared phase-A macros (pipelined) ----
#define PA_LD(Ea,Pa,Na,jcv) do { int j0=(jcv)*8; \
    Ea.v4[0]=*reinterpret_cast<const float4*>(e2r+j0); Ea.v4[1]=*reinterpret_cast<const float4*>(e2r+j0+4); \
    Pa.v4[0]=*reinterpret_cast<const float4*>(Epr+j0); Pa.v4[1]=*reinterpret_cast<const float4*>(Epr+j0+4); \
    Na.v4[0]=*reinterpret_cast<const float4*>(Enr+j0); Na.v4[1]=*reinterpret_cast<const float4*>(Enr+j0+4); } while(0)
#define PA_PROC(att, Ea,Pa,Na,jcv) do { BF8 pk; \
    _Pragma("unroll") \
    for (int jj=0;jj<8;++jj){ float p=(Ea.f[jj]>thr)?Ap*Pa.f[jj]:An*Na.f[jj]; lsum+=p; pk.u[jj]=f2bf(p);} \
    int c=qd*8+(jcv); *reinterpret_cast<short8*>(&att[r*512+attsw(c,r)*8])=pk.v; } while(0)

// ---------- K5: heads attention; 8 waves, factorized softmax, pipelined ----------
__global__ __launch_bounds__(512) void k5_attn(
    const float* __restrict__ e1h, const float* __restrict__ e2h,
    const float* __restrict__ M2h, const float* __restrict__ E2p, const float* __restrict__ E2n,
    const u16* __restrict__ Whtbf, u16* __restrict__ hcatbf, int nzh)
{
  __shared__ u16 att[64*512];
  __shared__ float inv_lds[64];
  const int orig = blockIdx.x;
  const int xcd = orig & 7;
  const int k = orig >> 3;
  const int nb = k & 7;
  const int zh = xcd * (nzh >> 3) + (k >> 3);
  const int z = zh >> 2, h = zh & 3;
  const int n0 = nb*64;
  const int tid = threadIdx.x;

  // phase A: factorized softmax (double-buffered loads)
  const int r = tid >> 3, qd = tid & 7;
  const float e1n = e1h[(size_t)zh*DD + n0 + r];
  const float M2 = M2h[zh];
  const float s = e1n + M2;
  const float mx = (s > 0.f) ? s : 0.1f*s;
  const float Ap = expf(s - mx);
  const float An = expf(0.1f*s - mx);
  const float thr = -e1n;
  const float* e2r = e2h + (size_t)zh*DD + qd*64;
  const float* Epr = E2p + (size_t)zh*DD + qd*64;
  const float* Enr = E2n + (size_t)zh*DD + qd*64;
  float lsum = 0.f;
  {
    F8 e2a,epa,ena, e2b,epb,enb;
    PA_LD(e2a,epa,ena,0);
    PA_LD(e2b,epb,enb,1);
    PA_PROC(att, e2a,epa,ena,0);
    PA_LD(e2a,epa,ena,2);
    PA_PROC(att, e2b,epb,enb,1);
    PA_LD(e2b,epb,enb,3);
    PA_PROC(att, e2a,epa,ena,2);
    PA_LD(e2a,epa,ena,4);
    PA_PROC(att, e2b,epb,enb,3);
    PA_LD(e2b,epb,enb,5);
    PA_PROC(att, e2a,epa,ena,4);
    PA_LD(e2a,epa,ena,6);
    PA_PROC(att, e2b,epb,enb,5);
    PA_LD(e2b,epb,enb,7);
    PA_PROC(att, e2a,epa,ena,6);
    PA_PROC(att, e2b,epb,enb,7);
  }
  lsum += __shfl_xor(lsum, 1);
  lsum += __shfl_xor(lsum, 2);
  lsum += __shfl_xor(lsum, 4);
  if ((tid & 7) == 0) inv_lds[r] = 1.f / lsum;
  __syncthreads();

  // phase B: PV. 8 waves; wave w owns os column w*16..+15; af LDS reads double-buffered.
  const int w = tid >> 6, l = tid & 63, ln = l & 15, kg = l >> 4;
  const u16* B0 = Whtbf + ((size_t)zh*NHID + w*16 + ln)*DD + kg*8;
  f32x4 acc[4];
  #pragma unroll
  for (int ns=0; ns<4; ++ns) acc[ns] = (f32x4){0,0,0,0};

  short8 Pb,Qb,Rb,Sb;
  short8 af0[4], af1[4];
#define K5_LDB(R0,kkv) do { int kc = ((kkv) < 16) ? (kkv) : 0; \
    R0 = *reinterpret_cast<const short8*>(B0 + (size_t)kc*32); } while(0)
#define K5_AFLD(AF,kkv) do { int kc = ((kkv) < 16) ? (kkv) : 0; \
    _Pragma("unroll") \
    for (int ns = 0; ns < 4; ++ns) { int row = ns*16 + ln; int c = kc*4 + kg; \
      AF[ns] = *reinterpret_cast<const short8*>(&att[row*512 + attsw(c,row)*8]); } } while(0)
#define K5_MM(AF,R0) do { \
    _Pragma("unroll") \
    for (int ns = 0; ns < 4; ++ns) \
      acc[ns] = __builtin_amdgcn_mfma_f32_16x16x32_bf16(AF[ns], R0, acc[ns], 0,0,0); } while(0)

  K5_LDB(Pb,0); K5_LDB(Qb,1); K5_LDB(Rb,2);
  K5_AFLD(af0,0);
  #pragma unroll 1
  for (int kk = 0; kk < 16; kk += 4) {
    K5_LDB(Sb,kk+3); K5_AFLD(af1,kk+1); K5_MM(af0,Pb);
    K5_LDB(Pb,kk+4); K5_AFLD(af0,kk+2); K5_MM(af1,Qb);
    K5_LDB(Qb,kk+5); K5_AFLD(af1,kk+3); K5_MM(af0,Rb);
    K5_LDB(Rb,kk+6); K5_AFLD(af0,kk+4); K5_MM(af1,Sb);
  }
#undef K5_LDB
#undef K5_AFLD
#undef K5_MM

  #pragma unroll
  for (int ns = 0; ns < 4; ++ns)
    #pragma unroll
    for (int rr = 0; rr < 4; ++rr) {
      int n = ns*16 + kg*4 + rr;
      float inv = inv_lds[n];
      float sv = acc[ns][rr] * inv;
      sv = (sv > 0.f) ? sv : expm1f(sv);
      hcatbf[((size_t)z*DD + n0 + n)*DD + h*NHID + w*16 + ln] = f2bf(sv);
    }
}

// ---------- K6: Wh2tbf[z][o][n] = (hcat @ oW^T + ob)^T, B=oW-panel staged ----------
__global__ __launch_bounds__(256) void k6_wh2(
    const u16* __restrict__ hcatbf, const u16* __restrict__ oWbf, const float* __restrict__ ob,
    u16* __restrict__ Wh2tbf)
{
  __shared__ u16 bp[2][64*64];
  const int tid = threadIdx.x;
  const int w = tid >> 6, l = tid & 63, ln = l & 15, kg = l >> 4;
  const int n0 = blockIdx.x*64 + w*16;
  const int o0 = blockIdx.y*64;
  const int z  = blockIdx.z;
  const int sc = tid & 7, sr = tid >> 3;
  const int sp = sc ^ (sr & 7);
  const int sp2 = sc ^ ((sr+32) & 7);
  const u16* B0 = oWbf + (size_t)o0*DD;
  const u16* Asrc = hcatbf + (size_t)(z*DD + n0 + ln)*DD + kg*8;

  f32x4 acc[4];
  #pragma unroll
  for (int os=0;os<4;++os) acc[os] = (f32x4){0.f,0.f,0.f,0.f};
  short8 aP0, aP1, aQ0, aQ1, sg0, sg1;

  sg0 = *reinterpret_cast<const short8*>(B0 + (size_t)sr*DD + sc*8);
  sg1 = *reinterpret_cast<const short8*>(B0 + (size_t)(sr+32)*DD + sc*8);
  aP0 = *reinterpret_cast<const short8*>(Asrc);
  aP1 = *reinterpret_cast<const short8*>(Asrc + 32);
  *reinterpret_cast<short8*>(&bp[0][sr*64 + sp*8]) = sg0;
  *reinterpret_cast<short8*>(&bp[0][(sr+32)*64 + sp2*8]) = sg1;
  __syncthreads();

  int cur = 0;
  #pragma unroll 1
  for (int s = 0; s < 8; ++s) {
    const int fn = (s+1)*64;
    if (s < 7) {
      sg0 = *reinterpret_cast<const short8*>(B0 + (size_t)sr*DD + fn + sc*8);
      sg1 = *reinterpret_cast<const short8*>(B0 + (size_t)(sr+32)*DD + fn + sc*8);
      aQ0 = *reinterpret_cast<const short8*>(Asrc + fn);
      aQ1 = *reinterpret_cast<const short8*>(Asrc + fn + 32);
    }
    #pragma unroll
    for (int os = 0; os < 4; ++os) {
      int row = os*16 + ln;
      short8 b0 = *reinterpret_cast<const short8*>(&bp[cur][row*64 + ((kg ^ (row&7))<<3)]);
      acc[os] = __builtin_amdgcn_mfma_f32_16x16x32_bf16(aP0, b0, acc[os], 0,0,0);
      short8 b1 = *reinterpret_cast<const short8*>(&bp[cur][row*64 + (((4+kg) ^ (row&7))<<3)]);
      acc[os] = __builtin_amdgcn_mfma_f32_16x16x32_bf16(aP1, b1, acc[os], 0,0,0);
    }
    if (s < 7) {
      *reinterpret_cast<short8*>(&bp[cur^1][sr*64 + sp*8]) = sg0;
      *reinterpret_cast<short8*>(&bp[cur^1][(sr+32)*64 + sp2*8]) = sg1;
      __syncthreads();
      cur ^= 1;
      aP0 = aQ0; aP1 = aQ1;
    }
  }
  #pragma unroll
  for (int os=0; os<4; ++os)
    #pragma unroll
    for (int r=0; r<4; ++r) {
      int o = o0 + os*16 + ln;
      int n = n0 + kg*4 + r;
      Wh2tbf[((size_t)z*WW + o)*DD + n] = f2bf(acc[os][r] + ob[o]);
    }
}

// ---------- K7: e1o/e2o ----------
__global__ __launch_bounds__(256) void k7_eout(
    const u16* __restrict__ hcatbf,
    const float* __restrict__ oahat_i, const float* __restrict__ oahat_j,
    const float* __restrict__ cvec,
    float* __restrict__ e1, float* __restrict__ e2)
{
  int row = blockIdx.x*4 + (threadIdx.x >> 6);
  int lane = threadIdx.x & 63;
  BF8 v8; v8.v = *reinterpret_cast<const short8*>(hcatbf + (size_t)row*DD + lane*8);
  float a1 = 0.f, a2 = 0.f;
  #pragma unroll
  for (int j = 0; j < 8; ++j) {
    float vf = bf2f(v8.u[j]);
    a1 += vf * oahat_i[lane*8 + j];
    a2 += vf * oahat_j[lane*8 + j];
  }
  #pragma unroll
  for (int off = 32; off >= 1; off >>= 1) { a1 += __shfl_xor(a1, off); a2 += __shfl_xor(a2, off); }
  if (lane == 0) { e1[row] = a1 + cvec[8]; e2[row] = a2 + cvec[9]; }
}

// ---------- K8a: out attention PV; 8 waves, pipelined -> g f32 (elu) ----------
__global__ __launch_bounds__(512) void k8_pv(
    const float* __restrict__ e1o, const float* __restrict__ e2o,
    const float* __restrict__ M2o, const float* __restrict__ E2p, const float* __restrict__ E2n,
    const u16* __restrict__ Wh2tbf, float* __restrict__ g, int CBv)
{
  __shared__ u16 att[64*512];
  __shared__ float inv_lds[64];
  const int orig = blockIdx.x;
  int nb, z, oh;
  if (CBv >= 8) {
    int xcd = orig & 7;
    int k = orig >> 3;
    nb = k & 7;
    int rest = k >> 3;
    oh = rest & 1;
    z = xcd * (CBv >> 3) + (rest >> 1);
  } else {
    nb = orig & 7;
    int k = orig >> 3;
    z = k >> 1;
    oh = k & 1;
  }
  const int n0 = nb*64;
  const int tid = threadIdx.x;

  const int r = tid >> 3, qd = tid & 7;
  const float e1n = e1o[(size_t)z*DD + n0 + r];
  const float M2 = M2o[z];
  const float s = e1n + M2;
  const float mx = (s > 0.f) ? s : 0.1f*s;
  const float Ap = expf(s - mx);
  const float An = expf(0.1f*s - mx);
  const float thr = -e1n;
  const float* e2r = e2o + (size_t)z*DD + qd*64;
  const float* Epr = E2p + (size_t)z*DD + qd*64;
  const float* Enr = E2n + (size_t)z*DD + qd*64;
  float lsum = 0.f;
  {
    F8 e2a,epa,ena, e2b,epb,enb;
    PA_LD(e2a,epa,ena,0);
    PA_LD(e2b,epb,enb,1);
    PA_PROC(att, e2a,epa,ena,0);
    PA_LD(e2a,epa,ena,2);
    PA_PROC(att, e2b,epb,enb,1);
    PA_LD(e2b,epb,enb,3);
    PA_PROC(att, e2a,epa,ena,2);
    PA_LD(e2a,epa,ena,4);
    PA_PROC(att, e2b,epb,enb,3);
    PA_LD(e2b,epb,enb,5);
    PA_PROC(att, e2a,epa,ena,4);
    PA_LD(e2a,epa,ena,6);
    PA_PROC(att, e2b,epb,enb,5);
    PA_LD(e2b,epb,enb,7);
    PA_PROC(att, e2a,epa,ena,6);
    PA_PROC(att, e2b,epb,enb,7);
  }
  lsum += __shfl_xor(lsum, 1);
  lsum += __shfl_xor(lsum, 2);
  lsum += __shfl_xor(lsum, 4);
  if ((tid & 7) == 0) inv_lds[r] = 1.f / lsum;
  __syncthreads();

  const int w = tid >> 6, l = tid & 63, ln = l & 15, kg = l >> 4;
  const u16* B0 = Wh2tbf + ((size_t)z*WW + oh*128 + w*16 + ln)*DD + kg*8;
  f32x4 acc[4];
  #pragma unroll
  for (int ns=0; ns<4; ++ns) acc[ns] = (f32x4){0,0,0,0};

  short8 Pb,Qb,Rb,Sb;
  short8 af0[4], af1[4];
#define K8_LDB(R0,kkv) do { int kc = ((kkv) < 16) ? (kkv) : 0; \
    R0 = *reinterpret_cast<const short8*>(B0 + (size_t)kc*32); } while(0)
#define K8_AFLD(AF,kkv) do { int kc = ((kkv) < 16) ? (kkv) : 0; \
    _Pragma("unroll") \
    for (int ns = 0; ns < 4; ++ns) { int row = ns*16 + ln; int c = kc*4 + kg; \
      AF[ns] = *reinterpret_cast<const short8*>(&att[row*512 + attsw(c,row)*8]); } } while(0)
#define K8_MM(AF,R0) do { \
    _Pragma("unroll") \
    for (int ns = 0; ns < 4; ++ns) \
      acc[ns] = __builtin_amdgcn_mfma_f32_16x16x32_bf16(AF[ns], R0, acc[ns], 0,0,0); } while(0)

  K8_LDB(Pb,0); K8_LDB(Qb,1); K8_LDB(Rb,2);
  K8_AFLD(af0,0);
  #pragma unroll 1
  for (int kk = 0; kk < 16; kk += 4) {
    K8_LDB(Sb,kk+3); K8_AFLD(af1,kk+1); K8_MM(af0,Pb);
    K8_LDB(Pb,kk+4); K8_AFLD(af0,kk+2); K8_MM(af1,Qb);
    K8_LDB(Qb,kk+5); K8_AFLD(af1,kk+3); K8_MM(af0,Rb);
    K8_LDB(Rb,kk+6); K8_AFLD(af0,kk+4); K8_MM(af1,Sb);
  }
#undef K8_LDB
#undef K8_AFLD
#undef K8_MM

  #pragma unroll
  for (int ns = 0; ns < 4; ++ns)
    #pragma unroll
    for (int rr = 0; rr < 4; ++rr) {
      int n = ns*16 + kg*4 + rr;
      float inv = inv_lds[n];
      float val = acc[ns][rr] * inv;
      val = (val > 0.f) ? val : expm1f(val);    // elu
      g[((size_t)z*DD + n0 + n)*WW + oh*128 + w*16 + ln] = val;
    }
}

// ---------- K8b: row log_softmax over o(256) -> gaty bf16 ----------
__global__ __launch_bounds__(256) void k8_lsm(
    const float* __restrict__ g, u16* __restrict__ gatybf)
{
  int row = blockIdx.x*4 + (threadIdx.x >> 6);
  int lane = threadIdx.x & 63;
  const float* gr = g + (size_t)row*WW;
  float v0 = gr[lane], v1 = gr[lane+64], v2 = gr[lane+128], v3 = gr[lane+192];
  float mx = fmaxf(fmaxf(v0,v1), fmaxf(v2,v3));
  #pragma unroll
  for (int off = 32; off >= 1; off >>= 1) mx = fmaxf(mx, __shfl_xor(mx, off));
  float sm = expf(v0-mx) + expf(v1-mx) + expf(v2-mx) + expf(v3-mx);
  #pragma unroll
  for (int off = 32; off >= 1; off >>= 1) sm += __shfl_xor(sm, off);
  float lg = mx + logf(sm);
  u16* go = gatybf + (size_t)row*WW;
  go[lane]     = f2bf(v0 - lg);
  go[lane+64]  = f2bf(v1 - lg);
  go[lane+128] = f2bf(v2 - lg);
  go[lane+192] = f2bf(v3 - lg);
}

// ---------- K9: out = gaty^T @ pW^T + pb ----------
__global__ __launch_bounds__(256) void k9_proj(
    const u16* __restrict__ gatybf, const u16* __restrict__ pWbf, const float* __restrict__ pb,
    int zb, float* __restrict__ out0)
{
  __shared__ u16 gt[64*40];
  const int t0 = blockIdx.x*64, d0 = blockIdx.y*64, z = blockIdx.z;
  const int tid = threadIdx.x;
  const int w = tid >> 6, l = tid & 63, ln = l & 15, kg = l >> 4;
  const int el = tid >> 3, t8 = tid & 7;
  f32x4 acc[4];
  #pragma unroll
  for (int os=0;os<4;++os) acc[os] = (f32x4){0.f,0.f,0.f,0.f};
  for (int e0 = 0; e0 < DD; e0 += 32) {
    __syncthreads();
    BF8 g8;
    g8.v = *reinterpret_cast<const short8*>(gatybf + ((size_t)z*DD + e0 + el)*WW + t0 + t8*8);
    #pragma unroll
    for (int j = 0; j < 8; ++j) gt[(t8*8 + j)*40 + el] = g8.u[j];
    __syncthreads();
    short8 a = *reinterpret_cast<const short8*>(&gt[(w*16 + ln)*40 + kg*8]);
    #pragma unroll
    for (int os = 0; os < 4; ++os) {
      short8 b = *reinterpret_cast<const short8*>(pWbf + (size_t)(d0 + os*16 + ln)*DD + e0 + kg*8);
      acc[os] = __builtin_amdgcn_mfma_f32_16x16x32_bf16(a, b, acc[os], 0,0,0);
    }
  }
  #pragma unroll
  for (int os=0; os<4; ++os)
    #pragma unroll
    for (int rr=0; rr<4; ++rr) {
      int t = t0 + w*16 + kg*4 + rr;
      int d = d0 + os*16 + ln;
      out0[((size_t)(zb+z)*WW + t)*DD + d] = acc[os][rr] + pb[d];
    }
}

extern "C" void kernel_launch(void* const* d_in, const int* in_sizes, int n_in,
                              void* d_out, int out_size, void* d_ws, size_t ws_size,
                              hipStream_t stream)
{
  const float* x   = (const float*)d_in[0];
  const float* qW  = (const float*)d_in[1];
  const float* qb  = (const float*)d_in[2];
  const float* kW  = (const float*)d_in[3];
  const float* kb  = (const float*)d_in[4];
  const float* vW  = (const float*)d_in[5];
  const float* vb  = (const float*)d_in[6];
  const float* hW  = (const float*)d_in[7];
  const float* hb  = (const float*)d_in[8];
  const float* hai = (const float*)d_in[9];
  const float* haib= (const float*)d_in[10];
  const float* haj = (const float*)d_in[11];
  const float* hajb= (const float*)d_in[12];
  const float* oW  = (const float*)d_in[13];
  const float* ob  = (const float*)d_in[14];
  const float* oai = (const float*)d_in[15];
  const float* oaib= (const float*)d_in[16];
  const float* oaj = (const float*)d_in[17];
  const float* oajb= (const float*)d_in[18];
  const float* pW  = (const float*)d_in[19];
  const float* pb  = (const float*)d_in[20];

  float* out0 = (float*)d_out;                   // [B,W,D] f32
  float* adjo = out0 + (size_t)BB*WW*DD;         // [B,D,D] f32

  // static region (float offsets)
  float* ws      = (float*)d_ws;
  u16*   Wt      = (u16*)(ws + 0);           // 1,179,648 f
  u16*   hWbf    = (u16*)(ws + 1179648);     //    65,536 f
  u16*   oWbf    = (u16*)(ws + 1245184);     //    65,536 f
  u16*   pWbf    = (u16*)(ws + 1310720);     //   131,072 f
  float* ahat_i  = ws + 1441792;
  float* ahat_j  = ws + 1442816;
  float* oahat_i = ws + 1443840;
  float* oahat_j = ws + 1444352;
  float* cvec    = ws + 1444864;
  float* e1h     = ws + 1444880;             //    65,536 f (CB=32 max)
  float* e2h     = ws + 1510416;
  float* e1o     = ws + 1575952;             //    16,384 f
  float* e2o     = ws + 1592336;
  float* M2h     = ws + 1608720;             //       128 f
  float* E2hp    = ws + 1608848;             //    65,536 f
  float* E2hn    = ws + 1674384;             //    65,536 f
  float* M2o     = ws + 1739920;             //        32 f
  float* E2op    = ws + 1739952;             //    16,384 f
  float* E2on    = ws + 1756336;             //    16,384 f
  const size_t X0 = 1772720;                 // dynamic region start

  // per-CB dynamic: xpad 66,048 + vbf 65,536 + qbf 65,536 + kbf 65,536 + Whtbf 131,072 = 393,728 f
  int CB = 4;
  {
    const int cand[3] = {32, 16, 8};
    for (int i = 0; i < 3; ++i) {
      size_t need = (X0 + (size_t)cand[i]*393728) * 4;
      if (need <= ws_size) { CB = cand[i]; break; }
    }
  }

  u16* xpad   = (u16*)(ws + X0);                        // CB*66,048 f  ([z][258][512])
  u16* vbf    = (u16*)(ws + X0 + (size_t)CB*66048);     // CB*65,536 f
  u16* qbf    = (u16*)(ws + X0 + (size_t)CB*131584);    // CB*65,536 f
  u16* kbf    = (u16*)(ws + X0 + (size_t)CB*197120);    // CB*65,536 f
  u16* Whtbf  = (u16*)(ws + X0 + (size_t)CB*262656);    // CB*131,072 f
  // overlays (lifetimes: xpad dead after k1; vbf dead after k4; qbf,kbf dead after k2;
  // hcatbf dead after k7; Whtbf dead after k5)
  u16*   hcatbf = (u16*)(ws + X0);                      // over xpad+vbf
  float* g      = (float*)(ws + X0);                    // over hcatbf region (k8 phase)
  u16*   gatybf = (u16*)(ws + X0 + (size_t)CB*131584);  // over qbf
  u16*   Wh2tbf = (u16*)(ws + X0 + (size_t)CB*197120);  // over kbf

  kprep_w<<<dim3((3*DD*DD + 255)/256), 256, 0, stream>>>(qW, kW, vW, Wt);
  kcvt<<<dim3((NHEADS*NHID*WW + 255)/256), 256, 0, stream>>>(hW, hWbf, NHEADS*NHID*WW);
  kcvt<<<dim3((WW*DD + 255)/256), 256, 0, stream>>>(oW, oWbf, WW*DD);
  kcvt<<<dim3((DD*DD + 255)/256), 256, 0, stream>>>(pW, pWbf, DD*DD);
  kprep_a<<<dim3(13), 256, 0, stream>>>(hW, hai, haib, haj, hajb, hb,
                                        oW, oai, oaib, oaj, oajb, ob,
                                        ahat_i, ahat_j, oahat_i, oahat_j, cvec);

  for (int zb = 0; zb < BB; zb += CB) {
    int nrow8 = CB*258*64;
    kprep_x  <<<dim3((nrow8 + 255)/256), 256, 0, stream>>>(x, zb, nrow8, xpad);
    k1_mfma  <<<dim3(DD/64, WW/128, CB), 256, 0, stream>>>(xpad, Wt, qb, kb, vb, qbf, kbf, vbf);
    k2_adj   <<<dim3(DD/64, DD/64, CB), 256, 0, stream>>>(qbf, kbf, zb, adjo);
    k3_wh    <<<dim3(DD/64, NHID/64, CB*NHEADS), 256, 0, stream>>>(vbf, hWbf, hb, Whtbf);
    k4_eheads<<<dim3(CB*NHEADS*DD/4), 256, 0, stream>>>(vbf, ahat_i, ahat_j, cvec, e1h, e2h);
    kexp2    <<<dim3(CB*NHEADS), 256, 0, stream>>>(e2h, M2h, E2hp, E2hn);
    k5_attn  <<<dim3(32*CB), 512, 0, stream>>>(e1h, e2h, M2h, E2hp, E2hn, Whtbf, hcatbf, CB*NHEADS);
    k6_wh2   <<<dim3(DD/64, WW/64, CB), 256, 0, stream>>>(hcatbf, oWbf, ob, Wh2tbf);
    k7_eout  <<<dim3(CB*DD/4), 256, 0, stream>>>(hcatbf, oahat_i, oahat_j, cvec, e1o, e2o);
    kexp2    <<<dim3(CB), 256, 0, stream>>>(e2o, M2o, E2op, E2on);
    k8_pv    <<<dim3(16*CB), 512, 0, stream>>>(e1o, e2o, M2o, E2op, E2on, Wh2tbf, g, CB);
    k8_lsm   <<<dim3(CB*128), 256, 0, stream>>>(g, gatybf);
    k9_proj  <<<dim3(WW/64, DD/64, CB), 256, 0, stream>>>(gatybf, pWbf, pb, zb, out0);
  }
}

// Round 18
// 303.659 us; speedup vs baseline: 1.0934x; 1.0249x over previous
//
#include <hip/hip_runtime.h>
#include <math.h>

typedef unsigned short u16;
typedef __attribute__((ext_vector_type(8))) short short8;
typedef __attribute__((ext_vector_type(4))) float f32x4;

#define BB 32
#define WW 256
#define DD 512
#define NHEADS 4
#define NHID 128

__device__ __forceinline__ u16 f2bf(float f) {
  union { float f; unsigned int i; } x; x.f = f;
  unsigned int i = x.i;
  i += 0x7fffu + ((i >> 16) & 1u);
  return (u16)(i >> 16);
}
__device__ __forceinline__ float bf2f(u16 u) {
  union { float f; unsigned int i; } x; x.i = ((unsigned int)u) << 16; return x.f;
}

union BF8 { short8 v; u16 u[8]; };
union BF4 { ushort4 v; u16 u[4]; };
union F8 { float4 v4[2]; float f[8]; };

// ---------- prep (once) ----------
__global__ __launch_bounds__(256) void kprep_w(
    const float* __restrict__ qW, const float* __restrict__ kW, const float* __restrict__ vW,
    u16* __restrict__ Wt)
{
  int idx = blockIdx.x*256 + threadIdx.x;     // (c, o, i)
  if (idx >= 3*DD*DD) return;
  int c = idx >> 18;
  int oi = idx & (DD*DD - 1);
  int i = oi & (DD-1);
  int o = oi >> 9;
  const float* W = (c==0) ? qW : (c==1) ? kW : vW;
  float w0 = W[oi*3+0], w1 = W[oi*3+1], w2 = W[oi*3+2];
  Wt[((size_t)(c*3+0)*DD + o)*DD + i] = f2bf(w0);
  Wt[((size_t)(c*3+1)*DD + o)*DD + i] = f2bf(w1);
  Wt[((size_t)(c*3+2)*DD + o)*DD + i] = f2bf(w2);
}

__global__ __launch_bounds__(256) void kcvt(const float* __restrict__ s, u16* __restrict__ d, int n) {
  int i = blockIdx.x*256 + threadIdx.x;
  if (i < n) d[i] = f2bf(s[i]);
}

__global__ __launch_bounds__(256) void kprep_a(
    const float* __restrict__ hW, const float* __restrict__ hai, const float* __restrict__ haib,
    const float* __restrict__ haj, const float* __restrict__ hajb,
    const float* __restrict__ hb,
    const float* __restrict__ oW, const float* __restrict__ oai, const float* __restrict__ oaib,
    const float* __restrict__ oaj, const float* __restrict__ oajb,
    const float* __restrict__ ob,
    float* __restrict__ ahat_i, float* __restrict__ ahat_j,
    float* __restrict__ oahat_i, float* __restrict__ oahat_j,
    float* __restrict__ cvec)
{
  int idx = blockIdx.x*256 + threadIdx.x;
  if (idx < 1024) {
    int h = idx >> 8, f = idx & 255;
    float s = 0.f;
    for (int o = 0; o < NHID; ++o) s += hW[((size_t)h*NHID + o)*WW + f] * hai[h*NHID + o];
    ahat_i[idx] = s;
  } else if (idx < 2048) {
    int t = idx - 1024; int h = t >> 8, f = t & 255;
    float s = 0.f;
    for (int o = 0; o < NHID; ++o) s += hW[((size_t)h*NHID + o)*WW + f] * haj[h*NHID + o];
    ahat_j[t] = s;
  } else if (idx < 2560) {
    int f = idx - 2048;
    float s = 0.f;
    for (int o = 0; o < WW; ++o) s += oW[(size_t)o*DD + f] * oai[o];
    oahat_i[f] = s;
  } else if (idx < 3072) {
    int f = idx - 2560;
    float s = 0.f;
    for (int o = 0; o < WW; ++o) s += oW[(size_t)o*DD + f] * oaj[o];
    oahat_j[f] = s;
  } else if (idx < 3082) {
    int t = idx - 3072;
    if (t < 4) {
      float s = 0.f;
      for (int o = 0; o < NHID; ++o) s += hb[t*NHID + o]*hai[t*NHID + o];
      cvec[t] = s + haib[t];
    } else if (t < 8) {
      int h = t - 4; float s = 0.f;
      for (int o = 0; o < NHID; ++o) s += hb[h*NHID + o]*haj[h*NHID + o];
      cvec[t] = s + hajb[h];
    } else if (t == 8) {
      float s = 0.f;
      for (int o = 0; o < WW; ++o) s += ob[o]*oai[o];
      cvec[8] = s + oaib[0];
    } else {
      float s = 0.f;
      for (int o = 0; o < WW; ++o) s += ob[o]*oaj[o];
      cvec[9] = s + oajb[0];
    }
  }
}

// x f32 -> xpad bf16 [z][258][512] with zero halo rows (t=-1, t=256)
__global__ __launch_bounds__(256) void kprep_x(
    const float* __restrict__ x, int zb, int nrow8, u16* __restrict__ xpad)
{
  int idx8 = blockIdx.x*256 + threadIdx.x;
  if (idx8 >= nrow8) return;
  int i8 = idx8 & 63;
  int rowg = idx8 >> 6;                       // z*258 + r
  int z = rowg / 258, r = rowg - z*258;
  int t = r - 1;
  BF8 o8;
  if (t >= 0 && t < WW) {
    const float* src = x + ((size_t)(zb+z)*WW + t)*DD + i8*8;
    float4 v0 = *reinterpret_cast<const float4*>(src);
    float4 v1 = *reinterpret_cast<const float4*>(src + 4);
    o8.u[0]=f2bf(v0.x); o8.u[1]=f2bf(v0.y); o8.u[2]=f2bf(v0.z); o8.u[3]=f2bf(v0.w);
    o8.u[4]=f2bf(v1.x); o8.u[5]=f2bf(v1.y); o8.u[6]=f2bf(v1.z); o8.u[7]=f2bf(v1.w);
  } else {
    #pragma unroll
    for (int j = 0; j < 8; ++j) o8.u[j] = 0;
  }
  *reinterpret_cast<short8*>(xpad + (size_t)rowg*DD + i8*8) = o8.v;
}

// kexp2: per row-group (512 e2 values): M2 = max, E2p = exp(e2-M2), E2n = exp(0.1(e2-M2))
__global__ __launch_bounds__(256) void kexp2(
    const float* __restrict__ e2, float* __restrict__ M2,
    float* __restrict__ E2p, float* __restrict__ E2n)
{
  __shared__ float s4[4];
  const int zh = blockIdx.x, tid = threadIdx.x;
  float v0 = e2[(size_t)zh*DD + tid], v1 = e2[(size_t)zh*DD + 256 + tid];
  float m = fmaxf(v0, v1);
  #pragma unroll
  for (int off=32; off>=1; off>>=1) m = fmaxf(m, __shfl_xor(m, off));
  if ((tid & 63) == 0) s4[tid >> 6] = m;
  __syncthreads();
  m = fmaxf(fmaxf(s4[0], s4[1]), fmaxf(s4[2], s4[3]));
  if (tid == 0) M2[zh] = m;
  E2p[(size_t)zh*DD + tid]       = expf(v0 - m);
  E2p[(size_t)zh*DD + 256 + tid] = expf(v1 - m);
  E2n[(size_t)zh*DD + tid]       = expf(0.1f*(v0 - m));
  E2n[(size_t)zh*DD + 256 + tid] = expf(0.1f*(v1 - m));
}

// ---------- K1: conv via MFMA; 64o x 128t tile; B LDS-staged; A double-buffered ----------
__global__ __launch_bounds__(256) void k1_mfma(
    const u16* __restrict__ xpad, const u16* __restrict__ Wt,
    const float* __restrict__ qb, const float* __restrict__ kb, const float* __restrict__ vb,
    u16* __restrict__ qbf, u16* __restrict__ kbf, u16* __restrict__ vbf)
{
  __shared__ u16 bt[2][130*64];
  const int tid = threadIdx.x;
  const int w  = tid >> 6;
  const int l  = tid & 63;
  const int ln = l & 15;
  const int kg = l >> 4;
  const int og = blockIdx.x * 64 + w * 16;
  const int t0 = blockIdx.y * 128;
  const int z  = blockIdx.z;

  const u16* A0 = Wt + (size_t)(og + ln)*DD + kg*8;
  const u16* Xb = xpad + ((size_t)z*258 + t0)*DD;

  f32x4 acc[3][8];
  #pragma unroll
  for (int c=0;c<3;++c)
    #pragma unroll
    for (int ts=0;ts<8;++ts) acc[c][ts] = (f32x4){0.f,0.f,0.f,0.f};

  short8 ArP[9], ArQ[9];
  short8 sg0, sg1, sg2, sg3, sg4;
  const int ccw = tid & 7;
  const int rs = tid >> 3;

#define K1_LOADX(i0v) do { \
    sg0 = *reinterpret_cast<const short8*>(Xb + (size_t)rs*DD + (i0v) + ccw*8); \
    sg1 = *reinterpret_cast<const short8*>(Xb + (size_t)(rs+32)*DD + (i0v) + ccw*8); \
    sg2 = *reinterpret_cast<const short8*>(Xb + (size_t)(rs+64)*DD + (i0v) + ccw*8); \
    sg3 = *reinterpret_cast<const short8*>(Xb + (size_t)(rs+96)*DD + (i0v) + ccw*8); \
    if (tid < 16) sg4 = *reinterpret_cast<const short8*>(Xb + (size_t)(rs+128)*DD + (i0v) + ccw*8); \
  } while(0)

#define K1_WRITEX(bufv) do { \
    *reinterpret_cast<short8*>(&bt[bufv][rs*64 + ((ccw^(rs&7))<<3)]) = sg0; \
    *reinterpret_cast<short8*>(&bt[bufv][(rs+32)*64 + ((ccw^((rs+32)&7))<<3)]) = sg1; \
    *reinterpret_cast<short8*>(&bt[bufv][(rs+64)*64 + ((ccw^((rs+64)&7))<<3)]) = sg2; \
    *reinterpret_cast<short8*>(&bt[bufv][(rs+96)*64 + ((ccw^((rs+96)&7))<<3)]) = sg3; \
    if (tid < 16) *reinterpret_cast<short8*>(&bt[bufv][(rs+128)*64 + ((ccw^((rs+128)&7))<<3)]) = sg4; \
  } while(0)

#define K1_LOADA(Abuf, i0v, khv) do { \
    _Pragma("unroll") \
    for (int c = 0; c < 3; ++c) { \
      _Pragma("unroll") \
      for (int tap = 0; tap < 3; ++tap) \
        Abuf[c*3+tap] = *reinterpret_cast<const short8*>(A0 + (size_t)(c*3+tap)*DD*DD + (i0v) + (khv)*32); \
    } \
  } while(0)

#define K1_MFMAS(Abuf, khv) do { \
    _Pragma("unroll") \
    for (int tap = 0; tap < 3; ++tap) { \
      _Pragma("unroll") \
      for (int ts = 0; ts < 8; ++ts) { \
        int row = ts*16 + ln + tap; \
        short8 bfr = *reinterpret_cast<const short8*>(&bt[cur][row*64 + ((((khv)*4+kg) ^ (row&7))<<3)]); \
        acc[0][ts] = __builtin_amdgcn_mfma_f32_16x16x32_bf16(Abuf[0*3+tap], bfr, acc[0][ts], 0,0,0); \
        acc[1][ts] = __builtin_amdgcn_mfma_f32_16x16x32_bf16(Abuf[1*3+tap], bfr, acc[1][ts], 0,0,0); \
        acc[2][ts] = __builtin_amdgcn_mfma_f32_16x16x32_bf16(Abuf[2*3+tap], bfr, acc[2][ts], 0,0,0); \
      } \
    } \
  } while(0)

  K1_LOADX(0);
  K1_LOADA(ArP, 0, 0);
  K1_WRITEX(0);
  __syncthreads();

  int cur = 0;
  #pragma unroll 1
  for (int p = 0; p < 8; ++p) {
    const int i0 = p*64;
    if (p < 7) K1_LOADX(i0 + 64);
    K1_LOADA(ArQ, i0, 1);
    K1_MFMAS(ArP, 0);
    const int i0n = (p < 7) ? i0 + 64 : 0;
    K1_LOADA(ArP, i0n, 0);
    K1_MFMAS(ArQ, 1);
    if (p < 7) {
      K1_WRITEX(cur ^ 1);
      __syncthreads();
      cur ^= 1;
    }
  }

#undef K1_LOADX
#undef K1_WRITEX
#undef K1_LOADA
#undef K1_MFMAS

  #pragma unroll
  for (int ts=0; ts<8; ++ts) {
    int tg = t0 + ts*16 + ln;
    #pragma unroll
    for (int r=0;r<4;++r) {
      int o = og + kg*4 + r;
      size_t oi = (size_t)(z*DD + o)*WW + tg;
      qbf[oi] = f2bf(acc[0][ts][r] + qb[o]);
      kbf[oi] = f2bf(acc[1][ts][r] + kb[o]);
      vbf[oi] = f2bf(acc[2][ts][r] + vb[o]);
    }
  }
}

// ---------- K2: adj = sigmoid(q.kT * scale), B=k-panel staged ----------
__global__ __launch_bounds__(256) void k2_adj(
    const u16* __restrict__ qbf, const u16* __restrict__ kbf, int zb, float* __restrict__ adjo)
{
  __shared__ u16 bp[2][64*64];
  const int tid = threadIdx.x;
  const int w = tid >> 6, l = tid & 63, ln = l & 15, kg = l >> 4;
  const int d0 = blockIdx.x*64 + w*16;
  const int e0 = blockIdx.y*64;
  const int z  = blockIdx.z;
  const int sc = tid & 7, sr = tid >> 3;
  const int sp = sc ^ (sr & 7);
  const int sp2 = sc ^ ((sr+32) & 7);
  const u16* B0 = kbf + (size_t)(z*DD + e0)*WW;
  const u16* Asrc = qbf + (size_t)(z*DD + d0 + ln)*WW + kg*8;

  f32x4 acc[4];
  #pragma unroll
  for (int es=0;es<4;++es) acc[es] = (f32x4){0.f,0.f,0.f,0.f};
  short8 aP0, aP1, aQ0, aQ1, sg0, sg1;

  sg0 = *reinterpret_cast<const short8*>(B0 + (size_t)sr*WW + sc*8);
  sg1 = *reinterpret_cast<const short8*>(B0 + (size_t)(sr+32)*WW + sc*8);
  aP0 = *reinterpret_cast<const short8*>(Asrc);
  aP1 = *reinterpret_cast<const short8*>(Asrc + 32);
  *reinterpret_cast<short8*>(&bp[0][sr*64 + sp*8]) = sg0;
  *reinterpret_cast<short8*>(&bp[0][(sr+32)*64 + sp2*8]) = sg1;
  __syncthreads();

  int cur = 0;
  #pragma unroll 1
  for (int s = 0; s < 4; ++s) {
    const int fn = (s+1)*64;
    if (s < 3) {
      sg0 = *reinterpret_cast<const short8*>(B0 + (size_t)sr*WW + fn + sc*8);
      sg1 = *reinterpret_cast<const short8*>(B0 + (size_t)(sr+32)*WW + fn + sc*8);
      aQ0 = *reinterpret_cast<const short8*>(Asrc + fn);
      aQ1 = *reinterpret_cast<const short8*>(Asrc + fn + 32);
    }
    #pragma unroll
    for (int es = 0; es < 4; ++es) {
      int row = es*16 + ln;
      short8 b0 = *reinterpret_cast<const short8*>(&bp[cur][row*64 + ((kg ^ (row&7))<<3)]);
      acc[es] = __builtin_amdgcn_mfma_f32_16x16x32_bf16(aP0, b0, acc[es], 0,0,0);
      short8 b1 = *reinterpret_cast<const short8*>(&bp[cur][row*64 + (((4+kg) ^ (row&7))<<3)]);
      acc[es] = __builtin_amdgcn_mfma_f32_16x16x32_bf16(aP1, b1, acc[es], 0,0,0);
    }
    if (s < 3) {
      *reinterpret_cast<short8*>(&bp[cur^1][sr*64 + sp*8]) = sg0;
      *reinterpret_cast<short8*>(&bp[cur^1][(sr+32)*64 + sp2*8]) = sg1;
      __syncthreads();
      cur ^= 1;
      aP0 = aQ0; aP1 = aQ1;
    }
  }
  const float scale = 0.044194173824159216f;
  #pragma unroll
  for (int es=0; es<4; ++es)
    #pragma unroll
    for (int r=0; r<4; ++r) {
      float sig = 1.f/(1.f + expf(-acc[es][r]*scale));
      adjo[((size_t)(zb+z)*DD + d0 + kg*4 + r)*DD + e0 + es*16 + ln] = sig;
    }
}

// ---------- K3: Whtbf[zh][o][n] = (v @ hW^T + hb)^T, B=hW-panel staged ----------
__global__ __launch_bounds__(256) void k3_wh(
    const u16* __restrict__ vbf, const u16* __restrict__ hWbf, const float* __restrict__ hb,
    u16* __restrict__ Whtbf)
{
  __shared__ u16 bp[2][64*64];
  const int tid = threadIdx.x;
  const int w = tid >> 6, l = tid & 63, ln = l & 15, kg = l >> 4;
  const int n0 = blockIdx.x*64 + w*16;
  const int o0 = blockIdx.y*64;
  const int zh = blockIdx.z, z = zh >> 2, h = zh & 3;
  const int sc = tid & 7, sr = tid >> 3;
  const int sp = sc ^ (sr & 7);
  const int sp2 = sc ^ ((sr+32) & 7);
  const u16* B0 = hWbf + (size_t)(h*NHID + o0)*WW;
  const u16* Asrc = vbf + (size_t)(z*DD + n0 + ln)*WW + kg*8;

  f32x4 acc[4];
  #pragma unroll
  for (int os=0;os<4;++os) acc[os] = (f32x4){0.f,0.f,0.f,0.f};
  short8 aP0, aP1, aQ0, aQ1, sg0, sg1;

  sg0 = *reinterpret_cast<const short8*>(B0 + (size_t)sr*WW + sc*8);
  sg1 = *reinterpret_cast<const short8*>(B0 + (size_t)(sr+32)*WW + sc*8);
  aP0 = *reinterpret_cast<const short8*>(Asrc);
  aP1 = *reinterpret_cast<const short8*>(Asrc + 32);
  *reinterpret_cast<short8*>(&bp[0][sr*64 + sp*8]) = sg0;
  *reinterpret_cast<short8*>(&bp[0][(sr+32)*64 + sp2*8]) = sg1;
  __syncthreads();

  int cur = 0;
  #pragma unroll 1
  for (int s = 0; s < 4; ++s) {
    const int fn = (s+1)*64;
    if (s < 3) {
      sg0 = *reinterpret_cast<const short8*>(B0 + (size_t)sr*WW + fn + sc*8);
      sg1 = *reinterpret_cast<const short8*>(B0 + (size_t)(sr+32)*WW + fn + sc*8);
      aQ0 = *reinterpret_cast<const short8*>(Asrc + fn);
      aQ1 = *reinterpret_cast<const short8*>(Asrc + fn + 32);
    }
    #pragma unroll
    for (int os = 0; os < 4; ++os) {
      int row = os*16 + ln;
      short8 b0 = *reinterpret_cast<const short8*>(&bp[cur][row*64 + ((kg ^ (row&7))<<3)]);
      acc[os] = __builtin_amdgcn_mfma_f32_16x16x32_bf16(aP0, b0, acc[os], 0,0,0);
      short8 b1 = *reinterpret_cast<const short8*>(&bp[cur][row*64 + (((4+kg) ^ (row&7))<<3)]);
      acc[os] = __builtin_amdgcn_mfma_f32_16x16x32_bf16(aP1, b1, acc[os], 0,0,0);
    }
    if (s < 3) {
      *reinterpret_cast<short8*>(&bp[cur^1][sr*64 + sp*8]) = sg0;
      *reinterpret_cast<short8*>(&bp[cur^1][(sr+32)*64 + sp2*8]) = sg1;
      __syncthreads();
      cur ^= 1;
      aP0 = aQ0; aP1 = aQ1;
    }
  }
  #pragma unroll
  for (int os=0; os<4; ++os)
    #pragma unroll
    for (int r=0; r<4; ++r) {
      int o = o0 + os*16 + ln;
      int n = n0 + kg*4 + r;
      Whtbf[((size_t)zh*NHID + o)*DD + n] = f2bf(acc[os][r] + hb[h*NHID + o]);
    }
}

// ---------- K4: e1h/e2h ----------
__global__ __launch_bounds__(256) void k4_eheads(
    const u16* __restrict__ vbf,
    const float* __restrict__ ahat_i, const float* __restrict__ ahat_j,
    const float* __restrict__ cvec,
    float* __restrict__ e1, float* __restrict__ e2)
{
  int row = blockIdx.x*4 + (threadIdx.x >> 6);   // row = zh*512 + n
  int lane = threadIdx.x & 63;
  int zh = row >> 9, n = row & 511;
  int z = zh >> 2, h = zh & 3;
  BF4 v4; v4.v = *reinterpret_cast<const ushort4*>(vbf + ((size_t)(z*DD + n))*WW + lane*4);
  const float* aif = ahat_i + h*WW + lane*4;
  const float* ajf = ahat_j + h*WW + lane*4;
  float a1 = 0.f, a2 = 0.f;
  #pragma unroll
  for (int j = 0; j < 4; ++j) {
    float vf = bf2f(v4.u[j]);
    a1 += vf * aif[j];
    a2 += vf * ajf[j];
  }
  #pragma unroll
  for (int off = 32; off >= 1; off >>= 1) { a1 += __shfl_xor(a1, off); a2 += __shfl_xor(a2, off); }
  if (lane == 0) { e1[row] = a1 + cvec[h]; e2[row] = a2 + cvec[4+h]; }
}

// swizzled att chunk index
__device__ __forceinline__ int attsw(int c, int row) {
  return c ^ ((c >> 3) & 7) ^ (row & 7);
}

// ---- shared phase-A macros (pipelined) ----
#define PA_LD(Ea,Pa,Na,jcv) do { int j0=(jcv)*8; \
    Ea.v4[0]=*reinterpret_cast<const float4*>(e2r+j0); Ea.v4[1]=*reinterpret_cast<const float4*>(e2r+j0+4); \
    Pa.v4[0]=*reinterpret_cast<const float4*>(Epr+j0); Pa.v4[1]=*reinterpret_cast<const float4*>(Epr+j0+4); \
    Na.v4[0]=*reinterpret_cast<const float4*>(Enr+j0); Na.v4[1]=*reinterpret_cast<const float4*>(Enr+j0+4); } while(0)
#define PA_PROC(att, Ea,Pa,Na,jcv) do { BF8 pk; \
    _Pragma("unroll") \
    for (int jj=0;jj<8;++jj){ float p=(Ea.f[jj]>thr)?Ap*Pa.f[jj]:An*Na.f[jj]; lsum+=p; pk.u[jj]=f2bf(p);} \
    int c=qd*8+(jcv); *reinterpret_cast<short8*>(&att[r*512+attsw(c,r)*8])=pk.v; } while(0)

// ---------- K5: heads attention; 8 waves, factorized softmax, pipelined ----------
__global__ __launch_bounds__(512) void k5_attn(
    const float* __restrict__ e1h, const float* __restrict__ e2h,
    const float* __restrict__ M2h, const float* __restrict__ E2p, const float* __restrict__ E2n,
    const u16* __restrict__ Whtbf, u16* __restrict__ hcatbf, int nzh)
{
  __shared__ u16 att[64*512];
  __shared__ float inv_lds[64];
  const int orig = blockIdx.x;
  const int xcd = orig & 7;
  const int k = orig >> 3;
  const int nb = k & 7;
  const int zh = xcd * (nzh >> 3) + (k >> 3);
  const int z = zh >> 2, h = zh & 3;
  const int n0 = nb*64;
  const int tid = threadIdx.x;

  const int r = tid >> 3, qd = tid & 7;
  const float e1n = e1h[(size_t)zh*DD + n0 + r];
  const float M2 = M2h[zh];
  const float s = e1n + M2;
  const float mx = (s > 0.f) ? s : 0.1f*s;
  const float Ap = expf(s - mx);
  const float An = expf(0.1f*s - mx);
  const float thr = -e1n;
  const float* e2r = e2h + (size_t)zh*DD + qd*64;
  const float* Epr = E2p + (size_t)zh*DD + qd*64;
  const float* Enr = E2n + (size_t)zh*DD + qd*64;
  float lsum = 0.f;
  {
    F8 e2a,epa,ena, e2b,epb,enb;
    PA_LD(e2a,epa,ena,0);
    PA_LD(e2b,epb,enb,1);
    PA_PROC(att, e2a,epa,ena,0);
    PA_LD(e2a,epa,ena,2);
    PA_PROC(att, e2b,epb,enb,1);
    PA_LD(e2b,epb,enb,3);
    PA_PROC(att, e2a,epa,ena,2);
    PA_LD(e2a,epa,ena,4);
    PA_PROC(att, e2b,epb,enb,3);
    PA_LD(e2b,epb,enb,5);
    PA_PROC(att, e2a,epa,ena,4);
    PA_LD(e2a,epa,ena,6);
    PA_PROC(att, e2b,epb,enb,5);
    PA_LD(e2b,epb,enb,7);
    PA_PROC(att, e2a,epa,ena,6);
    PA_PROC(att, e2b,epb,enb,7);
  }
  lsum += __shfl_xor(lsum, 1);
  lsum += __shfl_xor(lsum, 2);
  lsum += __shfl_xor(lsum, 4);
  if ((tid & 7) == 0) inv_lds[r] = 1.f / lsum;
  __syncthreads();

  const int w = tid >> 6, l = tid & 63, ln = l & 15, kg = l >> 4;
  const u16* B0 = Whtbf + ((size_t)zh*NHID + w*16 + ln)*DD + kg*8;
  f32x4 acc[4];
  #pragma unroll
  for (int ns=0; ns<4; ++ns) acc[ns] = (f32x4){0,0,0,0};

  short8 Pb,Qb,Rb,Sb;
  short8 af0[4], af1[4];
#define K5_LDB(R0,kkv) do { int kc = ((kkv) < 16) ? (kkv) : 0; \
    R0 = *reinterpret_cast<const short8*>(B0 + (size_t)kc*32); } while(0)
#define K5_AFLD(AF,kkv) do { int kc = ((kkv) < 16) ? (kkv) : 0; \
    _Pragma("unroll") \
    for (int ns = 0; ns < 4; ++ns) { int row = ns*16 + ln; int c = kc*4 + kg; \
      AF[ns] = *reinterpret_cast<const short8*>(&att[row*512 + attsw(c,row)*8]); } } while(0)
#define K5_MM(AF,R0) do { \
    _Pragma("unroll") \
    for (int ns = 0; ns < 4; ++ns) \
      acc[ns] = __builtin_amdgcn_mfma_f32_16x16x32_bf16(AF[ns], R0, acc[ns], 0,0,0); } while(0)

  K5_LDB(Pb,0); K5_LDB(Qb,1); K5_LDB(Rb,2);
  K5_AFLD(af0,0);
  #pragma unroll 1
  for (int kk = 0; kk < 16; kk += 4) {
    K5_LDB(Sb,kk+3); K5_AFLD(af1,kk+1); K5_MM(af0,Pb);
    K5_LDB(Pb,kk+4); K5_AFLD(af0,kk+2); K5_MM(af1,Qb);
    K5_LDB(Qb,kk+5); K5_AFLD(af1,kk+3); K5_MM(af0,Rb);
    K5_LDB(Rb,kk+6); K5_AFLD(af0,kk+4); K5_MM(af1,Sb);
  }
#undef K5_LDB
#undef K5_AFLD
#undef K5_MM

  #pragma unroll
  for (int ns = 0; ns < 4; ++ns)
    #pragma unroll
    for (int rr = 0; rr < 4; ++rr) {
      int n = ns*16 + kg*4 + rr;
      float inv = inv_lds[n];
      float sv = acc[ns][rr] * inv;
      sv = (sv > 0.f) ? sv : expm1f(sv);
      hcatbf[((size_t)z*DD + n0 + n)*DD + h*NHID + w*16 + ln] = f2bf(sv);
    }
}

// ---------- K6: Wh2tbf[z][o][n] = (hcat @ oW^T + ob)^T, B=oW-panel staged ----------
__global__ __launch_bounds__(256) void k6_wh2(
    const u16* __restrict__ hcatbf, const u16* __restrict__ oWbf, const float* __restrict__ ob,
    u16* __restrict__ Wh2tbf)
{
  __shared__ u16 bp[2][64*64];
  const int tid = threadIdx.x;
  const int w = tid >> 6, l = tid & 63, ln = l & 15, kg = l >> 4;
  const int n0 = blockIdx.x*64 + w*16;
  const int o0 = blockIdx.y*64;
  const int z  = blockIdx.z;
  const int sc = tid & 7, sr = tid >> 3;
  const int sp = sc ^ (sr & 7);
  const int sp2 = sc ^ ((sr+32) & 7);
  const u16* B0 = oWbf + (size_t)o0*DD;
  const u16* Asrc = hcatbf + (size_t)(z*DD + n0 + ln)*DD + kg*8;

  f32x4 acc[4];
  #pragma unroll
  for (int os=0;os<4;++os) acc[os] = (f32x4){0.f,0.f,0.f,0.f};
  short8 aP0, aP1, aQ0, aQ1, sg0, sg1;

  sg0 = *reinterpret_cast<const short8*>(B0 + (size_t)sr*DD + sc*8);
  sg1 = *reinterpret_cast<const short8*>(B0 + (size_t)(sr+32)*DD + sc*8);
  aP0 = *reinterpret_cast<const short8*>(Asrc);
  aP1 = *reinterpret_cast<const short8*>(Asrc + 32);
  *reinterpret_cast<short8*>(&bp[0][sr*64 + sp*8]) = sg0;
  *reinterpret_cast<short8*>(&bp[0][(sr+32)*64 + sp2*8]) = sg1;
  __syncthreads();

  int cur = 0;
  #pragma unroll 1
  for (int s = 0; s < 8; ++s) {
    const int fn = (s+1)*64;
    if (s < 7) {
      sg0 = *reinterpret_cast<const short8*>(B0 + (size_t)sr*DD + fn + sc*8);
      sg1 = *reinterpret_cast<const short8*>(B0 + (size_t)(sr+32)*DD + fn + sc*8);
      aQ0 = *reinterpret_cast<const short8*>(Asrc + fn);
      aQ1 = *reinterpret_cast<const short8*>(Asrc + fn + 32);
    }
    #pragma unroll
    for (int os = 0; os < 4; ++os) {
      int row = os*16 + ln;
      short8 b0 = *reinterpret_cast<const short8*>(&bp[cur][row*64 + ((kg ^ (row&7))<<3)]);
      acc[os] = __builtin_amdgcn_mfma_f32_16x16x32_bf16(aP0, b0, acc[os], 0,0,0);
      short8 b1 = *reinterpret_cast<const short8*>(&bp[cur][row*64 + (((4+kg) ^ (row&7))<<3)]);
      acc[os] = __builtin_amdgcn_mfma_f32_16x16x32_bf16(aP1, b1, acc[os], 0,0,0);
    }
    if (s < 7) {
      *reinterpret_cast<short8*>(&bp[cur^1][sr*64 + sp*8]) = sg0;
      *reinterpret_cast<short8*>(&bp[cur^1][(sr+32)*64 + sp2*8]) = sg1;
      __syncthreads();
      cur ^= 1;
      aP0 = aQ0; aP1 = aQ1;
    }
  }
  #pragma unroll
  for (int os=0; os<4; ++os)
    #pragma unroll
    for (int r=0; r<4; ++r) {
      int o = o0 + os*16 + ln;
      int n = n0 + kg*4 + r;
      Wh2tbf[((size_t)z*WW + o)*DD + n] = f2bf(acc[os][r] + ob[o]);
    }
}

// ---------- K7: e1o/e2o ----------
__global__ __launch_bounds__(256) void k7_eout(
    const u16* __restrict__ hcatbf,
    const float* __restrict__ oahat_i, const float* __restrict__ oahat_j,
    const float* __restrict__ cvec,
    float* __restrict__ e1, float* __restrict__ e2)
{
  int row = blockIdx.x*4 + (threadIdx.x >> 6);
  int lane = threadIdx.x & 63;
  BF8 v8; v8.v = *reinterpret_cast<const short8*>(hcatbf + (size_t)row*DD + lane*8);
  float a1 = 0.f, a2 = 0.f;
  #pragma unroll
  for (int j = 0; j < 8; ++j) {
    float vf = bf2f(v8.u[j]);
    a1 += vf * oahat_i[lane*8 + j];
    a2 += vf * oahat_j[lane*8 + j];
  }
  #pragma unroll
  for (int off = 32; off >= 1; off >>= 1) { a1 += __shfl_xor(a1, off); a2 += __shfl_xor(a2, off); }
  if (lane == 0) { e1[row] = a1 + cvec[8]; e2[row] = a2 + cvec[9]; }
}

// ---------- K8 (fused): out attention PV + elu + row log_softmax -> gaty bf16 ----------
// One block per (nb, z): all 256 os columns. 8 waves x 2 os-cols (j=0: os=w*16, j=1: os=128+w*16).
__global__ __launch_bounds__(512) void k8_fused(
    const float* __restrict__ e1o, const float* __restrict__ e2o,
    const float* __restrict__ M2o, const float* __restrict__ E2p, const float* __restrict__ E2n,
    const u16* __restrict__ Wh2tbf, u16* __restrict__ gatybf, int CBv)
{
  __shared__ u16 att[64*512];
  __shared__ float inv_lds[64];
  const int orig = blockIdx.x;
  int nb, z;
  if (CBv >= 8) {
    int xcd = orig & 7;
    int k = orig >> 3;            // [0, CBv)
    nb = k & 7;
    z = xcd * (CBv >> 3) + (k >> 3);
  } else {
    nb = orig & 7;
    z = orig >> 3;
  }
  const int n0 = nb*64;
  const int tid = threadIdx.x;

  // phase A: factorized softmax numerators (unnormalized bf16) into swizzled att
  const int r = tid >> 3, qd = tid & 7;
  const float e1n = e1o[(size_t)z*DD + n0 + r];
  const float M2 = M2o[z];
  const float s = e1n + M2;
  const float mxA = (s > 0.f) ? s : 0.1f*s;
  const float Ap = expf(s - mxA);
  const float An = expf(0.1f*s - mxA);
  const float thr = -e1n;
  const float* e2r = e2o + (size_t)z*DD + qd*64;
  const float* Epr = E2p + (size_t)z*DD + qd*64;
  const float* Enr = E2n + (size_t)z*DD + qd*64;
  float lsum = 0.f;
  {
    F8 e2a,epa,ena, e2b,epb,enb;
    PA_LD(e2a,epa,ena,0);
    PA_LD(e2b,epb,enb,1);
    PA_PROC(att, e2a,epa,ena,0);
    PA_LD(e2a,epa,ena,2);
    PA_PROC(att, e2b,epb,enb,1);
    PA_LD(e2b,epb,enb,3);
    PA_PROC(att, e2a,epa,ena,2);
    PA_LD(e2a,epa,ena,4);
    PA_PROC(att, e2b,epb,enb,3);
    PA_LD(e2b,epb,enb,5);
    PA_PROC(att, e2a,epa,ena,4);
    PA_LD(e2a,epa,ena,6);
    PA_PROC(att, e2b,epb,enb,5);
    PA_LD(e2b,epb,enb,7);
    PA_PROC(att, e2a,epa,ena,6);
    PA_PROC(att, e2b,epb,enb,7);
  }
  lsum += __shfl_xor(lsum, 1);
  lsum += __shfl_xor(lsum, 2);
  lsum += __shfl_xor(lsum, 4);
  if ((tid & 7) == 0) inv_lds[r] = 1.f / lsum;
  __syncthreads();

  // phase B: PV for both os columns of this wave.
  const int w = tid >> 6, l = tid & 63, ln = l & 15, kg = l >> 4;
  const u16* B0 = Wh2tbf + ((size_t)z*WW + w*16 + ln)*DD + kg*8;   // j=0; j=1 adds 128*DD
  f32x4 acc[4][2];
  #pragma unroll
  for (int ns=0; ns<4; ++ns) { acc[ns][0] = (f32x4){0,0,0,0}; acc[ns][1] = (f32x4){0,0,0,0}; }

  short8 Pb0,Pb1,Qb0,Qb1;
  short8 af0[4], af1[4];
#define K8_LDB(R0,R1,kkv) do { int kc = ((kkv) < 16) ? (kkv) : 0; \
    R0 = *reinterpret_cast<const short8*>(B0 + (size_t)kc*32); \
    R1 = *reinterpret_cast<const short8*>(B0 + (size_t)128*DD + (size_t)kc*32); } while(0)
#define K8_AFLD(AF,kkv) do { int kc = ((kkv) < 16) ? (kkv) : 0; \
    _Pragma("unroll") \
    for (int ns = 0; ns < 4; ++ns) { int row = ns*16 + ln; int c = kc*4 + kg; \
      AF[ns] = *reinterpret_cast<const short8*>(&att[row*512 + attsw(c,row)*8]); } } while(0)
#define K8_MM(AF,R0,R1) do { \
    _Pragma("unroll") \
    for (int ns = 0; ns < 4; ++ns) { \
      acc[ns][0] = __builtin_amdgcn_mfma_f32_16x16x32_bf16(AF[ns], R0, acc[ns][0], 0,0,0); \
      acc[ns][1] = __builtin_amdgcn_mfma_f32_16x16x32_bf16(AF[ns], R1, acc[ns][1], 0,0,0); \
    } } while(0)

  K8_LDB(Pb0,Pb1,0);
  K8_AFLD(af0,0);
  #pragma unroll 1
  for (int kk = 0; kk < 16; kk += 2) {
    K8_LDB(Qb0,Qb1,kk+1); K8_AFLD(af1,kk+1); K8_MM(af0,Pb0,Pb1);
    K8_LDB(Pb0,Pb1,kk+2); K8_AFLD(af0,kk+2); K8_MM(af1,Qb0,Qb1);
  }
#undef K8_LDB
#undef K8_AFLD
#undef K8_MM

  // ---- in-kernel row log_softmax over all 256 os ----
  __syncthreads();                    // att region now dead; reuse for reductions
  float* red = (float*)att;           // pmax [64][8] at 0, psum at 512, mxf at 1024, lgf at 1088
  float inv_r[4];
  #pragma unroll
  for (int ns=0; ns<4; ++ns) inv_r[ns] = 0.f;  // placeholder (per-n inv read below)

  // pass 1: per-thread max over its 2 os values, then ln-group (16-lane) shuffle max
  #pragma unroll
  for (int ns = 0; ns < 4; ++ns) {
    #pragma unroll
    for (int rr = 0; rr < 4; ++rr) {
      int n = ns*16 + kg*4 + rr;
      float inv = inv_lds[n];
      float v0 = acc[ns][0][rr] * inv; v0 = (v0 > 0.f) ? v0 : expm1f(v0);
      float v1 = acc[ns][1][rr] * inv; v1 = (v1 > 0.f) ? v1 : expm1f(v1);
      float m = fmaxf(v0, v1);
      m = fmaxf(m, __shfl_xor(m, 1));
      m = fmaxf(m, __shfl_xor(m, 2));
      m = fmaxf(m, __shfl_xor(m, 4));
      m = fmaxf(m, __shfl_xor(m, 8));
      if (ln == 0) red[n*8 + w] = m;
    }
  }
  __syncthreads();
  if (tid < 64) {
    float m = red[tid*8];
    #pragma unroll
    for (int j = 1; j < 8; ++j) m = fmaxf(m, red[tid*8 + j]);
    red[1024 + tid] = m;
  }
  __syncthreads();
  // pass 2: sum of exp
  #pragma unroll
  for (int ns = 0; ns < 4; ++ns) {
    #pragma unroll
    for (int rr = 0; rr < 4; ++rr) {
      int n = ns*16 + kg*4 + rr;
      float inv = inv_lds[n];
      float mxn = red[1024 + n];
      float v0 = acc[ns][0][rr] * inv; v0 = (v0 > 0.f) ? v0 : expm1f(v0);
      float v1 = acc[ns][1][rr] * inv; v1 = (v1 > 0.f) ? v1 : expm1f(v1);
      float sm = expf(v0 - mxn) + expf(v1 - mxn);
      sm += __shfl_xor(sm, 1);
      sm += __shfl_xor(sm, 2);
      sm += __shfl_xor(sm, 4);
      sm += __shfl_xor(sm, 8);
      if (ln == 0) red[512 + n*8 + w] = sm;
    }
  }
  __syncthreads();
  if (tid < 64) {
    float sm = 0.f;
    #pragma unroll
    for (int j = 0; j < 8; ++j) sm += red[512 + tid*8 + j];
    red[1088 + tid] = red[1024 + tid] + logf(sm);
  }
  __syncthreads();
  // final write
  #pragma unroll
  for (int ns = 0; ns < 4; ++ns) {
    #pragma unroll
    for (int rr = 0; rr < 4; ++rr) {
      int n = ns*16 + kg*4 + rr;
      float inv = inv_lds[n];
      float lg = red[1088 + n];
      float v0 = acc[ns][0][rr] * inv; v0 = (v0 > 0.f) ? v0 : expm1f(v0);
      float v1 = acc[ns][1][rr] * inv; v1 = (v1 > 0.f) ? v1 : expm1f(v1);
      size_t base = ((size_t)z*DD + n0 + n)*WW;
      gatybf[base + w*16 + ln]       = f2bf(v0 - lg);
      gatybf[base + 128 + w*16 + ln] = f2bf(v1 - lg);
    }
  }
}

// ---------- K9: out = gaty^T @ pW^T + pb ----------
__global__ __launch_bounds__(256) void k9_proj(
    const u16* __restrict__ gatybf, const u16* __restrict__ pWbf, const float* __restrict__ pb,
    int zb, float* __restrict__ out0)
{
  __shared__ u16 gt[64*40];
  const int t0 = blockIdx.x*64, d0 = blockIdx.y*64, z = blockIdx.z;
  const int tid = threadIdx.x;
  const int w = tid >> 6, l = tid & 63, ln = l & 15, kg = l >> 4;
  const int el = tid >> 3, t8 = tid & 7;
  f32x4 acc[4];
  #pragma unroll
  for (int os=0;os<4;++os) acc[os] = (f32x4){0.f,0.f,0.f,0.f};
  for (int e0 = 0; e0 < DD; e0 += 32) {
    __syncthreads();
    BF8 g8;
    g8.v = *reinterpret_cast<const short8*>(gatybf + ((size_t)z*DD + e0 + el)*WW + t0 + t8*8);
    #pragma unroll
    for (int j = 0; j < 8; ++j) gt[(t8*8 + j)*40 + el] = g8.u[j];
    __syncthreads();
    short8 a = *reinterpret_cast<const short8*>(&gt[(w*16 + ln)*40 + kg*8]);
    #pragma unroll
    for (int os = 0; os < 4; ++os) {
      short8 b = *reinterpret_cast<const short8*>(pWbf + (size_t)(d0 + os*16 + ln)*DD + e0 + kg*8);
      acc[os] = __builtin_amdgcn_mfma_f32_16x16x32_bf16(a, b, acc[os], 0,0,0);
    }
  }
  #pragma unroll
  for (int os=0; os<4; ++os)
    #pragma unroll
    for (int rr=0; rr<4; ++rr) {
      int t = t0 + w*16 + kg*4 + rr;
      int d = d0 + os*16 + ln;
      out0[((size_t)(zb+z)*WW + t)*DD + d] = acc[os][rr] + pb[d];
    }
}

extern "C" void kernel_launch(void* const* d_in, const int* in_sizes, int n_in,
                              void* d_out, int out_size, void* d_ws, size_t ws_size,
                              hipStream_t stream)
{
  const float* x   = (const float*)d_in[0];
  const float* qW  = (const float*)d_in[1];
  const float* qb  = (const float*)d_in[2];
  const float* kW  = (const float*)d_in[3];
  const float* kb  = (const float*)d_in[4];
  const float* vW  = (const float*)d_in[5];
  const float* vb  = (const float*)d_in[6];
  const float* hW  = (const float*)d_in[7];
  const float* hb  = (const float*)d_in[8];
  const float* hai = (const float*)d_in[9];
  const float* haib= (const float*)d_in[10];
  const float* haj = (const float*)d_in[11];
  const float* hajb= (const float*)d_in[12];
  const float* oW  = (const float*)d_in[13];
  const float* ob  = (const float*)d_in[14];
  const float* oai = (const float*)d_in[15];
  const float* oaib= (const float*)d_in[16];
  const float* oaj = (const float*)d_in[17];
  const float* oajb= (const float*)d_in[18];
  const float* pW  = (const float*)d_in[19];
  const float* pb  = (const float*)d_in[20];

  float* out0 = (float*)d_out;                   // [B,W,D] f32
  float* adjo = out0 + (size_t)BB*WW*DD;         // [B,D,D] f32

  // static region (float offsets)
  float* ws      = (float*)d_ws;
  u16*   Wt      = (u16*)(ws + 0);           // 1,179,648 f
  u16*   hWbf    = (u16*)(ws + 1179648);     //    65,536 f
  u16*   oWbf    = (u16*)(ws + 1245184);     //    65,536 f
  u16*   pWbf    = (u16*)(ws + 1310720);     //   131,072 f
  float* ahat_i  = ws + 1441792;
  float* ahat_j  = ws + 1442816;
  float* oahat_i = ws + 1443840;
  float* oahat_j = ws + 1444352;
  float* cvec    = ws + 1444864;
  float* e1h     = ws + 1444880;             //    65,536 f (CB=32 max)
  float* e2h     = ws + 1510416;
  float* e1o     = ws + 1575952;             //    16,384 f
  float* e2o     = ws + 1592336;
  float* M2h     = ws + 1608720;             //       128 f
  float* E2hp    = ws + 1608848;             //    65,536 f
  float* E2hn    = ws + 1674384;             //    65,536 f
  float* M2o     = ws + 1739920;             //        32 f
  float* E2op    = ws + 1739952;             //    16,384 f
  float* E2on    = ws + 1756336;             //    16,384 f
  const size_t X0 = 1772720;                 // dynamic region start

  // per-CB dynamic: xpad 66,048 + vbf 65,536 + qbf 65,536 + kbf 65,536 + Whtbf 131,072 = 393,728 f
  int CB = 4;
  {
    const int cand[3] = {32, 16, 8};
    for (int i = 0; i < 3; ++i) {
      size_t need = (X0 + (size_t)cand[i]*393728) * 4;
      if (need <= ws_size) { CB = cand[i]; break; }
    }
  }

  u16* xpad   = (u16*)(ws + X0);                        // CB*66,048 f  ([z][258][512])
  u16* vbf    = (u16*)(ws + X0 + (size_t)CB*66048);     // CB*65,536 f
  u16* qbf    = (u16*)(ws + X0 + (size_t)CB*131584);    // CB*65,536 f
  u16* kbf    = (u16*)(ws + X0 + (size_t)CB*197120);    // CB*65,536 f
  u16* Whtbf  = (u16*)(ws + X0 + (size_t)CB*262656);    // CB*131,072 f
  // overlays (lifetimes: xpad dead after k1; vbf dead after k4; qbf,kbf dead after k2;
  // hcatbf dead after k7; Whtbf dead after k5)
  u16*   hcatbf = (u16*)(ws + X0);                      // over xpad+vbf
  u16*   gatybf = (u16*)(ws + X0 + (size_t)CB*131584);  // over qbf
  u16*   Wh2tbf = (u16*)(ws + X0 + (size_t)CB*197120);  // over kbf

  kprep_w<<<dim3((3*DD*DD + 255)/256), 256, 0, stream>>>(qW, kW, vW, Wt);
  kcvt<<<dim3((NHEADS*NHID*WW + 255)/256), 256, 0, stream>>>(hW, hWbf, NHEADS*NHID*WW);
  kcvt<<<dim3((WW*DD + 255)/256), 256, 0, stream>>>(oW, oWbf, WW*DD);
  kcvt<<<dim3((DD*DD + 255)/256), 256, 0, stream>>>(pW, pWbf, DD*DD);
  kprep_a<<<dim3(13), 256, 0, stream>>>(hW, hai, haib, haj, hajb, hb,
                                        oW, oai, oaib, oaj, oajb, ob,
                                        ahat_i, ahat_j, oahat_i, oahat_j, cvec);

  for (int zb = 0; zb < BB; zb += CB) {
    int nrow8 = CB*258*64;
    kprep_x  <<<dim3((nrow8 + 255)/256), 256, 0, stream>>>(x, zb, nrow8, xpad);
    k1_mfma  <<<dim3(DD/64, WW/128, CB), 256, 0, stream>>>(xpad, Wt, qb, kb, vb, qbf, kbf, vbf);
    k2_adj   <<<dim3(DD/64, DD/64, CB), 256, 0, stream>>>(qbf, kbf, zb, adjo);
    k3_wh    <<<dim3(DD/64, NHID/64, CB*NHEADS), 256, 0, stream>>>(vbf, hWbf, hb, Whtbf);
    k4_eheads<<<dim3(CB*NHEADS*DD/4), 256, 0, stream>>>(vbf, ahat_i, ahat_j, cvec, e1h, e2h);
    kexp2    <<<dim3(CB*NHEADS), 256, 0, stream>>>(e2h, M2h, E2hp, E2hn);
    k5_attn  <<<dim3(32*CB), 512, 0, stream>>>(e1h, e2h, M2h, E2hp, E2hn, Whtbf, hcatbf, CB*NHEADS);
    k6_wh2   <<<dim3(DD/64, WW/64, CB), 256, 0, stream>>>(hcatbf, oWbf, ob, Wh2tbf);
    k7_eout  <<<dim3(CB*DD/4), 256, 0, stream>>>(hcatbf, oahat_i, oahat_j, cvec, e1o, e2o);
    kexp2    <<<dim3(CB), 256, 0, stream>>>(e2o, M2o, E2op, E2on);
    k8_fused <<<dim3(8*CB), 512, 0, stream>>>(e1o, e2o, M2o, E2op, E2on, Wh2tbf, gatybf, CB);
    k9_proj  <<<dim3(WW/64, DD/64, CB), 256, 0, stream>>>(gatybf, pWbf, pb, zb, out0);
  }
}